// Round 1
// baseline (8652.771 us; speedup 1.0000x reference)
//
#include <hip/hip_runtime.h>
#include <math.h>

#define WS_BIG 8388608  // 16*128*64*64

__device__ __forceinline__ float gelu_f(float x) {
    return 0.5f * x * (1.0f + erff(x * 0.70710678118654752440f));
}

// nearest sample index per F.grid_sample(nearest, align_corners=False, zeros pad)
__device__ __forceinline__ void nsamp(float cy, float cx, int hi, int wi,
                                      int& iy, int& ix, bool& valid) {
    float fy = rintf(((cy + 1.0f) * (float)hi - 1.0f) * 0.5f);
    float fx = rintf(((cx + 1.0f) * (float)wi - 1.0f) * 0.5f);
    valid = (fy >= 0.0f) && (fy < (float)hi) && (fx >= 0.0f) && (fx < (float)wi);
    iy = (int)fminf(fmaxf(fy, 0.0f), (float)(hi - 1));
    ix = (int)fminf(fmaxf(fx, 0.0f), (float)(wi - 1));
}

__global__ __launch_bounds__(256) void concat_kernel(
    const float* __restrict__ a, const float* __restrict__ l,
    float* __restrict__ out, int total) {
    int i = blockIdx.x * 256 + threadIdx.x;
    if (i >= total) return;
    int p = i & 4095;
    int r = i >> 12;
    int ch = r % 34;
    int b = r / 34;
    out[i] = (ch < 3) ? a[((size_t)(b * 3 + ch)) * 4096 + p]
                      : l[((size_t)(b * 31 + (ch - 3))) * 4096 + p];
}

// conv3x3 SAME for 64x64 images, Cout=128. tile 32x32 px, 16 couts/block.
// mode: 0 = store (+skip), 1 = relu store, 2 = accumulate into out
__global__ __launch_bounds__(256) void conv3x3_64(
    const float* __restrict__ in, const float* __restrict__ w,
    const float* __restrict__ bias, const float* __restrict__ skip,
    float* __restrict__ out, int Cin, int mode) {
    __shared__ float s_in[4 * 1156];  // 4 cin x 34x34
    __shared__ float s_w[16 * 36];
    int bx = blockIdx.x;
    int cob = bx & 7;
    int t4 = (bx >> 3) & 3;
    int b = bx >> 5;
    int oy = (t4 >> 1) * 32, ox = (t4 & 1) * 32;
    int tid = threadIdx.x;
    int r = tid >> 3;            // 0..31 output row in tile
    int x0 = (tid & 7) * 4;      // 4 consecutive output cols
    float acc[16][4];
#pragma unroll
    for (int co = 0; co < 16; ++co) {
        acc[co][0] = acc[co][1] = acc[co][2] = acc[co][3] = 0.f;
    }

    for (int cin0 = 0; cin0 < Cin; cin0 += 4) {
        int cc = min(4, Cin - cin0);
        for (int ci = 0; ci < cc; ++ci) {
            const float* ip = in + (size_t)(b * Cin + cin0 + ci) * 4096;
            for (int p = tid; p < 1156; p += 256) {
                int row = p / 34, col = p - row * 34;
                int gy = oy + row - 1, gx = ox + col - 1;
                float v = 0.f;
                if (gy >= 0 && gy < 64 && gx >= 0 && gx < 64)
                    v = ip[gy * 64 + gx];
                s_in[ci * 1156 + p] = v;
            }
        }
        for (int i = tid; i < 16 * 36; i += 256) {
            int co = i / 36, rem = i - co * 36;
            int ci = rem / 9, tap = rem - ci * 9;
            if (ci < cc)
                s_w[i] = w[((size_t)(cob * 16 + co) * Cin + cin0 + ci) * 9 + tap];
        }
        __syncthreads();
        for (int ci = 0; ci < cc; ++ci) {
            float nb[3][6];
#pragma unroll
            for (int dy = 0; dy < 3; ++dy)
#pragma unroll
                for (int dx = 0; dx < 6; ++dx)
                    nb[dy][dx] = s_in[ci * 1156 + (r + dy) * 34 + x0 + dx];
#pragma unroll
            for (int co = 0; co < 16; ++co) {
                const float* wp = &s_w[co * 36 + ci * 9];
                float w0 = wp[0], w1_ = wp[1], w2_ = wp[2];
                float w3 = wp[3], w4_ = wp[4], w5 = wp[5];
                float w6 = wp[6], w7 = wp[7], w8 = wp[8];
#pragma unroll
                for (int px = 0; px < 4; ++px) {
                    acc[co][px] += w0 * nb[0][px] + w1_ * nb[0][px + 1] + w2_ * nb[0][px + 2]
                                 + w3 * nb[1][px] + w4_ * nb[1][px + 1] + w5 * nb[1][px + 2]
                                 + w6 * nb[2][px] + w7 * nb[2][px + 1] + w8 * nb[2][px + 2];
                }
            }
        }
        __syncthreads();
    }
    int cog0 = cob * 16;
#pragma unroll
    for (int co = 0; co < 16; ++co) {
        float bv = bias[cog0 + co];
        float v0 = acc[co][0] + bv, v1 = acc[co][1] + bv;
        float v2 = acc[co][2] + bv, v3 = acc[co][3] + bv;
        if (mode == 1) {
            v0 = fmaxf(v0, 0.f); v1 = fmaxf(v1, 0.f);
            v2 = fmaxf(v2, 0.f); v3 = fmaxf(v3, 0.f);
        }
        size_t idx = (((size_t)(b * 128 + cog0 + co) * 64 + oy + r) * 64 + ox + x0);
        if (skip) {
            float4 s = *(const float4*)&skip[idx];
            v0 += s.x; v1 += s.y; v2 += s.z; v3 += s.w;
        }
        if (mode == 2) {
            float4 o = *(const float4*)&out[idx];
            v0 += o.x; v1 += o.y; v2 += o.z; v3 += o.w;
        }
        *(float4*)&out[idx] = make_float4(v0, v1, v2, v3);
    }
}

// conv3x3 SAME for 16x16 images, Cout=128. 2 batches x 8 couts per block.
__global__ __launch_bounds__(256) void conv3x3_16(
    const float* __restrict__ in, const float* __restrict__ w,
    const float* __restrict__ bias, const float* __restrict__ skip,
    float* __restrict__ out, int Cin, int mode) {
    __shared__ float s_in[2 * 4 * 324];  // 2 batch x 4 cin x 18x18
    __shared__ float s_w[8 * 36];
    int bx = blockIdx.x;
    int cob = bx & 15;
    int b0 = (bx >> 4) * 2;
    int tid = threadIdx.x;
    int y = tid >> 4, x = tid & 15;
    float acc[2][8];
#pragma unroll
    for (int bt = 0; bt < 2; ++bt)
#pragma unroll
        for (int co = 0; co < 8; ++co) acc[bt][co] = 0.f;

    for (int cin0 = 0; cin0 < Cin; cin0 += 4) {
        int cc = min(4, Cin - cin0);
        for (int bt = 0; bt < 2; ++bt)
            for (int ci = 0; ci < cc; ++ci) {
                const float* ip = in + (size_t)((b0 + bt) * Cin + cin0 + ci) * 256;
                for (int p = tid; p < 324; p += 256) {
                    int row = p / 18, col = p - row * 18;
                    int gy = row - 1, gx = col - 1;
                    float v = 0.f;
                    if (gy >= 0 && gy < 16 && gx >= 0 && gx < 16)
                        v = ip[gy * 16 + gx];
                    s_in[(bt * 4 + ci) * 324 + p] = v;
                }
            }
        for (int i = tid; i < 8 * 36; i += 256) {
            int co = i / 36, rem = i - co * 36;
            int ci = rem / 9, tap = rem - ci * 9;
            if (ci < cc)
                s_w[i] = w[((size_t)(cob * 8 + co) * Cin + cin0 + ci) * 9 + tap];
        }
        __syncthreads();
        for (int ci = 0; ci < cc; ++ci) {
            float nb0[9], nb1[9];
#pragma unroll
            for (int dy = 0; dy < 3; ++dy)
#pragma unroll
                for (int dx = 0; dx < 3; ++dx) {
                    nb0[dy * 3 + dx] = s_in[(0 * 4 + ci) * 324 + (y + dy) * 18 + x + dx];
                    nb1[dy * 3 + dx] = s_in[(1 * 4 + ci) * 324 + (y + dy) * 18 + x + dx];
                }
#pragma unroll
            for (int co = 0; co < 8; ++co) {
                const float* wp = &s_w[co * 36 + ci * 9];
                float s0 = 0.f, s1 = 0.f;
#pragma unroll
                for (int t9 = 0; t9 < 9; ++t9) {
                    s0 += wp[t9] * nb0[t9];
                    s1 += wp[t9] * nb1[t9];
                }
                acc[0][co] += s0;
                acc[1][co] += s1;
            }
        }
        __syncthreads();
    }
    for (int bt = 0; bt < 2; ++bt)
        for (int co = 0; co < 8; ++co) {
            float v = acc[bt][co] + bias[cob * 8 + co];
            if (mode == 1) v = fmaxf(v, 0.f);
            size_t idx = (((size_t)((b0 + bt) * 128 + cob * 8 + co) * 16 + y) * 16 + x);
            if (skip) v += skip[idx];
            if (mode == 2) v += out[idx];
            out[idx] = v;
        }
}

// NCHW -> NHWC transpose (C, HW multiples of 64)
__global__ __launch_bounds__(256) void transpose_cn(
    const float* __restrict__ in, float* __restrict__ out, int C, int HW) {
    __shared__ float t[64][65];
    int pt = HW >> 6, ct = C >> 6;
    int bx = blockIdx.x;
    int p0 = (bx % pt) * 64;
    int c0 = ((bx / pt) % ct) * 64;
    int b = bx / (pt * ct);
    int tid = threadIdx.x;
    int li = tid & 63, lo = tid >> 6;
#pragma unroll
    for (int i = 0; i < 16; ++i) {
        int row = i * 4 + lo;
        t[row][li] = in[(size_t)(b * C + c0 + row) * HW + p0 + li];
    }
    __syncthreads();
#pragma unroll
    for (int i = 0; i < 16; ++i) {
        int prow = i * 4 + lo;
        out[(size_t)(b * HW + p0 + prow) * C + c0 + li] = t[li][prow];
    }
}

// max pool kxk stride k on NHWC (C=128)
__global__ __launch_bounds__(256) void maxpool_nhwc(
    const float* __restrict__ in, float* __restrict__ out,
    int H, int W, int k, int total) {
    int i = blockIdx.x * 256 + threadIdx.x;
    if (i >= total) return;
    int c = i & 127;
    int r = i >> 7;
    int Wo = W / k, Ho = H / k;
    int x = r % Wo; r /= Wo;
    int y = r % Ho;
    int b = r / Ho;
    float m = -3.402823466e38f;
    for (int dy = 0; dy < k; ++dy)
        for (int dx = 0; dx < k; ++dx)
            m = fmaxf(m, in[((size_t)(b * H + y * k + dy) * W + x * k + dx) * 128 + c]);
    out[i] = m;
}

// Fused level(): 8 queries per block (one batch). NHWC feature inputs.
__global__ __launch_bounds__(256) void level_kernel(
    const float* __restrict__ featT, int fh, int fw,
    const float* __restrict__ guideT, int Hg, int Wg,
    const float* __restrict__ glrT, int hl, int wl,
    int Hq, int Wq, int n_per_b,
    const float* __restrict__ imw, const float* __restrict__ imb,
    const float* __restrict__ w1, const float* __restrict__ b1,
    const float* __restrict__ w2, const float* __restrict__ b2,
    const float* __restrict__ f1, const float* __restrict__ fb1,
    const float* __restrict__ f2, const float* __restrict__ fb2,
    int odim, int residual, int out_nchw,
    const float* __restrict__ lms,
    float* __restrict__ out) {
    __shared__ float s_preds[64 * 130];  // [q*8+j][130] padded
    __shared__ float s_scr[64 * 66];     // inp [8][388] then h1 [qj][66]
    __shared__ float s_gr[8 * 128];      // g_s then recon
    __shared__ float s_h[8 * 64];

    int tid = threadIdx.x;
    int b = blockIdx.x / n_per_b;
    int n0 = (blockIdx.x % n_per_b) * 8;
    float invHq = 1.0f / (float)Hq, invWq = 1.0f / (float)Wq;
    float invfh = 1.0f / (float)fh, invfw = 1.0f / (float)fw;
    int wave = tid >> 6, lane = tid & 63;

    // phase 0: g_s at exact coords
    for (int it = 0; it < 4; ++it) {
        int q = it * 2 + (tid >> 7);
        int d = tid & 127;
        int n = n0 + q;
        int qy = n / Wq, qx = n - qy * Wq;
        float cy = -1.0f + (float)(2 * qy + 1) * invHq;
        float cx = -1.0f + (float)(2 * qx + 1) * invWq;
        int iy, ix; bool v;
        nsamp(cy, cx, Hg, Wg, iy, ix, v);
        s_gr[q * 128 + d] = v ? guideT[((size_t)(b * Hg + iy) * Wg + ix) * 128 + d] : 0.0f;
    }
    __syncthreads();

    float* s_inp = s_scr;  // [8][388]
    for (int cidx = 0; cidx < 4; ++cidx) {
        float vx = (cidx < 2) ? -1.0f : 1.0f;
        float vy = (cidx & 1) ? 1.0f : -1.0f;
        // build inp = [f_s | g_s | gl_s | rel]
        for (int it = 0; it < 4; ++it) {
            int q = it * 2 + (tid >> 7);
            int d = tid & 127;
            int n = n0 + q;
            int qy = n / Wq, qx = n - qy * Wq;
            float cy = -1.0f + (float)(2 * qy + 1) * invHq;
            float cx = -1.0f + (float)(2 * qx + 1) * invWq;
            float cy_ = cy + vx * invfh;
            float cx_ = cx + vy * invfw;
            int iy, ix; bool vf;
            nsamp(cy_, cx_, fh, fw, iy, ix, vf);
            s_inp[q * 388 + d] = vf ? featT[((size_t)(b * fh + iy) * fw + ix) * 128 + d] : 0.0f;
            s_inp[q * 388 + 128 + d] = s_gr[q * 128 + d];
            int iy2, ix2; bool vg;
            nsamp(cy_, cx_, hl, wl, iy2, ix2, vg);
            s_inp[q * 388 + 256 + d] = vg ? glrT[((size_t)(b * hl + iy2) * wl + ix2) * 128 + d] : 0.0f;
            if (d == 0) {
                float csy = vf ? (-1.0f + (float)(2 * iy + 1) * invfh) : 0.0f;
                float csx = vf ? (-1.0f + (float)(2 * ix + 1) * invfw) : 0.0f;
                s_inp[q * 388 + 384] = (cy - csy) * (float)fh;
                s_inp[q * 388 + 385] = (cx - csx) * (float)fw;
            }
        }
        __syncthreads();
        // inp[8][386] @ imw[386][256]: k-split over 4 waves, each lane 4 cols, all 8 q
        float acc[8][4];
#pragma unroll
        for (int q = 0; q < 8; ++q) {
            acc[q][0] = acc[q][1] = acc[q][2] = acc[q][3] = 0.f;
        }
        int k0 = wave * 96 + (wave < 2 ? wave : 2);
        int klen = (wave < 2) ? 97 : 96;
        const float4* imw4 = (const float4*)imw;
        for (int k = k0; k < k0 + klen; ++k) {
            float4 wv = imw4[k * 64 + lane];
#pragma unroll
            for (int q = 0; q < 8; ++q) {
                float a = s_inp[q * 388 + k];
                acc[q][0] += a * wv.x;
                acc[q][1] += a * wv.y;
                acc[q][2] += a * wv.z;
                acc[q][3] += a * wv.w;
            }
        }
        int j0 = cidx * 2;
        // serialized cross-wave reduction into s_preds
        for (int wr = 0; wr < 4; ++wr) {
            if (wave == wr) {
#pragma unroll
                for (int q = 0; q < 8; ++q)
#pragma unroll
                    for (int i = 0; i < 4; ++i) {
                        int c = lane * 4 + i;
                        int idx = (q * 8 + j0 + (c >> 7)) * 130 + (c & 127);
                        if (wr == 0) s_preds[idx] = acc[q][i];
                        else s_preds[idx] += acc[q][i];
                    }
            }
            __syncthreads();
        }
        // bias + relu
        for (int i = tid; i < 2048; i += 256) {
            int q = i >> 8, c = i & 255;
            int idx = (q * 8 + j0 + (c >> 7)) * 130 + (c & 127);
            s_preds[idx] = fmaxf(s_preds[idx] + imb[c], 0.0f);
        }
        __syncthreads();
    }

    // wg1: h1[qj][64] = gelu(preds @ w1 + b1)
    {
        int g = tid >> 4;
        int c0q = tid & 15;
        float a1[4][4];
#pragma unroll
        for (int p = 0; p < 4; ++p) {
            a1[p][0] = a1[p][1] = a1[p][2] = a1[p][3] = 0.f;
        }
        const float4* w14 = (const float4*)w1;
        for (int k = 0; k < 128; ++k) {
            float4 wv = w14[k * 16 + c0q];
#pragma unroll
            for (int p = 0; p < 4; ++p) {
                float pv = s_preds[(g + p * 16) * 130 + k];
                a1[p][0] += pv * wv.x; a1[p][1] += pv * wv.y;
                a1[p][2] += pv * wv.z; a1[p][3] += pv * wv.w;
            }
        }
#pragma unroll
        for (int p = 0; p < 4; ++p)
#pragma unroll
            for (int i = 0; i < 4; ++i) {
                float xx = a1[p][i] + b1[c0q * 4 + i];
                s_scr[(g + p * 16) * 66 + c0q * 4 + i] = gelu_f(xx);
            }
    }
    __syncthreads();

    // wg2 + softmax over j + recon
    {
        int q = tid >> 5;
        int d0 = (tid & 31) * 4;
        float wv[8][4];
#pragma unroll
        for (int j = 0; j < 8; ++j) {
            wv[j][0] = wv[j][1] = wv[j][2] = wv[j][3] = 0.f;
        }
        const float4* w24 = (const float4*)w2;
        for (int k = 0; k < 64; ++k) {
            float4 w2v = w24[k * 32 + (tid & 31)];
#pragma unroll
            for (int j = 0; j < 8; ++j) {
                float h1v = s_scr[(q * 8 + j) * 66 + k];
                wv[j][0] += h1v * w2v.x; wv[j][1] += h1v * w2v.y;
                wv[j][2] += h1v * w2v.z; wv[j][3] += h1v * w2v.w;
            }
        }
        float4 b2v = *(const float4*)&b2[d0];
        float bb[4] = {b2v.x, b2v.y, b2v.z, b2v.w};
#pragma unroll
        for (int i = 0; i < 4; ++i) {
            float m = -3.4e38f;
#pragma unroll
            for (int j = 0; j < 8; ++j) {
                wv[j][i] += bb[i];
                m = fmaxf(m, wv[j][i]);
            }
            float s = 0.f;
#pragma unroll
            for (int j = 0; j < 8; ++j) {
                wv[j][i] = __expf(wv[j][i] - m);
                s += wv[j][i];
            }
            float inv = 1.0f / s;
            float rec = 0.f;
#pragma unroll
            for (int j = 0; j < 8; ++j)
                rec += s_preds[(q * 8 + j) * 130 + d0 + i] * wv[j][i];
            s_gr[q * 128 + d0 + i] = rec * inv;
        }
    }
    __syncthreads();

    // ffn hidden
    for (int p = 0; p < 2; ++p) {
        int q = p * 4 + (tid >> 6);
        int c = tid & 63;
        float a = 0.f;
        for (int k = 0; k < 128; ++k)
            a += s_gr[q * 128 + k] * f1[k * 64 + c];
        s_h[q * 64 + c] = gelu_f(a + fb1[c]);
    }
    __syncthreads();

    if (!out_nchw) {
        // level1: odim=128, NHWC out, residual
        for (int it = 0; it < 4; ++it) {
            int q = it * 2 + (tid >> 7);
            int d = tid & 127;
            int n = n0 + q;
            int qy = n / Wq, qx = n - qy * Wq;
            float a = 0.f;
            for (int k = 0; k < 64; ++k)
                a += s_h[q * 64 + k] * f2[k * 128 + d];
            a += fb2[d];
            if (residual) a += s_gr[q * 128 + d];
            out[((size_t)(b * Hq + qy) * Wq + qx) * 128 + d] = a;
        }
    } else {
        // level2: odim=31, NCHW out, + lms
        if (tid < 8 * odim) {
            int q = tid / odim, d = tid - q * odim;
            int n = n0 + q;
            int qy = n / Wq, qx = n - qy * Wq;
            float a = 0.f;
            for (int k = 0; k < 64; ++k)
                a += s_h[q * 64 + k] * f2[k * odim + d];
            a += fb2[d];
            if (lms) a += lms[(((size_t)b * odim + d) * Hq + qy) * Wq + qx];
            out[(((size_t)b * odim + d) * Hq + qy) * Wq + qx] = a;
        }
    }
}

extern "C" void kernel_launch(void* const* d_in, const int* in_sizes, int n_in,
                              void* d_out, int out_size, void* d_ws, size_t ws_size,
                              hipStream_t stream) {
    (void)in_sizes; (void)n_in; (void)out_size; (void)ws_size;
    const float* HR_MSI     = (const float*)d_in[0];
    const float* lms        = (const float*)d_in[1];
    const float* LR_HSI     = (const float*)d_in[2];
    const float* spa_head_w = (const float*)d_in[3];
    const float* spa_head_b = (const float*)d_in[4];
    const float* spa_res_w  = (const float*)d_in[5];
    const float* spa_res_b  = (const float*)d_in[6];
    const float* spa_tail_w = (const float*)d_in[7];
    const float* spa_tail_b = (const float*)d_in[8];
    const float* spe_head_w = (const float*)d_in[9];
    const float* spe_head_b = (const float*)d_in[10];
    const float* spe_res_w  = (const float*)d_in[11];
    const float* spe_res_b  = (const float*)d_in[12];
    const float* spe_tail_w = (const float*)d_in[13];
    const float* spe_tail_b = (const float*)d_in[14];
    const float* l1_w   = (const float*)d_in[15];
    const float* l1_b   = (const float*)d_in[16];
    const float* wg32_w1 = (const float*)d_in[17];
    const float* wg32_b1 = (const float*)d_in[18];
    const float* wg32_w2 = (const float*)d_in[19];
    const float* wg32_b2 = (const float*)d_in[20];
    const float* ffn32_w1 = (const float*)d_in[21];
    const float* ffn32_b1 = (const float*)d_in[22];
    const float* ffn32_w2 = (const float*)d_in[23];
    const float* ffn32_b2 = (const float*)d_in[24];
    const float* l2_w   = (const float*)d_in[25];
    const float* l2_b   = (const float*)d_in[26];
    const float* wg64_w1 = (const float*)d_in[27];
    const float* wg64_b1 = (const float*)d_in[28];
    const float* wg64_w2 = (const float*)d_in[29];
    const float* wg64_b2 = (const float*)d_in[30];
    const float* ffn64_w1 = (const float*)d_in[31];
    const float* ffn64_b1 = (const float*)d_in[32];
    const float* ffn64_w2 = (const float*)d_in[33];
    const float* ffn64_b2 = (const float*)d_in[34];

    float* ws = (float*)d_ws;
    float* X = ws;                              // head out / skip; later pools+l1T region
    float* R = ws + (size_t)WS_BIG;             // res ping; later hr_spaT (NHWC)
    float* T = ws + 2 * (size_t)WS_BIG;         // temp; later hr_spa (NCHW)
    float* C = ws + 3 * (size_t)WS_BIG;         // concat [16,34,64,64]; later spe bufs
    float* X2 = C;
    float* R2 = C + 524288;
    float* T2 = C + 1048576;
    float* lr_speT = C + 1572864;
    float* g32T = X;                 // [16,32,32,128] NHWC
    float* g16T = X + 2097152;       // [16,16,16,128] NHWC
    float* l1T  = X + 2621440;       // [16,32,32,128] NHWC

    // ---- spatial EDSR on concat(HR_MSI, lms) ----
    concat_kernel<<<8704, 256, 0, stream>>>(HR_MSI, lms, C, 16 * 34 * 4096);
    conv3x3_64<<<512, 256, 0, stream>>>(C, spa_head_w, spa_head_b, nullptr, X, 34, 0);
    hipMemcpyAsync(R, X, (size_t)WS_BIG * 4, hipMemcpyDeviceToDevice, stream);
    for (int i = 0; i < 4; ++i) {
        conv3x3_64<<<512, 256, 0, stream>>>(R, spa_res_w + (size_t)(i * 2) * 147456,
                                            spa_res_b + (i * 2) * 128, nullptr, T, 128, 1);
        conv3x3_64<<<512, 256, 0, stream>>>(T, spa_res_w + (size_t)(i * 2 + 1) * 147456,
                                            spa_res_b + (i * 2 + 1) * 128, nullptr, R, 128, 2);
    }
    conv3x3_64<<<512, 256, 0, stream>>>(R, spa_tail_w, spa_tail_b, X, T, 128, 0);  // hr_spa = T
    transpose_cn<<<2048, 256, 0, stream>>>(T, R, 128, 4096);                       // hr_spaT = R
    maxpool_nhwc<<<8192, 256, 0, stream>>>(R, g32T, 64, 64, 2, 2097152);
    maxpool_nhwc<<<2048, 256, 0, stream>>>(R, g16T, 64, 64, 4, 524288);

    // ---- spectral EDSR on LR_HSI ----
    conv3x3_16<<<128, 256, 0, stream>>>(LR_HSI, spe_head_w, spe_head_b, nullptr, X2, 31, 0);
    hipMemcpyAsync(R2, X2, (size_t)524288 * 4, hipMemcpyDeviceToDevice, stream);
    for (int i = 0; i < 4; ++i) {
        conv3x3_16<<<128, 256, 0, stream>>>(R2, spe_res_w + (size_t)(i * 2) * 147456,
                                            spe_res_b + (i * 2) * 128, nullptr, T2, 128, 1);
        conv3x3_16<<<128, 256, 0, stream>>>(T2, spe_res_w + (size_t)(i * 2 + 1) * 147456,
                                            spe_res_b + (i * 2 + 1) * 128, nullptr, R2, 128, 2);
    }
    conv3x3_16<<<128, 256, 0, stream>>>(R2, spe_tail_w, spe_tail_b, X2, T2, 128, 0);  // lr_spe = T2
    transpose_cn<<<128, 256, 0, stream>>>(T2, lr_speT, 128, 256);

    // ---- level 1: 32x32 queries ----
    level_kernel<<<2048, 256, 0, stream>>>(
        lr_speT, 16, 16, g32T, 32, 32, g16T, 16, 16,
        32, 32, 128,
        l1_w, l1_b, wg32_w1, wg32_b1, wg32_w2, wg32_b2,
        ffn32_w1, ffn32_b1, ffn32_w2, ffn32_b2,
        128, 1, 0, nullptr, l1T);

    // ---- level 2: 64x64 queries, + lms, write NCHW to d_out ----
    level_kernel<<<8192, 256, 0, stream>>>(
        l1T, 32, 32, R, 64, 64, g32T, 32, 32,
        64, 64, 512,
        l2_w, l2_b, wg64_w1, wg64_b1, wg64_w2, wg64_b2,
        ffn64_w1, ffn64_b1, ffn64_w2, ffn64_b2,
        31, 0, 1, lms, (float*)d_out);
}

// Round 2
// 3417.896 us; speedup vs baseline: 2.5316x; 2.5316x over previous
//
#include <hip/hip_runtime.h>
#include <math.h>

typedef _Float16 f16;
typedef __attribute__((ext_vector_type(8))) _Float16 f16x8;
typedef __attribute__((ext_vector_type(4))) float f32x4;
typedef __attribute__((ext_vector_type(4))) unsigned int u32x4;

__device__ __forceinline__ float gelu_f(float x) {
    return 0.5f * x * (1.0f + erff(x * 0.70710678118654752440f));
}

__device__ __forceinline__ void nsamp(float cy, float cx, int hi, int wi,
                                      int& iy, int& ix, bool& valid) {
    float fy = rintf(((cy + 1.0f) * (float)hi - 1.0f) * 0.5f);
    float fx = rintf(((cx + 1.0f) * (float)wi - 1.0f) * 0.5f);
    valid = (fy >= 0.0f) && (fy < (float)hi) && (fx >= 0.0f) && (fx < (float)wi);
    iy = (int)fminf(fmaxf(fy, 0.0f), (float)(hi - 1));
    ix = (int)fminf(fmaxf(fx, 0.0f), (float)(wi - 1));
}

// ---- weight pre-pack: OIHW fp32 -> [conv][cout][chunk][tap][ci32] fp16 ----
__global__ __launch_bounds__(256) void pack_w(
    const float* __restrict__ src, f16* __restrict__ dst,
    int Cin, int NCHUNK, int total) {
    int i = blockIdx.x * 256 + threadIdx.x;
    if (i >= total) return;
    int ci = i & 31;
    int tap = (i >> 5) % 9;
    int q = i / 288;
    int chunk = q % NCHUNK;
    int q2 = q / NCHUNK;
    int cout = q2 & 127;
    int conv = q2 >> 7;
    int cin = chunk * 32 + ci;
    float v = (cin < Cin) ? src[((size_t)(conv * 128 + cout) * Cin + cin) * 9 + tap] : 0.f;
    dst[i] = (f16)v;
}

// concat(HR_MSI, lms) -> padded NHWC fp16 [16][66][66][64] (ch>=34 zero via memset)
__global__ __launch_bounds__(256) void build_cc(
    const float* __restrict__ msi, const float* __restrict__ lms,
    f16* __restrict__ out, int total) {
    int i = blockIdx.x * 256 + threadIdx.x;
    if (i >= total) return;
    int ch = i % 34;
    int p = i / 34;
    int x = p & 63, y = (p >> 6) & 63, b = p >> 12;
    float v = (ch < 3) ? msi[(((size_t)(b * 3 + ch) << 6) + y << 6) + x]
                       : lms[(((size_t)(b * 31 + ch - 3) << 6) + y << 6) + x];
    out[((size_t)(b * 66 + y + 1) * 66 + x + 1) * 64 + ch] = v;
}

// LR_HSI -> padded NHWC fp16 [16][18][18][32]
__global__ __launch_bounds__(256) void build_spe(
    const float* __restrict__ in, f16* __restrict__ out, int total) {
    int i = blockIdx.x * 256 + threadIdx.x;
    if (i >= total) return;
    int ch = i % 31;
    int p = i / 31;
    int x = p & 15, y = (p >> 4) & 15, b = p >> 8;
    out[((size_t)(b * 18 + y + 1) * 18 + x + 1) * 32 + ch] =
        (f16)in[(((size_t)(b * 31 + ch) << 4) + y << 4) + x];
}

// ---- implicit-GEMM conv3x3 SAME, NHWC fp16 padded in, Cout=128 ----
// mode: 0 plain->out_h, 1 relu->out_h, 2 self-add (out_h += conv), 3 tail (+skip_h -> out_f)
template<int PXW, int XSH, int ROWS>
__global__ __launch_bounds__(256) void conv_mfma(
    const f16* __restrict__ in_h, int NCHUNK,
    const f16* __restrict__ wp, const float* __restrict__ bias,
    const f16* __restrict__ skip_h, f16* __restrict__ out_h,
    float* __restrict__ out_f, int mode) {
    constexpr int XW = 1 << XSH;
    constexpr int PH = XW + 2;
    constexpr int NPX = (ROWS + 2) * PXW;
    constexpr int UNITS = NPX * 4;
    constexpr int ITER = (UNITS + 255) / 256;
    __shared__ u32x4 ldsv[UNITS];
    char* ldsb = (char*)ldsv;

    int tid = threadIdx.x;
    constexpr int NYB = XW / ROWS;
    int b = blockIdx.x / NYB;
    int y0 = (blockIdx.x % NYB) * ROWS;
    int wave = tid >> 6, lane = tid & 63;
    int wm = wave >> 1, wn = wave & 1;
    int l15 = lane & 15, lk = lane >> 4;
    int CST = NCHUNK * 32;

    int gaddr[ITER], laddr[ITER];
#pragma unroll
    for (int i = 0; i < ITER; ++i) {
        int u = tid + 256 * i;
        if (u < UNITS) {
            int px = u >> 2, kg = u & 3;
            int r = px / PXW, xp = px - r * PXW;
            gaddr[i] = ((b * PH + y0 + r) * PXW + xp) * CST + kg * 8;
            laddr[i] = (u * 16) ^ (((px >> 1) & 3) << 4);
        } else {
            gaddr[i] = -1; laddr[i] = 0;
        }
    }

    f32x4 acc[2][4];
#pragma unroll
    for (int mt = 0; mt < 2; ++mt)
#pragma unroll
        for (int nt = 0; nt < 4; ++nt)
            acc[mt][nt] = (f32x4){0.f, 0.f, 0.f, 0.f};

    u32x4 v[ITER];
#pragma unroll
    for (int i = 0; i < ITER; ++i)
        if (gaddr[i] >= 0) v[i] = *(const u32x4*)(in_h + gaddr[i]);

    for (int c = 0; c < NCHUNK; ++c) {
        if (c) __syncthreads();
#pragma unroll
        for (int i = 0; i < ITER; ++i)
            if (gaddr[i] >= 0) *(u32x4*)(ldsb + laddr[i]) = v[i];
        __syncthreads();
        if (c + 1 < NCHUNK) {
#pragma unroll
            for (int i = 0; i < ITER; ++i)
                if (gaddr[i] >= 0) v[i] = *(const u32x4*)(in_h + gaddr[i] + (c + 1) * 32);
        }
#pragma unroll
        for (int tap = 0; tap < 9; ++tap) {
            const int dy = tap / 3, dx = tap % 3;
            f16x8 afr[2];
#pragma unroll
            for (int mt = 0; mt < 2; ++mt) {
                int px = wm * 32 + mt * 16 + l15;
                int row = px >> XSH, x = px & (XW - 1);
                int pxl = (row + dy) * PXW + x + dx;
                int la = pxl * 64 + lk * 16;
                afr[mt] = *(const f16x8*)(ldsb + (la ^ (((pxl >> 1) & 3) << 4)));
            }
#pragma unroll
            for (int nt = 0; nt < 4; ++nt) {
                int cout = wn * 64 + nt * 16 + l15;
                f16x8 bfr = *(const f16x8*)(wp + ((size_t)(cout * NCHUNK + c) * 9 + tap) * 32 + lk * 8);
                acc[0][nt] = __builtin_amdgcn_mfma_f32_16x16x32_f16(afr[0], bfr, acc[0][nt], 0, 0, 0);
                acc[1][nt] = __builtin_amdgcn_mfma_f32_16x16x32_f16(afr[1], bfr, acc[1][nt], 0, 0, 0);
            }
        }
    }

#pragma unroll
    for (int mt = 0; mt < 2; ++mt)
#pragma unroll
        for (int nt = 0; nt < 4; ++nt) {
            int cout = wn * 64 + nt * 16 + l15;
            float bv = bias[cout];
#pragma unroll
            for (int reg = 0; reg < 4; ++reg) {
                int px = wm * 32 + mt * 16 + lk * 4 + reg;
                int row = px >> XSH, x = px & (XW - 1);
                int yim = y0 + row;
                float vv = acc[mt][nt][reg] + bv;
                size_t ah = ((size_t)(b * PH + yim + 1) * PXW + x + 1) * 128 + cout;
                if (mode == 1) vv = fmaxf(vv, 0.f);
                if (mode == 2) vv += (float)out_h[ah];
                if (mode == 3) {
                    vv += (float)skip_h[ah];
                    out_f[((size_t)((b << XSH) + yim) << XSH | x) * 128 + cout] = vv;
                } else {
                    out_h[ah] = (f16)vv;
                }
            }
        }
}

// max pool kxk stride k on NHWC (C=128)
__global__ __launch_bounds__(256) void maxpool_nhwc(
    const float* __restrict__ in, float* __restrict__ out,
    int H, int W, int k, int total) {
    int i = blockIdx.x * 256 + threadIdx.x;
    if (i >= total) return;
    int c = i & 127;
    int r = i >> 7;
    int Wo = W / k, Ho = H / k;
    int x = r % Wo; r /= Wo;
    int y = r % Ho;
    int b = r / Ho;
    float m = -3.402823466e38f;
    for (int dy = 0; dy < k; ++dy)
        for (int dx = 0; dx < k; ++dx)
            m = fmaxf(m, in[((size_t)(b * H + y * k + dy) * W + x * k + dx) * 128 + c]);
    out[i] = m;
}

// Fused level(): 8 queries per block (one batch). NHWC feature inputs.
__global__ __launch_bounds__(256) void level_kernel(
    const float* __restrict__ featT, int fh, int fw,
    const float* __restrict__ guideT, int Hg, int Wg,
    const float* __restrict__ glrT, int hl, int wl,
    int Hq, int Wq, int n_per_b,
    const float* __restrict__ imw, const float* __restrict__ imb,
    const float* __restrict__ w1, const float* __restrict__ b1,
    const float* __restrict__ w2, const float* __restrict__ b2,
    const float* __restrict__ f1, const float* __restrict__ fb1,
    const float* __restrict__ f2, const float* __restrict__ fb2,
    int odim, int residual, int out_nchw,
    const float* __restrict__ lms,
    float* __restrict__ out) {
    __shared__ float s_preds[64 * 130];
    __shared__ float s_scr[64 * 66];
    __shared__ float s_gr[8 * 128];
    __shared__ float s_h[8 * 64];

    int tid = threadIdx.x;
    int b = blockIdx.x / n_per_b;
    int n0 = (blockIdx.x % n_per_b) * 8;
    float invHq = 1.0f / (float)Hq, invWq = 1.0f / (float)Wq;
    float invfh = 1.0f / (float)fh, invfw = 1.0f / (float)fw;
    int wave = tid >> 6, lane = tid & 63;

    for (int it = 0; it < 4; ++it) {
        int q = it * 2 + (tid >> 7);
        int d = tid & 127;
        int n = n0 + q;
        int qy = n / Wq, qx = n - qy * Wq;
        float cy = -1.0f + (float)(2 * qy + 1) * invHq;
        float cx = -1.0f + (float)(2 * qx + 1) * invWq;
        int iy, ix; bool v;
        nsamp(cy, cx, Hg, Wg, iy, ix, v);
        s_gr[q * 128 + d] = v ? guideT[((size_t)(b * Hg + iy) * Wg + ix) * 128 + d] : 0.0f;
    }
    __syncthreads();

    float* s_inp = s_scr;
    for (int cidx = 0; cidx < 4; ++cidx) {
        float vx = (cidx < 2) ? -1.0f : 1.0f;
        float vy = (cidx & 1) ? 1.0f : -1.0f;
        for (int it = 0; it < 4; ++it) {
            int q = it * 2 + (tid >> 7);
            int d = tid & 127;
            int n = n0 + q;
            int qy = n / Wq, qx = n - qy * Wq;
            float cy = -1.0f + (float)(2 * qy + 1) * invHq;
            float cx = -1.0f + (float)(2 * qx + 1) * invWq;
            float cy_ = cy + vx * invfh;
            float cx_ = cx + vy * invfw;
            int iy, ix; bool vf;
            nsamp(cy_, cx_, fh, fw, iy, ix, vf);
            s_inp[q * 388 + d] = vf ? featT[((size_t)(b * fh + iy) * fw + ix) * 128 + d] : 0.0f;
            s_inp[q * 388 + 128 + d] = s_gr[q * 128 + d];
            int iy2, ix2; bool vg;
            nsamp(cy_, cx_, hl, wl, iy2, ix2, vg);
            s_inp[q * 388 + 256 + d] = vg ? glrT[((size_t)(b * hl + iy2) * wl + ix2) * 128 + d] : 0.0f;
            if (d == 0) {
                float csy = vf ? (-1.0f + (float)(2 * iy + 1) * invfh) : 0.0f;
                float csx = vf ? (-1.0f + (float)(2 * ix + 1) * invfw) : 0.0f;
                s_inp[q * 388 + 384] = (cy - csy) * (float)fh;
                s_inp[q * 388 + 385] = (cx - csx) * (float)fw;
            }
        }
        __syncthreads();
        float acc[8][4];
#pragma unroll
        for (int q = 0; q < 8; ++q) {
            acc[q][0] = acc[q][1] = acc[q][2] = acc[q][3] = 0.f;
        }
        int k0 = wave * 96 + (wave < 2 ? wave : 2);
        int klen = (wave < 2) ? 97 : 96;
        const float4* imw4 = (const float4*)imw;
        for (int k = k0; k < k0 + klen; ++k) {
            float4 wv = imw4[k * 64 + lane];
#pragma unroll
            for (int q = 0; q < 8; ++q) {
                float a = s_inp[q * 388 + k];
                acc[q][0] += a * wv.x;
                acc[q][1] += a * wv.y;
                acc[q][2] += a * wv.z;
                acc[q][3] += a * wv.w;
            }
        }
        int j0 = cidx * 2;
        for (int wr = 0; wr < 4; ++wr) {
            if (wave == wr) {
#pragma unroll
                for (int q = 0; q < 8; ++q)
#pragma unroll
                    for (int i = 0; i < 4; ++i) {
                        int c = lane * 4 + i;
                        int idx = (q * 8 + j0 + (c >> 7)) * 130 + (c & 127);
                        if (wr == 0) s_preds[idx] = acc[q][i];
                        else s_preds[idx] += acc[q][i];
                    }
            }
            __syncthreads();
        }
        for (int i = tid; i < 2048; i += 256) {
            int q = i >> 8, c = i & 255;
            int idx = (q * 8 + j0 + (c >> 7)) * 130 + (c & 127);
            s_preds[idx] = fmaxf(s_preds[idx] + imb[c], 0.0f);
        }
        __syncthreads();
    }

    {
        int g = tid >> 4;
        int c0q = tid & 15;
        float a1[4][4];
#pragma unroll
        for (int p = 0; p < 4; ++p) {
            a1[p][0] = a1[p][1] = a1[p][2] = a1[p][3] = 0.f;
        }
        const float4* w14 = (const float4*)w1;
        for (int k = 0; k < 128; ++k) {
            float4 wv = w14[k * 16 + c0q];
#pragma unroll
            for (int p = 0; p < 4; ++p) {
                float pv = s_preds[(g + p * 16) * 130 + k];
                a1[p][0] += pv * wv.x; a1[p][1] += pv * wv.y;
                a1[p][2] += pv * wv.z; a1[p][3] += pv * wv.w;
            }
        }
#pragma unroll
        for (int p = 0; p < 4; ++p)
#pragma unroll
            for (int i = 0; i < 4; ++i) {
                float xx = a1[p][i] + b1[c0q * 4 + i];
                s_scr[(g + p * 16) * 66 + c0q * 4 + i] = gelu_f(xx);
            }
    }
    __syncthreads();

    {
        int q = tid >> 5;
        int d0 = (tid & 31) * 4;
        float wv[8][4];
#pragma unroll
        for (int j = 0; j < 8; ++j) {
            wv[j][0] = wv[j][1] = wv[j][2] = wv[j][3] = 0.f;
        }
        const float4* w24 = (const float4*)w2;
        for (int k = 0; k < 64; ++k) {
            float4 w2v = w24[k * 32 + (tid & 31)];
#pragma unroll
            for (int j = 0; j < 8; ++j) {
                float h1v = s_scr[(q * 8 + j) * 66 + k];
                wv[j][0] += h1v * w2v.x; wv[j][1] += h1v * w2v.y;
                wv[j][2] += h1v * w2v.z; wv[j][3] += h1v * w2v.w;
            }
        }
        float4 b2v = *(const float4*)&b2[d0];
        float bb[4] = {b2v.x, b2v.y, b2v.z, b2v.w};
#pragma unroll
        for (int i = 0; i < 4; ++i) {
            float m = -3.4e38f;
#pragma unroll
            for (int j = 0; j < 8; ++j) {
                wv[j][i] += bb[i];
                m = fmaxf(m, wv[j][i]);
            }
            float s = 0.f;
#pragma unroll
            for (int j = 0; j < 8; ++j) {
                wv[j][i] = __expf(wv[j][i] - m);
                s += wv[j][i];
            }
            float inv = 1.0f / s;
            float rec = 0.f;
#pragma unroll
            for (int j = 0; j < 8; ++j)
                rec += s_preds[(q * 8 + j) * 130 + d0 + i] * wv[j][i];
            s_gr[q * 128 + d0 + i] = rec * inv;
        }
    }
    __syncthreads();

    for (int p = 0; p < 2; ++p) {
        int q = p * 4 + (tid >> 6);
        int c = tid & 63;
        float a = 0.f;
        for (int k = 0; k < 128; ++k)
            a += s_gr[q * 128 + k] * f1[k * 64 + c];
        s_h[q * 64 + c] = gelu_f(a + fb1[c]);
    }
    __syncthreads();

    if (!out_nchw) {
        for (int it = 0; it < 4; ++it) {
            int q = it * 2 + (tid >> 7);
            int d = tid & 127;
            int n = n0 + q;
            int qy = n / Wq, qx = n - qy * Wq;
            float a = 0.f;
            for (int k = 0; k < 64; ++k)
                a += s_h[q * 64 + k] * f2[k * 128 + d];
            a += fb2[d];
            if (residual) a += s_gr[q * 128 + d];
            out[((size_t)(b * Hq + qy) * Wq + qx) * 128 + d] = a;
        }
    } else {
        if (tid < 8 * odim) {
            int q = tid / odim, d = tid - q * odim;
            int n = n0 + q;
            int qy = n / Wq, qx = n - qy * Wq;
            float a = 0.f;
            for (int k = 0; k < 64; ++k)
                a += s_h[q * 64 + k] * f2[k * odim + d];
            a += fb2[d];
            if (lms) a += lms[(((size_t)b * odim + d) * Hq + qy) * Wq + qx];
            out[(((size_t)b * odim + d) * Hq + qy) * Wq + qx] = a;
        }
    }
}

// ---- workspace byte offsets ----
#define WPACK_B   0ull
#define CC_B      5529600ull
#define SPEIN_B   (CC_B)
#define X2_B      (CC_B + 331776ull)
#define R2_B      (CC_B + 1658880ull)
#define T2_B      (CC_B + 2985984ull)
#define LRSPE_B   (CC_B + 4313088ull)
#define RH_B      14450688ull
#define TH_B      32292864ull
#define XH_B      50135040ull
#define G32_B     (TH_B)
#define G16_B     (TH_B + 8388608ull)
#define L1T_B     (TH_B + 10485760ull)
#define HR32_B    67977216ull

extern "C" void kernel_launch(void* const* d_in, const int* in_sizes, int n_in,
                              void* d_out, int out_size, void* d_ws, size_t ws_size,
                              hipStream_t stream) {
    (void)in_sizes; (void)n_in; (void)out_size; (void)ws_size;
    const float* HR_MSI     = (const float*)d_in[0];
    const float* lms        = (const float*)d_in[1];
    const float* LR_HSI     = (const float*)d_in[2];
    const float* spa_head_w = (const float*)d_in[3];
    const float* spa_head_b = (const float*)d_in[4];
    const float* spa_res_w  = (const float*)d_in[5];
    const float* spa_res_b  = (const float*)d_in[6];
    const float* spa_tail_w = (const float*)d_in[7];
    const float* spa_tail_b = (const float*)d_in[8];
    const float* spe_head_w = (const float*)d_in[9];
    const float* spe_head_b = (const float*)d_in[10];
    const float* spe_res_w  = (const float*)d_in[11];
    const float* spe_res_b  = (const float*)d_in[12];
    const float* spe_tail_w = (const float*)d_in[13];
    const float* spe_tail_b = (const float*)d_in[14];
    const float* l1_w   = (const float*)d_in[15];
    const float* l1_b   = (const float*)d_in[16];
    const float* wg32_w1 = (const float*)d_in[17];
    const float* wg32_b1 = (const float*)d_in[18];
    const float* wg32_w2 = (const float*)d_in[19];
    const float* wg32_b2 = (const float*)d_in[20];
    const float* ffn32_w1 = (const float*)d_in[21];
    const float* ffn32_b1 = (const float*)d_in[22];
    const float* ffn32_w2 = (const float*)d_in[23];
    const float* ffn32_b2 = (const float*)d_in[24];
    const float* l2_w   = (const float*)d_in[25];
    const float* l2_b   = (const float*)d_in[26];
    const float* wg64_w1 = (const float*)d_in[27];
    const float* wg64_b1 = (const float*)d_in[28];
    const float* wg64_w2 = (const float*)d_in[29];
    const float* wg64_b2 = (const float*)d_in[30];
    const float* ffn64_w1 = (const float*)d_in[31];
    const float* ffn64_b1 = (const float*)d_in[32];
    const float* ffn64_w2 = (const float*)d_in[33];
    const float* ffn64_b2 = (const float*)d_in[34];

    char* ws = (char*)d_ws;
    f16* Wp     = (f16*)(ws + WPACK_B);
    f16* Cc     = (f16*)(ws + CC_B);
    f16* SPEin  = (f16*)(ws + SPEIN_B);
    f16* X2h    = (f16*)(ws + X2_B);
    f16* R2h    = (f16*)(ws + R2_B);
    f16* T2h    = (f16*)(ws + T2_B);
    float* lrspe32 = (float*)(ws + LRSPE_B);
    f16* Rh     = (f16*)(ws + RH_B);
    f16* Th     = (f16*)(ws + TH_B);
    f16* Xh     = (f16*)(ws + XH_B);
    float* g32T = (float*)(ws + G32_B);
    float* g16T = (float*)(ws + G16_B);
    float* l1T  = (float*)(ws + L1T_B);
    float* hr32 = (float*)(ws + HR32_B);

    // zero padded fp16 regions (borders must be 0; harness poisons ws once)
    hipMemsetAsync(ws + CC_B, 0, 8921088ull, stream);
    hipMemsetAsync(ws + RH_B, 0, 53526528ull, stream);

    // pack weights to fp16 GEMM layout
    pack_w<<<288, 256, 0, stream>>>(spa_head_w, Wp + 0, 34, 2, 73728);
    pack_w<<<4608, 256, 0, stream>>>(spa_res_w, Wp + 73728, 128, 4, 1179648);
    pack_w<<<576, 256, 0, stream>>>(spa_tail_w, Wp + 1253376, 128, 4, 147456);
    pack_w<<<144, 256, 0, stream>>>(spe_head_w, Wp + 1400832, 31, 1, 36864);
    pack_w<<<4608, 256, 0, stream>>>(spe_res_w, Wp + 1437696, 128, 4, 1179648);
    pack_w<<<576, 256, 0, stream>>>(spe_tail_w, Wp + 2617344, 128, 4, 147456);

    // ---- spatial EDSR ----
    build_cc<<<8704, 256, 0, stream>>>(HR_MSI, lms, Cc, 16 * 64 * 64 * 34);
    conv_mfma<66, 6, 1><<<1024, 256, 0, stream>>>(Cc, 2, Wp + 0, spa_head_b,
                                                  nullptr, Xh, nullptr, 0);
    // CC region free now: zero spe sub-buffers (borders)
    hipMemsetAsync(ws + SPEIN_B, 0, 4313088ull, stream);
    hipMemcpyAsync(Rh, Xh, 17842176ull, hipMemcpyDeviceToDevice, stream);
    for (int i = 0; i < 4; ++i) {
        conv_mfma<66, 6, 1><<<1024, 256, 0, stream>>>(
            Rh, 4, Wp + 73728 + (size_t)(2 * i) * 147456, spa_res_b + 2 * i * 128,
            nullptr, Th, nullptr, 1);
        conv_mfma<66, 6, 1><<<1024, 256, 0, stream>>>(
            Th, 4, Wp + 73728 + (size_t)(2 * i + 1) * 147456, spa_res_b + (2 * i + 1) * 128,
            nullptr, Rh, nullptr, 2);
    }
    conv_mfma<66, 6, 1><<<1024, 256, 0, stream>>>(Rh, 4, Wp + 1253376, spa_tail_b,
                                                  Xh, nullptr, hr32, 3);
    maxpool_nhwc<<<8192, 256, 0, stream>>>(hr32, g32T, 64, 64, 2, 2097152);
    maxpool_nhwc<<<2048, 256, 0, stream>>>(hr32, g16T, 64, 64, 4, 524288);

    // ---- spectral EDSR ----
    build_spe<<<496, 256, 0, stream>>>(LR_HSI, SPEin, 16 * 16 * 16 * 31);
    conv_mfma<18, 4, 4><<<64, 256, 0, stream>>>(SPEin, 1, Wp + 1400832, spe_head_b,
                                                nullptr, X2h, nullptr, 0);
    hipMemcpyAsync(R2h, X2h, 1327104ull, hipMemcpyDeviceToDevice, stream);
    for (int i = 0; i < 4; ++i) {
        conv_mfma<18, 4, 4><<<64, 256, 0, stream>>>(
            R2h, 4, Wp + 1437696 + (size_t)(2 * i) * 147456, spe_res_b + 2 * i * 128,
            nullptr, T2h, nullptr, 1);
        conv_mfma<18, 4, 4><<<64, 256, 0, stream>>>(
            T2h, 4, Wp + 1437696 + (size_t)(2 * i + 1) * 147456, spe_res_b + (2 * i + 1) * 128,
            nullptr, R2h, nullptr, 2);
    }
    conv_mfma<18, 4, 4><<<64, 256, 0, stream>>>(R2h, 4, Wp + 2617344, spe_tail_b,
                                                X2h, nullptr, lrspe32, 3);

    // ---- level 1: 32x32 queries ----
    level_kernel<<<2048, 256, 0, stream>>>(
        lrspe32, 16, 16, g32T, 32, 32, g16T, 16, 16,
        32, 32, 128,
        l1_w, l1_b, wg32_w1, wg32_b1, wg32_w2, wg32_b2,
        ffn32_w1, ffn32_b1, ffn32_w2, ffn32_b2,
        128, 1, 0, nullptr, l1T);

    // ---- level 2: 64x64 queries, + lms, NCHW to d_out ----
    level_kernel<<<8192, 256, 0, stream>>>(
        l1T, 32, 32, hr32, 64, 64, g32T, 32, 32,
        64, 64, 512,
        l2_w, l2_b, wg64_w1, wg64_b1, wg64_w2, wg64_b2,
        ffn64_w1, ffn64_b1, ffn64_w2, ffn64_b2,
        31, 0, 1, lms, (float*)d_out);
}

// Round 4
// 1783.636 us; speedup vs baseline: 4.8512x; 1.9163x over previous
//
#include <hip/hip_runtime.h>
#include <math.h>

typedef _Float16 f16;
typedef __attribute__((ext_vector_type(4))) _Float16 f16x4;
typedef __attribute__((ext_vector_type(8))) _Float16 f16x8;
typedef __attribute__((ext_vector_type(4))) float f32x4;
typedef __attribute__((ext_vector_type(4))) unsigned int u32x4;

__device__ __forceinline__ float gelu_f(float x) {
    return 0.5f * x * (1.0f + erff(x * 0.70710678118654752440f));
}

__device__ __forceinline__ void nsamp(float cy, float cx, int hi, int wi,
                                      int& iy, int& ix, bool& valid) {
    float fy = rintf(((cy + 1.0f) * (float)hi - 1.0f) * 0.5f);
    float fx = rintf(((cx + 1.0f) * (float)wi - 1.0f) * 0.5f);
    valid = (fy >= 0.0f) && (fy < (float)hi) && (fx >= 0.0f) && (fx < (float)wi);
    iy = (int)fminf(fmaxf(fy, 0.0f), (float)(hi - 1));
    ix = (int)fminf(fmaxf(fx, 0.0f), (float)(wi - 1));
}

// ---- conv weight pre-pack: OIHW fp32 -> [conv][cout][chunk][tap][ci32] fp16 ----
__global__ __launch_bounds__(256) void pack_w(
    const float* __restrict__ src, f16* __restrict__ dst,
    int Cin, int NCHUNK, int total) {
    int i = blockIdx.x * 256 + threadIdx.x;
    if (i >= total) return;
    int ci = i & 31;
    int tap = (i >> 5) % 9;
    int q = i / 288;
    int chunk = q % NCHUNK;
    int q2 = q / NCHUNK;
    int cout = q2 & 127;
    int conv = q2 >> 7;
    int cin = chunk * 32 + ci;
    float v = (cin < Cin) ? src[((size_t)(conv * 128 + cout) * Cin + cin) * 9 + tap] : 0.f;
    dst[i] = (f16)v;
}

// ---- level MLP weight pack: src fp32 [K][N] -> dst fp16 [N][NC][32] ----
__global__ __launch_bounds__(256) void pack_lvl(
    const float* __restrict__ src, f16* __restrict__ dst,
    int Ksrc, int N, int NC) {
    int i = blockIdx.x * 256 + threadIdx.x;
    if (i >= N * NC * 32) return;
    int kk = i & 31;
    int c = (i >> 5) % NC;
    int n = i / (32 * NC);
    int k = c * 32 + kk;
    dst[i] = (f16)((k < Ksrc) ? src[(size_t)k * N + n] : 0.f);
}

// concat(HR_MSI, lms) -> padded NHWC fp16 [16][66][66][64]
__global__ __launch_bounds__(256) void build_cc(
    const float* __restrict__ msi, const float* __restrict__ lms,
    f16* __restrict__ out, int total) {
    int i = blockIdx.x * 256 + threadIdx.x;
    if (i >= total) return;
    int ch = i % 34;
    int p = i / 34;
    int x = p & 63, y = (p >> 6) & 63, b = p >> 12;
    float v = (ch < 3) ? msi[(((size_t)(b * 3 + ch) << 6) + y << 6) + x]
                       : lms[(((size_t)(b * 31 + ch - 3) << 6) + y << 6) + x];
    out[((size_t)(b * 66 + y + 1) * 66 + x + 1) * 64 + ch] = v;
}

// LR_HSI -> padded NHWC fp16 [16][18][18][32]
__global__ __launch_bounds__(256) void build_spe(
    const float* __restrict__ in, f16* __restrict__ out, int total) {
    int i = blockIdx.x * 256 + threadIdx.x;
    if (i >= total) return;
    int ch = i % 31;
    int p = i / 31;
    int x = p & 15, y = (p >> 4) & 15, b = p >> 8;
    out[((size_t)(b * 18 + y + 1) * 18 + x + 1) * 32 + ch] =
        (f16)in[(((size_t)(b * 31 + ch) << 4) + y << 4) + x];
}

// ---- implicit-GEMM conv3x3 SAME, NHWC fp16 padded in, Cout=128 ----
template<int PXW, int XSH, int ROWS>
__global__ __launch_bounds__(256) void conv_mfma(
    const f16* __restrict__ in_h, int NCHUNK,
    const f16* __restrict__ wp, const float* __restrict__ bias,
    const f16* __restrict__ skip_h, f16* __restrict__ out_h,
    float* __restrict__ out_f, int mode) {
    constexpr int XW = 1 << XSH;
    constexpr int PH = XW + 2;
    constexpr int NPX = (ROWS + 2) * PXW;
    constexpr int UNITS = NPX * 4;
    constexpr int ITER = (UNITS + 255) / 256;
    __shared__ u32x4 ldsv[UNITS];
    char* ldsb = (char*)ldsv;

    int tid = threadIdx.x;
    constexpr int NYB = XW / ROWS;
    int b = blockIdx.x / NYB;
    int y0 = (blockIdx.x % NYB) * ROWS;
    int wave = tid >> 6, lane = tid & 63;
    int wm = wave >> 1, wn = wave & 1;
    int l15 = lane & 15, lk = lane >> 4;
    int CST = NCHUNK * 32;

    int gaddr[ITER], laddr[ITER];
#pragma unroll
    for (int i = 0; i < ITER; ++i) {
        int u = tid + 256 * i;
        if (u < UNITS) {
            int px = u >> 2, kg = u & 3;
            int r = px / PXW, xp = px - r * PXW;
            gaddr[i] = ((b * PH + y0 + r) * PXW + xp) * CST + kg * 8;
            laddr[i] = (u * 16) ^ (((px >> 1) & 3) << 4);
        } else {
            gaddr[i] = -1; laddr[i] = 0;
        }
    }

    f32x4 acc[2][4];
#pragma unroll
    for (int mt = 0; mt < 2; ++mt)
#pragma unroll
        for (int nt = 0; nt < 4; ++nt)
            acc[mt][nt] = (f32x4){0.f, 0.f, 0.f, 0.f};

    u32x4 v[ITER];
#pragma unroll
    for (int i = 0; i < ITER; ++i)
        if (gaddr[i] >= 0) v[i] = *(const u32x4*)(in_h + gaddr[i]);

    for (int c = 0; c < NCHUNK; ++c) {
        if (c) __syncthreads();
#pragma unroll
        for (int i = 0; i < ITER; ++i)
            if (gaddr[i] >= 0) *(u32x4*)(ldsb + laddr[i]) = v[i];
        __syncthreads();
        if (c + 1 < NCHUNK) {
#pragma unroll
            for (int i = 0; i < ITER; ++i)
                if (gaddr[i] >= 0) v[i] = *(const u32x4*)(in_h + gaddr[i] + (c + 1) * 32);
        }
#pragma unroll
        for (int tap = 0; tap < 9; ++tap) {
            const int dy = tap / 3, dx = tap % 3;
            f16x8 afr[2];
#pragma unroll
            for (int mt = 0; mt < 2; ++mt) {
                int px = wm * 32 + mt * 16 + l15;
                int row = px >> XSH, x = px & (XW - 1);
                int pxl = (row + dy) * PXW + x + dx;
                int la = pxl * 64 + lk * 16;
                afr[mt] = *(const f16x8*)(ldsb + (la ^ (((pxl >> 1) & 3) << 4)));
            }
#pragma unroll
            for (int nt = 0; nt < 4; ++nt) {
                int cout = wn * 64 + nt * 16 + l15;
                f16x8 bfr = *(const f16x8*)(wp + ((size_t)(cout * NCHUNK + c) * 9 + tap) * 32 + lk * 8);
                acc[0][nt] = __builtin_amdgcn_mfma_f32_16x16x32_f16(afr[0], bfr, acc[0][nt], 0, 0, 0);
                acc[1][nt] = __builtin_amdgcn_mfma_f32_16x16x32_f16(afr[1], bfr, acc[1][nt], 0, 0, 0);
            }
        }
    }

#pragma unroll
    for (int mt = 0; mt < 2; ++mt)
#pragma unroll
        for (int nt = 0; nt < 4; ++nt) {
            int cout = wn * 64 + nt * 16 + l15;
            float bv = bias[cout];
#pragma unroll
            for (int reg = 0; reg < 4; ++reg) {
                int px = wm * 32 + mt * 16 + lk * 4 + reg;
                int row = px >> XSH, x = px & (XW - 1);
                int yim = y0 + row;
                float vv = acc[mt][nt][reg] + bv;
                size_t ah = ((size_t)(b * PH + yim + 1) * PXW + x + 1) * 128 + cout;
                if (mode == 1) vv = fmaxf(vv, 0.f);
                if (mode == 2) vv += (float)out_h[ah];
                if (mode == 3) {
                    vv += (float)skip_h[ah];
                    out_f[((size_t)((b << XSH) + yim) << XSH | x) * 128 + cout] = vv;
                } else {
                    out_h[ah] = (f16)vv;
                }
            }
        }
}

// max pool kxk stride k on NHWC (C=128)
__global__ __launch_bounds__(256) void maxpool_nhwc(
    const float* __restrict__ in, float* __restrict__ out,
    int H, int W, int k, int total) {
    int i = blockIdx.x * 256 + threadIdx.x;
    if (i >= total) return;
    int c = i & 127;
    int r = i >> 7;
    int Wo = W / k, Ho = H / k;
    int x = r % Wo; r /= Wo;
    int y = r % Ho;
    int b = r / Ho;
    float m = -3.402823466e38f;
    for (int dy = 0; dy < k; ++dy)
        for (int dx = 0; dx < k; ++dx)
            m = fmaxf(m, in[((size_t)(b * H + y * k + dy) * W + x * k + dx) * 128 + c]);
    out[i] = m;
}

// ---- Fused level(), MFMA version. 8 queries/block, 256 threads. ----
__global__ __launch_bounds__(256) void level_kernel(
    const float* __restrict__ featT, int fh, int fw,
    const float* __restrict__ guideT, int Hg, int Wg,
    const float* __restrict__ glrT, int hl, int wl,
    int Hq, int Wq, int n_per_b,
    const f16* __restrict__ imw_h, const float* __restrict__ imb,
    const f16* __restrict__ w1h, const float* __restrict__ b1,
    const f16* __restrict__ w2h, const float* __restrict__ b2,
    const float* __restrict__ f1, const float* __restrict__ fb1,
    const float* __restrict__ f2, const float* __restrict__ fb2,
    int odim, int residual, int out_nchw,
    const float* __restrict__ lms,
    float* __restrict__ out) {
    __shared__ f16 s_inp[32 * 424];   // corner-GEMM A tile; later h1 overlay [64*72]
    __shared__ f16 s_pred[64 * 136];  // preds fp16 [qj][128] stride 136
    __shared__ float s_gr[8 * 128];   // recon fp32
    __shared__ float s_h[8 * 64];     // ffn hidden fp32

    int tid = threadIdx.x;
    int b = blockIdx.x / n_per_b;
    int n0 = (blockIdx.x % n_per_b) * 8;
    float invHq = 1.0f / (float)Hq, invWq = 1.0f / (float)Wq;
    float invfh = 1.0f / (float)fh, invfw = 1.0f / (float)fw;
    int wave = tid >> 6, lane = tid & 63;
    int l15 = lane & 15, lk = lane >> 4;

    // ---- gather: build s_inp[32][424] fp16 ----
    {
        const int r32 = tid >> 3, t8 = tid & 7;
        const int cidx = r32 >> 3, q = r32 & 7;
        int n = n0 + q;
        int qy = n / Wq, qx = n - qy * Wq;
        float cy = -1.0f + (float)(2 * qy + 1) * invHq;
        float cx = -1.0f + (float)(2 * qx + 1) * invWq;
        float vxc = (cidx < 2) ? -1.0f : 1.0f;
        float vyc = (cidx & 1) ? 1.0f : -1.0f;
        float cy_ = cy + vxc * invfh;
        float cx_ = cx + vyc * invfw;
        int iy, ix; bool vf;
        nsamp(cy_, cx_, fh, fw, iy, ix, vf);
        const float* fp = featT + ((size_t)(b * fh + iy) * fw + ix) * 128;
        int gy, gx; bool vg0;
        nsamp(cy, cx, Hg, Wg, gy, gx, vg0);
        const float* gp = guideT + ((size_t)(b * Hg + gy) * Wg + gx) * 128;
        int ly, lx; bool vl;
        nsamp(cy_, cx_, hl, wl, ly, lx, vl);
        const float* lp = glrT + ((size_t)(b * hl + ly) * wl + lx) * 128;
        f16* row = s_inp + r32 * 424;
#pragma unroll
        for (int e = 0; e < 4; ++e) {
            int d = t8 * 16 + e * 4;
            float4 a = vf ? *(const float4*)(fp + d) : make_float4(0.f, 0.f, 0.f, 0.f);
            float4 g = vg0 ? *(const float4*)(gp + d) : make_float4(0.f, 0.f, 0.f, 0.f);
            float4 l = vl ? *(const float4*)(lp + d) : make_float4(0.f, 0.f, 0.f, 0.f);
            *(f16x4*)(row + d)       = (f16x4){(f16)a.x, (f16)a.y, (f16)a.z, (f16)a.w};
            *(f16x4*)(row + 128 + d) = (f16x4){(f16)g.x, (f16)g.y, (f16)g.z, (f16)g.w};
            *(f16x4*)(row + 256 + d) = (f16x4){(f16)l.x, (f16)l.y, (f16)l.z, (f16)l.w};
        }
        if (t8 == 0) {
#pragma unroll
            for (int e = 0; e < 4; ++e)
                *(u32x4*)((char*)row + 768 + e * 16) = (u32x4){0, 0, 0, 0};
            float csy = vf ? (-1.0f + (float)(2 * iy + 1) * invfh) : 0.0f;
            float csx = vf ? (-1.0f + (float)(2 * ix + 1) * invfw) : 0.0f;
            row[384] = (f16)((cy - csy) * (float)fh);
            row[385] = (f16)((cx - csx) * (float)fw);
        }
    }
    __syncthreads();

    // ---- corner GEMM: 32x416 @ 416x256 ----
    {
        f32x4 acc[2][4];
#pragma unroll
        for (int mt = 0; mt < 2; ++mt)
#pragma unroll
            for (int nt = 0; nt < 4; ++nt)
                acc[mt][nt] = (f32x4){0.f, 0.f, 0.f, 0.f};
        int nbase = wave * 64;
#pragma unroll
        for (int ks = 0; ks < 13; ++ks) {
            f16x8 afr[2];
#pragma unroll
            for (int mt = 0; mt < 2; ++mt)
                afr[mt] = *(const f16x8*)((char*)s_inp + (mt * 16 + l15) * 848 + ks * 64 + lk * 16);
#pragma unroll
            for (int nt = 0; nt < 4; ++nt) {
                f16x8 bfr = *(const f16x8*)(imw_h + ((size_t)(nbase + nt * 16 + l15) * 13 + ks) * 32 + lk * 8);
                acc[0][nt] = __builtin_amdgcn_mfma_f32_16x16x32_f16(afr[0], bfr, acc[0][nt], 0, 0, 0);
                acc[1][nt] = __builtin_amdgcn_mfma_f32_16x16x32_f16(afr[1], bfr, acc[1][nt], 0, 0, 0);
            }
        }
#pragma unroll
        for (int nt = 0; nt < 4; ++nt) {
            int col = nbase + nt * 16 + l15;
            float bv = imb[col];
            int j_hi = col >> 7, d = col & 127;
#pragma unroll
            for (int mt = 0; mt < 2; ++mt)
#pragma unroll
                for (int reg = 0; reg < 4; ++reg) {
                    int row32 = mt * 16 + lk * 4 + reg;
                    int q = row32 & 7, cidx = row32 >> 3;
                    int qj = q * 8 + cidx * 2 + j_hi;
                    s_pred[qj * 136 + d] = (f16)fmaxf(acc[mt][nt][reg] + bv, 0.f);
                }
        }
    }
    __syncthreads();

    // ---- wg1: preds[64][128] @ w1[128][64] -> h1 fp16 (overlay s_inp) ----
    f16* s_h1 = s_inp;
    {
        f32x4 a1[4];
#pragma unroll
        for (int mt = 0; mt < 4; ++mt) a1[mt] = (f32x4){0.f, 0.f, 0.f, 0.f};
        int c1 = wave * 16 + l15;
#pragma unroll
        for (int ks = 0; ks < 4; ++ks) {
            f16x8 bfr = *(const f16x8*)(w1h + ((size_t)c1 * 4 + ks) * 32 + lk * 8);
#pragma unroll
            for (int mt = 0; mt < 4; ++mt) {
                f16x8 afr = *(const f16x8*)((char*)s_pred + (mt * 16 + l15) * 272 + ks * 64 + lk * 16);
                a1[mt] = __builtin_amdgcn_mfma_f32_16x16x32_f16(afr, bfr, a1[mt], 0, 0, 0);
            }
        }
        __syncthreads();  // all corner-GEMM s_inp reads done before overlay write
        float bb1 = b1[c1];
#pragma unroll
        for (int mt = 0; mt < 4; ++mt)
#pragma unroll
            for (int reg = 0; reg < 4; ++reg) {
                int row = mt * 16 + lk * 4 + reg;
                s_h1[row * 72 + c1] = (f16)gelu_f(a1[mt][reg] + bb1);
            }
    }
    __syncthreads();

    // ---- wg2 + softmax over j + recon ----
    {
        f32x4 a2[4][2];
#pragma unroll
        for (int mt = 0; mt < 4; ++mt) {
            a2[mt][0] = (f32x4){0.f, 0.f, 0.f, 0.f};
            a2[mt][1] = (f32x4){0.f, 0.f, 0.f, 0.f};
        }
#pragma unroll
        for (int ks = 0; ks < 2; ++ks) {
            f16x8 afr[4];
#pragma unroll
            for (int mt = 0; mt < 4; ++mt)
                afr[mt] = *(const f16x8*)((char*)s_h1 + (mt * 16 + l15) * 144 + ks * 64 + lk * 16);
#pragma unroll
            for (int nt = 0; nt < 2; ++nt) {
                int c2 = wave * 32 + nt * 16 + l15;
                f16x8 bfr = *(const f16x8*)(w2h + ((size_t)c2 * 2 + ks) * 32 + lk * 8);
#pragma unroll
                for (int mt = 0; mt < 4; ++mt)
                    a2[mt][nt] = __builtin_amdgcn_mfma_f32_16x16x32_f16(afr[mt], bfr, a2[mt][nt], 0, 0, 0);
            }
        }
        int qhalf = lk >> 1;
#pragma unroll
        for (int nt = 0; nt < 2; ++nt) {
            int col = wave * 32 + nt * 16 + l15;
            float bb2 = b2[col];
#pragma unroll
            for (int mt = 0; mt < 4; ++mt) {
                int q = mt * 2 + qhalf;
                float v[4];
                float mloc = -3.4e38f;
#pragma unroll
                for (int reg = 0; reg < 4; ++reg) {
                    v[reg] = a2[mt][nt][reg] + bb2;
                    mloc = fmaxf(mloc, v[reg]);
                }
                float mf = fmaxf(mloc, __shfl_xor(mloc, 16));
                float e[4], sl = 0.f;
#pragma unroll
                for (int reg = 0; reg < 4; ++reg) {
                    e[reg] = __expf(v[reg] - mf);
                    sl += e[reg];
                }
                float sf = sl + __shfl_xor(sl, 16);
                float inv = 1.0f / sf;
                float rp = 0.f;
#pragma unroll
                for (int reg = 0; reg < 4; ++reg) {
                    int row = mt * 16 + lk * 4 + reg;
                    rp += (float)s_pred[row * 136 + col] * e[reg];
                }
                rp *= inv;
                float rf = rp + __shfl_xor(rp, 16);
                if ((lk & 1) == 0) s_gr[q * 128 + col] = rf;
            }
        }
    }
    __syncthreads();

    // ---- ffn hidden (fp32) ----
    for (int p = 0; p < 2; ++p) {
        int q = p * 4 + (tid >> 6);
        int c = tid & 63;
        float a = 0.f;
        for (int k = 0; k < 128; ++k)
            a += s_gr[q * 128 + k] * f1[k * 64 + c];
        s_h[q * 64 + c] = gelu_f(a + fb1[c]);
    }
    __syncthreads();

    if (!out_nchw) {
        for (int it = 0; it < 4; ++it) {
            int q = it * 2 + (tid >> 7);
            int d = tid & 127;
            int n = n0 + q;
            int qy = n / Wq, qx = n - qy * Wq;
            float a = 0.f;
            for (int k = 0; k < 64; ++k)
                a += s_h[q * 64 + k] * f2[k * 128 + d];
            a += fb2[d];
            if (residual) a += s_gr[q * 128 + d];
            out[((size_t)(b * Hq + qy) * Wq + qx) * 128 + d] = a;
        }
    } else {
        if (tid < 8 * odim) {
            int q = tid / odim, d = tid - q * odim;
            int n = n0 + q;
            int qy = n / Wq, qx = n - qy * Wq;
            float a = 0.f;
            for (int k = 0; k < 64; ++k)
                a += s_h[q * 64 + k] * f2[k * odim + d];
            a += fb2[d];
            if (lms) a += lms[(((size_t)b * odim + d) * Hq + qy) * Wq + qx];
            out[(((size_t)b * odim + d) * Hq + qy) * Wq + qx] = a;
        }
    }
}

// ---- workspace byte offsets ----
#define WPACK_B   0ull
#define CC_B      5529600ull
#define SPEIN_B   (CC_B)
#define X2_B      (CC_B + 331776ull)
#define R2_B      (CC_B + 1658880ull)
#define T2_B      (CC_B + 2985984ull)
#define LRSPE_B   (CC_B + 4313088ull)
#define RH_B      14450688ull
#define TH_B      32292864ull
#define XH_B      50135040ull
#define G32_B     (TH_B)
#define G16_B     (TH_B + 8388608ull)
#define L1T_B     (TH_B + 10485760ull)
#define HR32_B    67977216ull
// level packed weights: PAST hr32 (hr32 ends at 101531648) — R3 bug was
// placing these under l1T's footprint (l1T ends at TH_B+18874368 > XH_B).
#define LVLW_B    101531648ull
#define L1IMW_B   (LVLW_B)
#define L1W1_B    (LVLW_B + 212992ull)
#define L1W2_B    (LVLW_B + 229376ull)
#define L2IMW_B   (LVLW_B + 245760ull)
#define L2W1_B    (LVLW_B + 458752ull)
#define L2W2_B    (LVLW_B + 475136ull)

extern "C" void kernel_launch(void* const* d_in, const int* in_sizes, int n_in,
                              void* d_out, int out_size, void* d_ws, size_t ws_size,
                              hipStream_t stream) {
    (void)in_sizes; (void)n_in; (void)out_size; (void)ws_size;
    const float* HR_MSI     = (const float*)d_in[0];
    const float* lms        = (const float*)d_in[1];
    const float* LR_HSI     = (const float*)d_in[2];
    const float* spa_head_w = (const float*)d_in[3];
    const float* spa_head_b = (const float*)d_in[4];
    const float* spa_res_w  = (const float*)d_in[5];
    const float* spa_res_b  = (const float*)d_in[6];
    const float* spa_tail_w = (const float*)d_in[7];
    const float* spa_tail_b = (const float*)d_in[8];
    const float* spe_head_w = (const float*)d_in[9];
    const float* spe_head_b = (const float*)d_in[10];
    const float* spe_res_w  = (const float*)d_in[11];
    const float* spe_res_b  = (const float*)d_in[12];
    const float* spe_tail_w = (const float*)d_in[13];
    const float* spe_tail_b = (const float*)d_in[14];
    const float* l1_w   = (const float*)d_in[15];
    const float* l1_b   = (const float*)d_in[16];
    const float* wg32_w1 = (const float*)d_in[17];
    const float* wg32_b1 = (const float*)d_in[18];
    const float* wg32_w2 = (const float*)d_in[19];
    const float* wg32_b2 = (const float*)d_in[20];
    const float* ffn32_w1 = (const float*)d_in[21];
    const float* ffn32_b1 = (const float*)d_in[22];
    const float* ffn32_w2 = (const float*)d_in[23];
    const float* ffn32_b2 = (const float*)d_in[24];
    const float* l2_w   = (const float*)d_in[25];
    const float* l2_b   = (const float*)d_in[26];
    const float* wg64_w1 = (const float*)d_in[27];
    const float* wg64_b1 = (const float*)d_in[28];
    const float* wg64_w2 = (const float*)d_in[29];
    const float* wg64_b2 = (const float*)d_in[30];
    const float* ffn64_w1 = (const float*)d_in[31];
    const float* ffn64_b1 = (const float*)d_in[32];
    const float* ffn64_w2 = (const float*)d_in[33];
    const float* ffn64_b2 = (const float*)d_in[34];

    char* ws = (char*)d_ws;
    f16* Wp     = (f16*)(ws + WPACK_B);
    f16* Cc     = (f16*)(ws + CC_B);
    f16* SPEin  = (f16*)(ws + SPEIN_B);
    f16* X2h    = (f16*)(ws + X2_B);
    f16* R2h    = (f16*)(ws + R2_B);
    f16* T2h    = (f16*)(ws + T2_B);
    float* lrspe32 = (float*)(ws + LRSPE_B);
    f16* Rh     = (f16*)(ws + RH_B);
    f16* Th     = (f16*)(ws + TH_B);
    f16* Xh     = (f16*)(ws + XH_B);
    float* g32T = (float*)(ws + G32_B);
    float* g16T = (float*)(ws + G16_B);
    float* l1T  = (float*)(ws + L1T_B);
    float* hr32 = (float*)(ws + HR32_B);
    f16* l1imw = (f16*)(ws + L1IMW_B);
    f16* l1w1  = (f16*)(ws + L1W1_B);
    f16* l1w2  = (f16*)(ws + L1W2_B);
    f16* l2imw = (f16*)(ws + L2IMW_B);
    f16* l2w1  = (f16*)(ws + L2W1_B);
    f16* l2w2  = (f16*)(ws + L2W2_B);

    // zero padded fp16 regions (borders must be 0)
    hipMemsetAsync(ws + CC_B, 0, 8921088ull, stream);
    hipMemsetAsync(ws + RH_B, 0, 53526528ull, stream);

    // pack conv weights
    pack_w<<<288, 256, 0, stream>>>(spa_head_w, Wp + 0, 34, 2, 73728);
    pack_w<<<4608, 256, 0, stream>>>(spa_res_w, Wp + 73728, 128, 4, 1179648);
    pack_w<<<576, 256, 0, stream>>>(spa_tail_w, Wp + 1253376, 128, 4, 147456);
    pack_w<<<144, 256, 0, stream>>>(spe_head_w, Wp + 1400832, 31, 1, 36864);
    pack_w<<<4608, 256, 0, stream>>>(spe_res_w, Wp + 1437696, 128, 4, 1179648);
    pack_w<<<576, 256, 0, stream>>>(spe_tail_w, Wp + 2617344, 128, 4, 147456);

    // pack level MLP weights (own region; no aliasing)
    pack_lvl<<<416, 256, 0, stream>>>(l1_w, l1imw, 386, 256, 13);
    pack_lvl<<<32, 256, 0, stream>>>(wg32_w1, l1w1, 128, 64, 4);
    pack_lvl<<<32, 256, 0, stream>>>(wg32_w2, l1w2, 64, 128, 2);
    pack_lvl<<<416, 256, 0, stream>>>(l2_w, l2imw, 386, 256, 13);
    pack_lvl<<<32, 256, 0, stream>>>(wg64_w1, l2w1, 128, 64, 4);
    pack_lvl<<<32, 256, 0, stream>>>(wg64_w2, l2w2, 64, 128, 2);

    // ---- spatial EDSR ----
    build_cc<<<8704, 256, 0, stream>>>(HR_MSI, lms, Cc, 16 * 64 * 64 * 34);
    conv_mfma<66, 6, 1><<<1024, 256, 0, stream>>>(Cc, 2, Wp + 0, spa_head_b,
                                                  nullptr, Xh, nullptr, 0);
    hipMemsetAsync(ws + SPEIN_B, 0, 4313088ull, stream);
    hipMemcpyAsync(Rh, Xh, 17842176ull, hipMemcpyDeviceToDevice, stream);
    for (int i = 0; i < 4; ++i) {
        conv_mfma<66, 6, 1><<<1024, 256, 0, stream>>>(
            Rh, 4, Wp + 73728 + (size_t)(2 * i) * 147456, spa_res_b + 2 * i * 128,
            nullptr, Th, nullptr, 1);
        conv_mfma<66, 6, 1><<<1024, 256, 0, stream>>>(
            Th, 4, Wp + 73728 + (size_t)(2 * i + 1) * 147456, spa_res_b + (2 * i + 1) * 128,
            nullptr, Rh, nullptr, 2);
    }
    conv_mfma<66, 6, 1><<<1024, 256, 0, stream>>>(Rh, 4, Wp + 1253376, spa_tail_b,
                                                  Xh, nullptr, hr32, 3);

    maxpool_nhwc<<<8192, 256, 0, stream>>>(hr32, g32T, 64, 64, 2, 2097152);
    maxpool_nhwc<<<2048, 256, 0, stream>>>(hr32, g16T, 64, 64, 4, 524288);

    // ---- spectral EDSR ----
    build_spe<<<496, 256, 0, stream>>>(LR_HSI, SPEin, 16 * 16 * 16 * 31);
    conv_mfma<18, 4, 4><<<64, 256, 0, stream>>>(SPEin, 1, Wp + 1400832, spe_head_b,
                                                nullptr, X2h, nullptr, 0);
    hipMemcpyAsync(R2h, X2h, 1327104ull, hipMemcpyDeviceToDevice, stream);
    for (int i = 0; i < 4; ++i) {
        conv_mfma<18, 4, 4><<<64, 256, 0, stream>>>(
            R2h, 4, Wp + 1437696 + (size_t)(2 * i) * 147456, spe_res_b + 2 * i * 128,
            nullptr, T2h, nullptr, 1);
        conv_mfma<18, 4, 4><<<64, 256, 0, stream>>>(
            T2h, 4, Wp + 1437696 + (size_t)(2 * i + 1) * 147456, spe_res_b + (2 * i + 1) * 128,
            nullptr, R2h, nullptr, 2);
    }
    conv_mfma<18, 4, 4><<<64, 256, 0, stream>>>(R2h, 4, Wp + 2617344, spe_tail_b,
                                                X2h, nullptr, lrspe32, 3);

    // ---- level 1: 32x32 queries ----
    level_kernel<<<2048, 256, 0, stream>>>(
        lrspe32, 16, 16, g32T, 32, 32, g16T, 16, 16,
        32, 32, 128,
        l1imw, l1_b, l1w1, wg32_b1, l1w2, wg32_b2,
        ffn32_w1, ffn32_b1, ffn32_w2, ffn32_b2,
        128, 1, 0, nullptr, l1T);

    // ---- level 2: 64x64 queries, + lms, NCHW to d_out ----
    level_kernel<<<8192, 256, 0, stream>>>(
        l1T, 32, 32, hr32, 64, 64, g32T, 32, 32,
        64, 64, 512,
        l2imw, l2_b, l2w1, wg64_b1, l2w2, wg64_b2,
        ffn64_w1, ffn64_b1, ffn64_w2, ffn64_b2,
        31, 0, 1, lms, (float*)d_out);
}

// Round 5
// 1250.128 us; speedup vs baseline: 6.9215x; 1.4268x over previous
//
#include <hip/hip_runtime.h>
#include <math.h>

typedef _Float16 f16;
typedef __attribute__((ext_vector_type(4))) _Float16 f16x4;
typedef __attribute__((ext_vector_type(8))) _Float16 f16x8;
typedef __attribute__((ext_vector_type(4))) float f32x4;
typedef __attribute__((ext_vector_type(4))) unsigned int u32x4;

// exact-GELU via Abramowitz-Stegun 7.1.26 erf (|err| <= 1.5e-7, ~12 VALU vs libm erff)
__device__ __forceinline__ float gelu_f(float x) {
    float xs = x * 0.70710678118654752440f;
    float ax = fabsf(xs);
    float t = __builtin_amdgcn_rcpf(1.0f + 0.3275911f * ax);
    float p = t * (0.254829592f + t * (-0.284496736f + t * (1.421413741f +
              t * (-1.453152027f + t * 1.061405429f))));
    float erfv = 1.0f - p * __expf(-ax * ax);
    erfv = copysignf(erfv, xs);
    return 0.5f * x * (1.0f + erfv);
}

__device__ __forceinline__ void nsamp(float cy, float cx, int hi, int wi,
                                      int& iy, int& ix, bool& valid) {
    float fy = rintf(((cy + 1.0f) * (float)hi - 1.0f) * 0.5f);
    float fx = rintf(((cx + 1.0f) * (float)wi - 1.0f) * 0.5f);
    valid = (fy >= 0.0f) && (fy < (float)hi) && (fx >= 0.0f) && (fx < (float)wi);
    iy = (int)fminf(fmaxf(fy, 0.0f), (float)(hi - 1));
    ix = (int)fminf(fmaxf(fx, 0.0f), (float)(wi - 1));
}

// ---- conv weight pre-pack: OIHW fp32 -> [conv][cout][chunk][tap][ci32] fp16 ----
__global__ __launch_bounds__(256) void pack_w(
    const float* __restrict__ src, f16* __restrict__ dst,
    int Cin, int NCHUNK, int total) {
    int i = blockIdx.x * 256 + threadIdx.x;
    if (i >= total) return;
    int ci = i & 31;
    int tap = (i >> 5) % 9;
    int q = i / 288;
    int chunk = q % NCHUNK;
    int q2 = q / NCHUNK;
    int cout = q2 & 127;
    int conv = q2 >> 7;
    int cin = chunk * 32 + ci;
    float v = (cin < Cin) ? src[((size_t)(conv * 128 + cout) * Cin + cin) * 9 + tap] : 0.f;
    dst[i] = (f16)v;
}

// ---- level MLP weight pack: src fp32 [K][N] -> dst fp16 [N][NC][32] ----
__global__ __launch_bounds__(256) void pack_lvl(
    const float* __restrict__ src, f16* __restrict__ dst,
    int Ksrc, int N, int NC) {
    int i = blockIdx.x * 256 + threadIdx.x;
    if (i >= N * NC * 32) return;
    int kk = i & 31;
    int c = (i >> 5) % NC;
    int n = i / (32 * NC);
    int k = c * 32 + kk;
    dst[i] = (f16)((k < Ksrc) ? src[(size_t)k * N + n] : 0.f);
}

// concat(HR_MSI, lms) -> padded NHWC fp16 [16][66][66][64]
__global__ __launch_bounds__(256) void build_cc(
    const float* __restrict__ msi, const float* __restrict__ lms,
    f16* __restrict__ out, int total) {
    int i = blockIdx.x * 256 + threadIdx.x;
    if (i >= total) return;
    int ch = i % 34;
    int p = i / 34;
    int x = p & 63, y = (p >> 6) & 63, b = p >> 12;
    float v = (ch < 3) ? msi[(((size_t)(b * 3 + ch) << 6) + y << 6) + x]
                       : lms[(((size_t)(b * 31 + ch - 3) << 6) + y << 6) + x];
    out[((size_t)(b * 66 + y + 1) * 66 + x + 1) * 64 + ch] = v;
}

// LR_HSI -> padded NHWC fp16 [16][18][18][32]
__global__ __launch_bounds__(256) void build_spe(
    const float* __restrict__ in, f16* __restrict__ out, int total) {
    int i = blockIdx.x * 256 + threadIdx.x;
    if (i >= total) return;
    int ch = i % 31;
    int p = i / 31;
    int x = p & 15, y = (p >> 4) & 15, b = p >> 8;
    out[((size_t)(b * 18 + y + 1) * 18 + x + 1) * 32 + ch] =
        (f16)in[(((size_t)(b * 31 + ch) << 4) + y << 4) + x];
}

// ---- implicit-GEMM conv3x3 SAME, NHWC fp16 padded in, Cout=128 ----
// Block computes ROWS*XW px x 128 cout; waves 2(Mhalf) x 2(Nhalf); MT m-tiles/wave.
template<int PXW, int XSH, int ROWS>
__global__ __launch_bounds__(256) void conv_mfma(
    const f16* __restrict__ in_h, int NCHUNK,
    const f16* __restrict__ wp, const float* __restrict__ bias,
    const f16* __restrict__ skip_h, f16* __restrict__ out_h,
    float* __restrict__ out_f, int mode) {
    constexpr int XW = 1 << XSH;
    constexpr int PH = XW + 2;
    constexpr int NPX = (ROWS + 2) * PXW;
    constexpr int UNITS = NPX * 4;
    constexpr int ITER = (UNITS + 255) / 256;
    constexpr int MT = (ROWS << XSH) >> 5;   // m-tiles per wave (Mhalf/16)
    __shared__ u32x4 ldsv[UNITS];
    char* ldsb = (char*)ldsv;

    int tid = threadIdx.x;
    constexpr int NYB = XW / ROWS;
    int b = blockIdx.x / NYB;
    int y0 = (blockIdx.x % NYB) * ROWS;
    int wave = tid >> 6, lane = tid & 63;
    int wm = wave >> 1, wn = wave & 1;
    int l15 = lane & 15, lk = lane >> 4;
    int CST = NCHUNK * 32;

    int gaddr[ITER], laddr[ITER];
#pragma unroll
    for (int i = 0; i < ITER; ++i) {
        int u = tid + 256 * i;
        if (u < UNITS) {
            int px = u >> 2, kg = u & 3;
            int r = px / PXW, xp = px - r * PXW;
            gaddr[i] = ((b * PH + y0 + r) * PXW + xp) * CST + kg * 8;
            laddr[i] = (u * 16) ^ (((px >> 1) & 3) << 4);
        } else {
            gaddr[i] = -1; laddr[i] = 0;
        }
    }

    f32x4 acc[MT][4];
#pragma unroll
    for (int mt = 0; mt < MT; ++mt)
#pragma unroll
        for (int nt = 0; nt < 4; ++nt)
            acc[mt][nt] = (f32x4){0.f, 0.f, 0.f, 0.f};

    u32x4 v[ITER];
#pragma unroll
    for (int i = 0; i < ITER; ++i)
        if (gaddr[i] >= 0) v[i] = *(const u32x4*)(in_h + gaddr[i]);

    for (int c = 0; c < NCHUNK; ++c) {
        if (c) __syncthreads();
#pragma unroll
        for (int i = 0; i < ITER; ++i)
            if (gaddr[i] >= 0) *(u32x4*)(ldsb + laddr[i]) = v[i];
        __syncthreads();
        if (c + 1 < NCHUNK) {
#pragma unroll
            for (int i = 0; i < ITER; ++i)
                if (gaddr[i] >= 0) v[i] = *(const u32x4*)(in_h + gaddr[i] + (c + 1) * 32);
        }
#pragma unroll
        for (int tap = 0; tap < 9; ++tap) {
            const int dy = tap / 3, dx = tap % 3;
            f16x8 afr[MT];
#pragma unroll
            for (int mt = 0; mt < MT; ++mt) {
                int px = (wm * MT + mt) * 16 + l15;
                int row = px >> XSH, x = px & (XW - 1);
                int pxl = (row + dy) * PXW + x + dx;
                int la = pxl * 64 + lk * 16;
                afr[mt] = *(const f16x8*)(ldsb + (la ^ (((pxl >> 1) & 3) << 4)));
            }
#pragma unroll
            for (int nt = 0; nt < 4; ++nt) {
                int cout = wn * 64 + nt * 16 + l15;
                f16x8 bfr = *(const f16x8*)(wp + ((size_t)(cout * NCHUNK + c) * 9 + tap) * 32 + lk * 8);
#pragma unroll
                for (int mt = 0; mt < MT; ++mt)
                    acc[mt][nt] = __builtin_amdgcn_mfma_f32_16x16x32_f16(afr[mt], bfr, acc[mt][nt], 0, 0, 0);
            }
        }
    }

#pragma unroll
    for (int mt = 0; mt < MT; ++mt)
#pragma unroll
        for (int nt = 0; nt < 4; ++nt) {
            int cout = wn * 64 + nt * 16 + l15;
            float bv = bias[cout];
#pragma unroll
            for (int reg = 0; reg < 4; ++reg) {
                int px = (wm * MT + mt) * 16 + lk * 4 + reg;
                int row = px >> XSH, x = px & (XW - 1);
                int yim = y0 + row;
                float vv = acc[mt][nt][reg] + bv;
                size_t ah = ((size_t)(b * PH + yim + 1) * PXW + x + 1) * 128 + cout;
                if (mode == 1) vv = fmaxf(vv, 0.f);
                if (mode == 2) vv += (float)out_h[ah];
                if (mode == 3) {
                    vv += (float)skip_h[ah];
                    out_f[((size_t)((b << XSH) + yim) << XSH | x) * 128 + cout] = vv;
                } else {
                    out_h[ah] = (f16)vv;
                }
            }
        }
}

// max pool kxk stride k on NHWC (C=128)
__global__ __launch_bounds__(256) void maxpool_nhwc(
    const float* __restrict__ in, float* __restrict__ out,
    int H, int W, int k, int total) {
    int i = blockIdx.x * 256 + threadIdx.x;
    if (i >= total) return;
    int c = i & 127;
    int r = i >> 7;
    int Wo = W / k, Ho = H / k;
    int x = r % Wo; r /= Wo;
    int y = r % Ho;
    int b = r / Ho;
    float m = -3.402823466e38f;
    for (int dy = 0; dy < k; ++dy)
        for (int dx = 0; dx < k; ++dx)
            m = fmaxf(m, in[((size_t)(b * H + y * k + dy) * W + x * k + dx) * 128 + c]);
    out[i] = m;
}

// ---- Fused level(), MFMA version. 8 queries/block, 256 threads. ----
// LDS overlay: s_inp[32][424] (27136B) -> after corner GEMM reads complete,
// region is reused for s_pred[64][136] (17408B) + h1[64][72] (9216B).
__global__ __launch_bounds__(256) void level_kernel(
    const float* __restrict__ featT, int fh, int fw,
    const float* __restrict__ guideT, int Hg, int Wg,
    const float* __restrict__ glrT, int hl, int wl,
    int Hq, int Wq, int n_per_b,
    const f16* __restrict__ imw_h, const float* __restrict__ imb,
    const f16* __restrict__ w1h, const float* __restrict__ b1,
    const f16* __restrict__ w2h, const float* __restrict__ b2,
    const float* __restrict__ f1, const float* __restrict__ fb1,
    const float* __restrict__ f2, const float* __restrict__ fb2,
    int odim, int residual, int out_nchw,
    const float* __restrict__ lms,
    float* __restrict__ out) {
    __shared__ char smem[33280];
    f16* s_inp  = (f16*)smem;            // [32][424]
    f16* s_pred = (f16*)smem;            // [64][136] overlay
    f16* s_h1   = (f16*)(smem + 17408);  // [64][72]
    float* s_gr = (float*)(smem + 27136);  // [8][128]
    float* s_h  = (float*)(smem + 31232);  // [8][64]

    int tid = threadIdx.x;
    int b = blockIdx.x / n_per_b;
    int n0 = (blockIdx.x % n_per_b) * 8;
    float invHq = 1.0f / (float)Hq, invWq = 1.0f / (float)Wq;
    float invfh = 1.0f / (float)fh, invfw = 1.0f / (float)fw;
    int wave = tid >> 6, lane = tid & 63;
    int l15 = lane & 15, lk = lane >> 4;

    // ---- gather: build s_inp[32][424] fp16 ----
    {
        const int r32 = tid >> 3, t8 = tid & 7;
        const int cidx = r32 >> 3, q = r32 & 7;
        int n = n0 + q;
        int qy = n / Wq, qx = n - qy * Wq;
        float cy = -1.0f + (float)(2 * qy + 1) * invHq;
        float cx = -1.0f + (float)(2 * qx + 1) * invWq;
        float vxc = (cidx < 2) ? -1.0f : 1.0f;
        float vyc = (cidx & 1) ? 1.0f : -1.0f;
        float cy_ = cy + vxc * invfh;
        float cx_ = cx + vyc * invfw;
        int iy, ix; bool vf;
        nsamp(cy_, cx_, fh, fw, iy, ix, vf);
        const float* fp = featT + ((size_t)(b * fh + iy) * fw + ix) * 128;
        int gy, gx; bool vg0;
        nsamp(cy, cx, Hg, Wg, gy, gx, vg0);
        const float* gp = guideT + ((size_t)(b * Hg + gy) * Wg + gx) * 128;
        int ly, lx; bool vl;
        nsamp(cy_, cx_, hl, wl, ly, lx, vl);
        const float* lp = glrT + ((size_t)(b * hl + ly) * wl + lx) * 128;
        f16* row = s_inp + r32 * 424;
#pragma unroll
        for (int e = 0; e < 4; ++e) {
            int d = t8 * 16 + e * 4;
            float4 a = vf ? *(const float4*)(fp + d) : make_float4(0.f, 0.f, 0.f, 0.f);
            float4 g = vg0 ? *(const float4*)(gp + d) : make_float4(0.f, 0.f, 0.f, 0.f);
            float4 l = vl ? *(const float4*)(lp + d) : make_float4(0.f, 0.f, 0.f, 0.f);
            *(f16x4*)(row + d)       = (f16x4){(f16)a.x, (f16)a.y, (f16)a.z, (f16)a.w};
            *(f16x4*)(row + 128 + d) = (f16x4){(f16)g.x, (f16)g.y, (f16)g.z, (f16)g.w};
            *(f16x4*)(row + 256 + d) = (f16x4){(f16)l.x, (f16)l.y, (f16)l.z, (f16)l.w};
        }
        if (t8 == 0) {
#pragma unroll
            for (int e = 0; e < 4; ++e)
                *(u32x4*)((char*)row + 768 + e * 16) = (u32x4){0, 0, 0, 0};
            float csy = vf ? (-1.0f + (float)(2 * iy + 1) * invfh) : 0.0f;
            float csx = vf ? (-1.0f + (float)(2 * ix + 1) * invfw) : 0.0f;
            row[384] = (f16)((cy - csy) * (float)fh);
            row[385] = (f16)((cx - csx) * (float)fw);
        }
    }
    __syncthreads();

    // ---- corner GEMM: 32x416 @ 416x256 (reads s_inp only) ----
    f32x4 acc[2][4];
    {
#pragma unroll
        for (int mt = 0; mt < 2; ++mt)
#pragma unroll
            for (int nt = 0; nt < 4; ++nt)
                acc[mt][nt] = (f32x4){0.f, 0.f, 0.f, 0.f};
        int nbase = wave * 64;
#pragma unroll
        for (int ks = 0; ks < 13; ++ks) {
            f16x8 afr[2];
#pragma unroll
            for (int mt = 0; mt < 2; ++mt)
                afr[mt] = *(const f16x8*)((char*)s_inp + (mt * 16 + l15) * 848 + ks * 64 + lk * 16);
#pragma unroll
            for (int nt = 0; nt < 4; ++nt) {
                f16x8 bfr = *(const f16x8*)(imw_h + ((size_t)(nbase + nt * 16 + l15) * 13 + ks) * 32 + lk * 8);
                acc[0][nt] = __builtin_amdgcn_mfma_f32_16x16x32_f16(afr[0], bfr, acc[0][nt], 0, 0, 0);
                acc[1][nt] = __builtin_amdgcn_mfma_f32_16x16x32_f16(afr[1], bfr, acc[1][nt], 0, 0, 0);
            }
        }
    }
    __syncthreads();  // all s_inp reads complete; region may be overlaid

    // ---- epilogue: bias + relu -> s_pred fp16 [qj][128] (overlay) ----
    {
        int nbase = wave * 64;
#pragma unroll
        for (int nt = 0; nt < 4; ++nt) {
            int col = nbase + nt * 16 + l15;
            float bv = imb[col];
            int j_hi = col >> 7, d = col & 127;
#pragma unroll
            for (int mt = 0; mt < 2; ++mt)
#pragma unroll
                for (int reg = 0; reg < 4; ++reg) {
                    int row32 = mt * 16 + lk * 4 + reg;
                    int q = row32 & 7, cidx = row32 >> 3;
                    int qj = q * 8 + cidx * 2 + j_hi;
                    s_pred[qj * 136 + d] = (f16)fmaxf(acc[mt][nt][reg] + bv, 0.f);
                }
        }
    }
    __syncthreads();

    // ---- wg1: preds[64][128] @ w1[128][64] -> h1 fp16 ----
    {
        f32x4 a1[4];
#pragma unroll
        for (int mt = 0; mt < 4; ++mt) a1[mt] = (f32x4){0.f, 0.f, 0.f, 0.f};
        int c1 = wave * 16 + l15;
#pragma unroll
        for (int ks = 0; ks < 4; ++ks) {
            f16x8 bfr = *(const f16x8*)(w1h + ((size_t)c1 * 4 + ks) * 32 + lk * 8);
#pragma unroll
            for (int mt = 0; mt < 4; ++mt) {
                f16x8 afr = *(const f16x8*)((char*)s_pred + (mt * 16 + l15) * 272 + ks * 64 + lk * 16);
                a1[mt] = __builtin_amdgcn_mfma_f32_16x16x32_f16(afr, bfr, a1[mt], 0, 0, 0);
            }
        }
        float bb1 = b1[c1];
#pragma unroll
        for (int mt = 0; mt < 4; ++mt)
#pragma unroll
            for (int reg = 0; reg < 4; ++reg) {
                int row = mt * 16 + lk * 4 + reg;
                s_h1[row * 72 + c1] = (f16)gelu_f(a1[mt][reg] + bb1);
            }
    }
    __syncthreads();

    // ---- wg2 + softmax over j + recon ----
    {
        f32x4 a2[4][2];
#pragma unroll
        for (int mt = 0; mt < 4; ++mt) {
            a2[mt][0] = (f32x4){0.f, 0.f, 0.f, 0.f};
            a2[mt][1] = (f32x4){0.f, 0.f, 0.f, 0.f};
        }
#pragma unroll
        for (int ks = 0; ks < 2; ++ks) {
            f16x8 afr[4];
#pragma unroll
            for (int mt = 0; mt < 4; ++mt)
                afr[mt] = *(const f16x8*)((char*)s_h1 + (mt * 16 + l15) * 144 + ks * 64 + lk * 16);
#pragma unroll
            for (int nt = 0; nt < 2; ++nt) {
                int c2 = wave * 32 + nt * 16 + l15;
                f16x8 bfr = *(const f16x8*)(w2h + ((size_t)c2 * 2 + ks) * 32 + lk * 8);
#pragma unroll
                for (int mt = 0; mt < 4; ++mt)
                    a2[mt][nt] = __builtin_amdgcn_mfma_f32_16x16x32_f16(afr[mt], bfr, a2[mt][nt], 0, 0, 0);
            }
        }
        int qhalf = lk >> 1;
#pragma unroll
        for (int nt = 0; nt < 2; ++nt) {
            int col = wave * 32 + nt * 16 + l15;
            float bb2 = b2[col];
#pragma unroll
            for (int mt = 0; mt < 4; ++mt) {
                int q = mt * 2 + qhalf;
                float v[4];
                float mloc = -3.4e38f;
#pragma unroll
                for (int reg = 0; reg < 4; ++reg) {
                    v[reg] = a2[mt][nt][reg] + bb2;
                    mloc = fmaxf(mloc, v[reg]);
                }
                float mf = fmaxf(mloc, __shfl_xor(mloc, 16));
                float e[4], sl = 0.f;
#pragma unroll
                for (int reg = 0; reg < 4; ++reg) {
                    e[reg] = __expf(v[reg] - mf);
                    sl += e[reg];
                }
                float sf = sl + __shfl_xor(sl, 16);
                float inv = 1.0f / sf;
                float rp = 0.f;
#pragma unroll
                for (int reg = 0; reg < 4; ++reg) {
                    int row = mt * 16 + lk * 4 + reg;
                    rp += (float)s_pred[row * 136 + col] * e[reg];
                }
                rp *= inv;
                float rf = rp + __shfl_xor(rp, 16);
                if ((lk & 1) == 0) s_gr[q * 128 + col] = rf;
            }
        }
    }
    __syncthreads();

    // ---- ffn hidden (fp32) ----
    for (int p = 0; p < 2; ++p) {
        int q = p * 4 + (tid >> 6);
        int c = tid & 63;
        float a = 0.f;
#pragma unroll 16
        for (int k = 0; k < 128; ++k)
            a += s_gr[q * 128 + k] * f1[k * 64 + c];
        s_h[q * 64 + c] = gelu_f(a + fb1[c]);
    }
    __syncthreads();

    if (!out_nchw) {
        for (int it = 0; it < 4; ++it) {
            int q = it * 2 + (tid >> 7);
            int d = tid & 127;
            int n = n0 + q;
            int qy = n / Wq, qx = n - qy * Wq;
            float a = 0.f;
#pragma unroll 16
            for (int k = 0; k < 64; ++k)
                a += s_h[q * 64 + k] * f2[k * 128 + d];
            a += fb2[d];
            if (residual) a += s_gr[q * 128 + d];
            out[((size_t)(b * Hq + qy) * Wq + qx) * 128 + d] = a;
        }
    } else {
        if (tid < 8 * odim) {
            int q = tid / odim, d = tid - q * odim;
            int n = n0 + q;
            int qy = n / Wq, qx = n - qy * Wq;
            float a = 0.f;
#pragma unroll 16
            for (int k = 0; k < 64; ++k)
                a += s_h[q * 64 + k] * f2[k * odim + d];
            a += fb2[d];
            if (lms) a += lms[(((size_t)b * odim + d) * Hq + qy) * Wq + qx];
            out[(((size_t)b * odim + d) * Hq + qy) * Wq + qx] = a;
        }
    }
}

// ---- workspace byte offsets ----
#define WPACK_B   0ull
#define CC_B      5529600ull
#define SPEIN_B   (CC_B)
#define X2_B      (CC_B + 331776ull)
#define R2_B      (CC_B + 1658880ull)
#define T2_B      (CC_B + 2985984ull)
#define LRSPE_B   (CC_B + 4313088ull)
#define RH_B      14450688ull
#define TH_B      32292864ull
#define XH_B      50135040ull
#define G32_B     (TH_B)
#define G16_B     (TH_B + 8388608ull)
#define L1T_B     (TH_B + 10485760ull)
#define HR32_B    67977216ull
#define LVLW_B    101531648ull
#define L1IMW_B   (LVLW_B)
#define L1W1_B    (LVLW_B + 212992ull)
#define L1W2_B    (LVLW_B + 229376ull)
#define L2IMW_B   (LVLW_B + 245760ull)
#define L2W1_B    (LVLW_B + 458752ull)
#define L2W2_B    (LVLW_B + 475136ull)

extern "C" void kernel_launch(void* const* d_in, const int* in_sizes, int n_in,
                              void* d_out, int out_size, void* d_ws, size_t ws_size,
                              hipStream_t stream) {
    (void)in_sizes; (void)n_in; (void)out_size; (void)ws_size;
    const float* HR_MSI     = (const float*)d_in[0];
    const float* lms        = (const float*)d_in[1];
    const float* LR_HSI     = (const float*)d_in[2];
    const float* spa_head_w = (const float*)d_in[3];
    const float* spa_head_b = (const float*)d_in[4];
    const float* spa_res_w  = (const float*)d_in[5];
    const float* spa_res_b  = (const float*)d_in[6];
    const float* spa_tail_w = (const float*)d_in[7];
    const float* spa_tail_b = (const float*)d_in[8];
    const float* spe_head_w = (const float*)d_in[9];
    const float* spe_head_b = (const float*)d_in[10];
    const float* spe_res_w  = (const float*)d_in[11];
    const float* spe_res_b  = (const float*)d_in[12];
    const float* spe_tail_w = (const float*)d_in[13];
    const float* spe_tail_b = (const float*)d_in[14];
    const float* l1_w   = (const float*)d_in[15];
    const float* l1_b   = (const float*)d_in[16];
    const float* wg32_w1 = (const float*)d_in[17];
    const float* wg32_b1 = (const float*)d_in[18];
    const float* wg32_w2 = (const float*)d_in[19];
    const float* wg32_b2 = (const float*)d_in[20];
    const float* ffn32_w1 = (const float*)d_in[21];
    const float* ffn32_b1 = (const float*)d_in[22];
    const float* ffn32_w2 = (const float*)d_in[23];
    const float* ffn32_b2 = (const float*)d_in[24];
    const float* l2_w   = (const float*)d_in[25];
    const float* l2_b   = (const float*)d_in[26];
    const float* wg64_w1 = (const float*)d_in[27];
    const float* wg64_b1 = (const float*)d_in[28];
    const float* wg64_w2 = (const float*)d_in[29];
    const float* wg64_b2 = (const float*)d_in[30];
    const float* ffn64_w1 = (const float*)d_in[31];
    const float* ffn64_b1 = (const float*)d_in[32];
    const float* ffn64_w2 = (const float*)d_in[33];
    const float* ffn64_b2 = (const float*)d_in[34];

    char* ws = (char*)d_ws;
    f16* Wp     = (f16*)(ws + WPACK_B);
    f16* Cc     = (f16*)(ws + CC_B);
    f16* SPEin  = (f16*)(ws + SPEIN_B);
    f16* X2h    = (f16*)(ws + X2_B);
    f16* R2h    = (f16*)(ws + R2_B);
    f16* T2h    = (f16*)(ws + T2_B);
    float* lrspe32 = (float*)(ws + LRSPE_B);
    f16* Rh     = (f16*)(ws + RH_B);
    f16* Th     = (f16*)(ws + TH_B);
    f16* Xh     = (f16*)(ws + XH_B);
    float* g32T = (float*)(ws + G32_B);
    float* g16T = (float*)(ws + G16_B);
    float* l1T  = (float*)(ws + L1T_B);
    float* hr32 = (float*)(ws + HR32_B);
    f16* l1imw = (f16*)(ws + L1IMW_B);
    f16* l1w1  = (f16*)(ws + L1W1_B);
    f16* l1w2  = (f16*)(ws + L1W2_B);
    f16* l2imw = (f16*)(ws + L2IMW_B);
    f16* l2w1  = (f16*)(ws + L2W1_B);
    f16* l2w2  = (f16*)(ws + L2W2_B);

    // zero padded fp16 regions (borders must be 0)
    hipMemsetAsync(ws + CC_B, 0, 8921088ull, stream);
    hipMemsetAsync(ws + RH_B, 0, 53526528ull, stream);

    // pack conv weights
    pack_w<<<288, 256, 0, stream>>>(spa_head_w, Wp + 0, 34, 2, 73728);
    pack_w<<<4608, 256, 0, stream>>>(spa_res_w, Wp + 73728, 128, 4, 1179648);
    pack_w<<<576, 256, 0, stream>>>(spa_tail_w, Wp + 1253376, 128, 4, 147456);
    pack_w<<<144, 256, 0, stream>>>(spe_head_w, Wp + 1400832, 31, 1, 36864);
    pack_w<<<4608, 256, 0, stream>>>(spe_res_w, Wp + 1437696, 128, 4, 1179648);
    pack_w<<<576, 256, 0, stream>>>(spe_tail_w, Wp + 2617344, 128, 4, 147456);

    // pack level MLP weights (own region; no aliasing)
    pack_lvl<<<416, 256, 0, stream>>>(l1_w, l1imw, 386, 256, 13);
    pack_lvl<<<32, 256, 0, stream>>>(wg32_w1, l1w1, 128, 64, 4);
    pack_lvl<<<32, 256, 0, stream>>>(wg32_w2, l1w2, 64, 128, 2);
    pack_lvl<<<416, 256, 0, stream>>>(l2_w, l2imw, 386, 256, 13);
    pack_lvl<<<32, 256, 0, stream>>>(wg64_w1, l2w1, 128, 64, 4);
    pack_lvl<<<32, 256, 0, stream>>>(wg64_w2, l2w2, 64, 128, 2);

    // ---- spatial EDSR (128 px x 128 cout per block) ----
    build_cc<<<8704, 256, 0, stream>>>(HR_MSI, lms, Cc, 16 * 64 * 64 * 34);
    conv_mfma<66, 6, 2><<<512, 256, 0, stream>>>(Cc, 2, Wp + 0, spa_head_b,
                                                 nullptr, Xh, nullptr, 0);
    hipMemsetAsync(ws + SPEIN_B, 0, 4313088ull, stream);
    hipMemcpyAsync(Rh, Xh, 17842176ull, hipMemcpyDeviceToDevice, stream);
    for (int i = 0; i < 4; ++i) {
        conv_mfma<66, 6, 2><<<512, 256, 0, stream>>>(
            Rh, 4, Wp + 73728 + (size_t)(2 * i) * 147456, spa_res_b + 2 * i * 128,
            nullptr, Th, nullptr, 1);
        conv_mfma<66, 6, 2><<<512, 256, 0, stream>>>(
            Th, 4, Wp + 73728 + (size_t)(2 * i + 1) * 147456, spa_res_b + (2 * i + 1) * 128,
            nullptr, Rh, nullptr, 2);
    }
    conv_mfma<66, 6, 2><<<512, 256, 0, stream>>>(Rh, 4, Wp + 1253376, spa_tail_b,
                                                 Xh, nullptr, hr32, 3);

    maxpool_nhwc<<<8192, 256, 0, stream>>>(hr32, g32T, 64, 64, 2, 2097152);
    maxpool_nhwc<<<2048, 256, 0, stream>>>(hr32, g16T, 64, 64, 4, 524288);

    // ---- spectral EDSR ----
    build_spe<<<496, 256, 0, stream>>>(LR_HSI, SPEin, 16 * 16 * 16 * 31);
    conv_mfma<18, 4, 4><<<64, 256, 0, stream>>>(SPEin, 1, Wp + 1400832, spe_head_b,
                                                nullptr, X2h, nullptr, 0);
    hipMemcpyAsync(R2h, X2h, 1327104ull, hipMemcpyDeviceToDevice, stream);
    for (int i = 0; i < 4; ++i) {
        conv_mfma<18, 4, 4><<<64, 256, 0, stream>>>(
            R2h, 4, Wp + 1437696 + (size_t)(2 * i) * 147456, spe_res_b + 2 * i * 128,
            nullptr, T2h, nullptr, 1);
        conv_mfma<18, 4, 4><<<64, 256, 0, stream>>>(
            T2h, 4, Wp + 1437696 + (size_t)(2 * i + 1) * 147456, spe_res_b + (2 * i + 1) * 128,
            nullptr, R2h, nullptr, 2);
    }
    conv_mfma<18, 4, 4><<<64, 256, 0, stream>>>(R2h, 4, Wp + 2617344, spe_tail_b,
                                                X2h, nullptr, lrspe32, 3);

    // ---- level 1: 32x32 queries ----
    level_kernel<<<2048, 256, 0, stream>>>(
        lrspe32, 16, 16, g32T, 32, 32, g16T, 16, 16,
        32, 32, 128,
        l1imw, l1_b, l1w1, wg32_b1, l1w2, wg32_b2,
        ffn32_w1, ffn32_b1, ffn32_w2, ffn32_b2,
        128, 1, 0, nullptr, l1T);

    // ---- level 2: 64x64 queries, + lms, NCHW to d_out ----
    level_kernel<<<8192, 256, 0, stream>>>(
        l1T, 32, 32, hr32, 64, 64, g32T, 32, 32,
        64, 64, 512,
        l2imw, l2_b, l2w1, wg64_b1, l2w2, wg64_b2,
        ffn64_w1, ffn64_b1, ffn64_w2, ffn64_b2,
        31, 0, 1, lms, (float*)d_out);
}

// Round 6
// 1162.592 us; speedup vs baseline: 7.4427x; 1.0753x over previous
//
#include <hip/hip_runtime.h>
#include <math.h>

typedef _Float16 f16;
typedef __attribute__((ext_vector_type(4))) _Float16 f16x4;
typedef __attribute__((ext_vector_type(8))) _Float16 f16x8;
typedef __attribute__((ext_vector_type(4))) float f32x4;
typedef __attribute__((ext_vector_type(4))) unsigned int u32x4;

// exact-GELU via Abramowitz-Stegun 7.1.26 erf (|err| <= 1.5e-7)
__device__ __forceinline__ float gelu_f(float x) {
    float xs = x * 0.70710678118654752440f;
    float ax = fabsf(xs);
    float t = __builtin_amdgcn_rcpf(1.0f + 0.3275911f * ax);
    float p = t * (0.254829592f + t * (-0.284496736f + t * (1.421413741f +
              t * (-1.453152027f + t * 1.061405429f))));
    float erfv = 1.0f - p * __expf(-ax * ax);
    erfv = copysignf(erfv, xs);
    return 0.5f * x * (1.0f + erfv);
}

__device__ __forceinline__ void nsamp(float cy, float cx, int hi, int wi,
                                      int& iy, int& ix, bool& valid) {
    float fy = rintf(((cy + 1.0f) * (float)hi - 1.0f) * 0.5f);
    float fx = rintf(((cx + 1.0f) * (float)wi - 1.0f) * 0.5f);
    valid = (fy >= 0.0f) && (fy < (float)hi) && (fx >= 0.0f) && (fx < (float)wi);
    iy = (int)fminf(fmaxf(fy, 0.0f), (float)(hi - 1));
    ix = (int)fminf(fmaxf(fx, 0.0f), (float)(wi - 1));
}

// ---- conv weight pre-pack: OIHW fp32 -> [conv][cout][chunk][tap][ci32] fp16 ----
__global__ __launch_bounds__(256) void pack_w(
    const float* __restrict__ src, f16* __restrict__ dst,
    int Cin, int NCHUNK, int total) {
    int i = blockIdx.x * 256 + threadIdx.x;
    if (i >= total) return;
    int ci = i & 31;
    int tap = (i >> 5) % 9;
    int q = i / 288;
    int chunk = q % NCHUNK;
    int q2 = q / NCHUNK;
    int cout = q2 & 127;
    int conv = q2 >> 7;
    int cin = chunk * 32 + ci;
    float v = (cin < Cin) ? src[((size_t)(conv * 128 + cout) * Cin + cin) * 9 + tap] : 0.f;
    dst[i] = (f16)v;
}

// ---- level MLP weight pack: src fp32 [K][N] -> dst fp16 [N][NC][32] ----
__global__ __launch_bounds__(256) void pack_lvl(
    const float* __restrict__ src, f16* __restrict__ dst,
    int Ksrc, int N, int NC) {
    int i = blockIdx.x * 256 + threadIdx.x;
    if (i >= N * NC * 32) return;
    int kk = i & 31;
    int c = (i >> 5) % NC;
    int n = i / (32 * NC);
    int k = c * 32 + kk;
    dst[i] = (f16)((k < Ksrc) ? src[(size_t)k * N + n] : 0.f);
}

// concat(HR_MSI, lms) -> padded NHWC fp16 [16][66][66][64]
__global__ __launch_bounds__(256) void build_cc(
    const float* __restrict__ msi, const float* __restrict__ lms,
    f16* __restrict__ out, int total) {
    int i = blockIdx.x * 256 + threadIdx.x;
    if (i >= total) return;
    int ch = i % 34;
    int p = i / 34;
    int x = p & 63, y = (p >> 6) & 63, b = p >> 12;
    float v = (ch < 3) ? msi[(((size_t)(b * 3 + ch) << 6) + y << 6) + x]
                       : lms[(((size_t)(b * 31 + ch - 3) << 6) + y << 6) + x];
    out[((size_t)(b * 66 + y + 1) * 66 + x + 1) * 64 + ch] = v;
}

// LR_HSI -> padded NHWC fp16 [16][18][18][32]
__global__ __launch_bounds__(256) void build_spe(
    const float* __restrict__ in, f16* __restrict__ out, int total) {
    int i = blockIdx.x * 256 + threadIdx.x;
    if (i >= total) return;
    int ch = i % 31;
    int p = i / 31;
    int x = p & 15, y = (p >> 4) & 15, b = p >> 8;
    out[((size_t)(b * 18 + y + 1) * 18 + x + 1) * 32 + ch] =
        (f16)in[(((size_t)(b * 31 + ch) << 4) + y << 4) + x];
}

// ---- implicit-GEMM conv3x3 SAME, NHWC fp16 padded in, Cout=128 ----
// mode: 0 plain->out_h, 1 relu->out_h, 2 self-add, 3 tail (+skip_h -> out2 f16 NHWC unpadded)
template<int PXW, int XSH, int ROWS>
__global__ __launch_bounds__(256) void conv_mfma(
    const f16* __restrict__ in_h, int NCHUNK,
    const f16* __restrict__ wp, const float* __restrict__ bias,
    const f16* __restrict__ skip_h, f16* __restrict__ out_h,
    f16* __restrict__ out2, int mode) {
    constexpr int XW = 1 << XSH;
    constexpr int PH = XW + 2;
    constexpr int NPX = (ROWS + 2) * PXW;
    constexpr int UNITS = NPX * 4;
    constexpr int ITER = (UNITS + 255) / 256;
    constexpr int MT = (ROWS << XSH) >> 5;
    __shared__ u32x4 ldsv[UNITS];
    char* ldsb = (char*)ldsv;

    int tid = threadIdx.x;
    constexpr int NYB = XW / ROWS;
    int b = blockIdx.x / NYB;
    int y0 = (blockIdx.x % NYB) * ROWS;
    int wave = tid >> 6, lane = tid & 63;
    int wm = wave >> 1, wn = wave & 1;
    int l15 = lane & 15, lk = lane >> 4;
    int CST = NCHUNK * 32;

    int gaddr[ITER], laddr[ITER];
#pragma unroll
    for (int i = 0; i < ITER; ++i) {
        int u = tid + 256 * i;
        if (u < UNITS) {
            int px = u >> 2, kg = u & 3;
            int r = px / PXW, xp = px - r * PXW;
            gaddr[i] = ((b * PH + y0 + r) * PXW + xp) * CST + kg * 8;
            laddr[i] = (u * 16) ^ (((px >> 1) & 3) << 4);
        } else {
            gaddr[i] = -1; laddr[i] = 0;
        }
    }

    f32x4 acc[MT][4];
#pragma unroll
    for (int mt = 0; mt < MT; ++mt)
#pragma unroll
        for (int nt = 0; nt < 4; ++nt)
            acc[mt][nt] = (f32x4){0.f, 0.f, 0.f, 0.f};

    u32x4 v[ITER];
#pragma unroll
    for (int i = 0; i < ITER; ++i)
        if (gaddr[i] >= 0) v[i] = *(const u32x4*)(in_h + gaddr[i]);

    for (int c = 0; c < NCHUNK; ++c) {
        if (c) __syncthreads();
#pragma unroll
        for (int i = 0; i < ITER; ++i)
            if (gaddr[i] >= 0) *(u32x4*)(ldsb + laddr[i]) = v[i];
        __syncthreads();
        if (c + 1 < NCHUNK) {
#pragma unroll
            for (int i = 0; i < ITER; ++i)
                if (gaddr[i] >= 0) v[i] = *(const u32x4*)(in_h + gaddr[i] + (c + 1) * 32);
        }
#pragma unroll
        for (int tap = 0; tap < 9; ++tap) {
            const int dy = tap / 3, dx = tap % 3;
            f16x8 afr[MT];
#pragma unroll
            for (int mt = 0; mt < MT; ++mt) {
                int px = (wm * MT + mt) * 16 + l15;
                int row = px >> XSH, x = px & (XW - 1);
                int pxl = (row + dy) * PXW + x + dx;
                int la = pxl * 64 + lk * 16;
                afr[mt] = *(const f16x8*)(ldsb + (la ^ (((pxl >> 1) & 3) << 4)));
            }
#pragma unroll
            for (int nt = 0; nt < 4; ++nt) {
                int cout = wn * 64 + nt * 16 + l15;
                f16x8 bfr = *(const f16x8*)(wp + ((size_t)(cout * NCHUNK + c) * 9 + tap) * 32 + lk * 8);
#pragma unroll
                for (int mt = 0; mt < MT; ++mt)
                    acc[mt][nt] = __builtin_amdgcn_mfma_f32_16x16x32_f16(afr[mt], bfr, acc[mt][nt], 0, 0, 0);
            }
        }
    }

#pragma unroll
    for (int mt = 0; mt < MT; ++mt)
#pragma unroll
        for (int nt = 0; nt < 4; ++nt) {
            int cout = wn * 64 + nt * 16 + l15;
            float bv = bias[cout];
#pragma unroll
            for (int reg = 0; reg < 4; ++reg) {
                int px = (wm * MT + mt) * 16 + lk * 4 + reg;
                int row = px >> XSH, x = px & (XW - 1);
                int yim = y0 + row;
                float vv = acc[mt][nt][reg] + bv;
                size_t ah = ((size_t)(b * PH + yim + 1) * PXW + x + 1) * 128 + cout;
                if (mode == 1) vv = fmaxf(vv, 0.f);
                if (mode == 2) vv += (float)out_h[ah];
                if (mode == 3) {
                    vv += (float)skip_h[ah];
                    out2[((size_t)((b << XSH) + yim) << XSH | x) * 128 + cout] = (f16)vv;
                } else {
                    out_h[ah] = (f16)vv;
                }
            }
        }
}

// max pool kxk stride k on NHWC f16 (C=128)
__global__ __launch_bounds__(256) void maxpool_nhwc(
    const f16* __restrict__ in, f16* __restrict__ out,
    int H, int W, int k, int total) {
    int i = blockIdx.x * 256 + threadIdx.x;
    if (i >= total) return;
    int c = i & 127;
    int r = i >> 7;
    int Wo = W / k, Ho = H / k;
    int x = r % Wo; r /= Wo;
    int y = r % Ho;
    int b = r / Ho;
    float m = -3.402823466e38f;
    for (int dy = 0; dy < k; ++dy)
        for (int dx = 0; dx < k; ++dx)
            m = fmaxf(m, (float)in[((size_t)(b * H + y * k + dy) * W + x * k + dx) * 128 + c]);
    out[i] = (f16)m;
}

// ---- Fused level(), all-MFMA version. 8 queries/block, 256 threads. ----
// LDS map (31488 B):
//   [0, 27136)      s_inp[32][424]    -> overlay: s_pred[64][136] (17408) + s_h1[64][72] @17408
//                                     -> after wg2: s_hh[16][72] @0 (s_pred dead)
//   [27136, 31488)  s_rec[16][136] f16 (recon A-tile; rows 8-15 garbage, unused)
__global__ __launch_bounds__(256) void level_kernel(
    const f16* __restrict__ featT, int fh, int fw,
    const f16* __restrict__ guideT, int Hg, int Wg,
    const f16* __restrict__ glrT, int hl, int wl,
    int Hq, int Wq, int n_per_b,
    const f16* __restrict__ imw_h, const float* __restrict__ imb,
    const f16* __restrict__ w1h, const float* __restrict__ b1,
    const f16* __restrict__ w2h, const float* __restrict__ b2,
    const f16* __restrict__ f1h, const float* __restrict__ fb1,
    const f16* __restrict__ f2h, const float* __restrict__ fb2,
    int odim, int residual, int out_nchw,
    const float* __restrict__ lms,
    f16* __restrict__ out16, float* __restrict__ outf) {
    __shared__ char smem[31488];
    f16* s_inp  = (f16*)smem;            // [32][424]
    f16* s_pred = (f16*)smem;            // [64][136] overlay
    f16* s_h1   = (f16*)(smem + 17408);  // [64][72]
    f16* s_hh   = (f16*)smem;            // [16][72] overlay (after s_pred dead)
    f16* s_rec  = (f16*)(smem + 27136);  // [16][136]

    int tid = threadIdx.x;
    int b = blockIdx.x / n_per_b;
    int n0 = (blockIdx.x % n_per_b) * 8;
    float invHq = 1.0f / (float)Hq, invWq = 1.0f / (float)Wq;
    float invfh = 1.0f / (float)fh, invfw = 1.0f / (float)fw;
    int wave = tid >> 6, lane = tid & 63;
    int l15 = lane & 15, lk = lane >> 4;

    // ---- gather: build s_inp[32][424] fp16 (all sources already f16 NHWC) ----
    {
        const int r32 = tid >> 3, t8 = tid & 7;
        const int cidx = r32 >> 3, q = r32 & 7;
        int n = n0 + q;
        int qy = n / Wq, qx = n - qy * Wq;
        float cy = -1.0f + (float)(2 * qy + 1) * invHq;
        float cx = -1.0f + (float)(2 * qx + 1) * invWq;
        float vxc = (cidx < 2) ? -1.0f : 1.0f;
        float vyc = (cidx & 1) ? 1.0f : -1.0f;
        float cy_ = cy + vxc * invfh;
        float cx_ = cx + vyc * invfw;
        int iy, ix; bool vf;
        nsamp(cy_, cx_, fh, fw, iy, ix, vf);
        const f16* fp = featT + ((size_t)(b * fh + iy) * fw + ix) * 128;
        int gy, gx; bool vg0;
        nsamp(cy, cx, Hg, Wg, gy, gx, vg0);
        const f16* gp = guideT + ((size_t)(b * Hg + gy) * Wg + gx) * 128;
        int ly, lx; bool vl;
        nsamp(cy_, cx_, hl, wl, ly, lx, vl);
        const f16* lp = glrT + ((size_t)(b * hl + ly) * wl + lx) * 128;
        f16* row = s_inp + r32 * 424;
        const u32x4 zz = (u32x4){0, 0, 0, 0};
#pragma unroll
        for (int e = 0; e < 2; ++e) {
            int d0 = t8 * 8 + e * 64;
            u32x4 av = vf ? *(const u32x4*)(fp + d0) : zz;
            u32x4 gv = vg0 ? *(const u32x4*)(gp + d0) : zz;
            u32x4 lv = vl ? *(const u32x4*)(lp + d0) : zz;
            *(u32x4*)(row + d0) = av;
            *(u32x4*)(row + 128 + d0) = gv;
            *(u32x4*)(row + 256 + d0) = lv;
        }
        if (t8 == 0) {
#pragma unroll
            for (int e = 0; e < 4; ++e)
                *(u32x4*)((char*)row + 768 + e * 16) = zz;
            float csy = vf ? (-1.0f + (float)(2 * iy + 1) * invfh) : 0.0f;
            float csx = vf ? (-1.0f + (float)(2 * ix + 1) * invfw) : 0.0f;
            row[384] = (f16)((cy - csy) * (float)fh);
            row[385] = (f16)((cx - csx) * (float)fw);
        }
    }
    __syncthreads();

    // ---- corner GEMM: 32x416 @ 416x256 ----
    f32x4 acc[2][4];
    {
#pragma unroll
        for (int mt = 0; mt < 2; ++mt)
#pragma unroll
            for (int nt = 0; nt < 4; ++nt)
                acc[mt][nt] = (f32x4){0.f, 0.f, 0.f, 0.f};
        int nbase = wave * 64;
#pragma unroll
        for (int ks = 0; ks < 13; ++ks) {
            f16x8 afr[2];
#pragma unroll
            for (int mt = 0; mt < 2; ++mt)
                afr[mt] = *(const f16x8*)((char*)s_inp + (mt * 16 + l15) * 848 + ks * 64 + lk * 16);
#pragma unroll
            for (int nt = 0; nt < 4; ++nt) {
                f16x8 bfr = *(const f16x8*)(imw_h + ((size_t)(nbase + nt * 16 + l15) * 13 + ks) * 32 + lk * 8);
                acc[0][nt] = __builtin_amdgcn_mfma_f32_16x16x32_f16(afr[0], bfr, acc[0][nt], 0, 0, 0);
                acc[1][nt] = __builtin_amdgcn_mfma_f32_16x16x32_f16(afr[1], bfr, acc[1][nt], 0, 0, 0);
            }
        }
    }
    __syncthreads();  // s_inp reads complete

    // ---- epilogue: bias + relu -> s_pred fp16 [qj][128] (overlay) ----
    {
        int nbase = wave * 64;
#pragma unroll
        for (int nt = 0; nt < 4; ++nt) {
            int col = nbase + nt * 16 + l15;
            float bv = imb[col];
            int j_hi = col >> 7, d = col & 127;
#pragma unroll
            for (int mt = 0; mt < 2; ++mt)
#pragma unroll
                for (int reg = 0; reg < 4; ++reg) {
                    int row32 = mt * 16 + lk * 4 + reg;
                    int q = row32 & 7, cidx = row32 >> 3;
                    int qj = q * 8 + cidx * 2 + j_hi;
                    s_pred[qj * 136 + d] = (f16)fmaxf(acc[mt][nt][reg] + bv, 0.f);
                }
        }
    }
    __syncthreads();

    // ---- wg1: preds[64][128] @ w1[128][64] -> h1 fp16 ----
    {
        f32x4 a1[4];
#pragma unroll
        for (int mt = 0; mt < 4; ++mt) a1[mt] = (f32x4){0.f, 0.f, 0.f, 0.f};
        int c1 = wave * 16 + l15;
#pragma unroll
        for (int ks = 0; ks < 4; ++ks) {
            f16x8 bfr = *(const f16x8*)(w1h + ((size_t)c1 * 4 + ks) * 32 + lk * 8);
#pragma unroll
            for (int mt = 0; mt < 4; ++mt) {
                f16x8 afr = *(const f16x8*)((char*)s_pred + (mt * 16 + l15) * 272 + ks * 64 + lk * 16);
                a1[mt] = __builtin_amdgcn_mfma_f32_16x16x32_f16(afr, bfr, a1[mt], 0, 0, 0);
            }
        }
        float bb1 = b1[c1];
#pragma unroll
        for (int mt = 0; mt < 4; ++mt)
#pragma unroll
            for (int reg = 0; reg < 4; ++reg) {
                int row = mt * 16 + lk * 4 + reg;
                s_h1[row * 72 + c1] = (f16)gelu_f(a1[mt][reg] + bb1);
            }
    }
    __syncthreads();

    // ---- wg2 + softmax over j + recon -> s_rec f16 [16][136] ----
    {
        f32x4 a2[4][2];
#pragma unroll
        for (int mt = 0; mt < 4; ++mt) {
            a2[mt][0] = (f32x4){0.f, 0.f, 0.f, 0.f};
            a2[mt][1] = (f32x4){0.f, 0.f, 0.f, 0.f};
        }
#pragma unroll
        for (int ks = 0; ks < 2; ++ks) {
            f16x8 afr[4];
#pragma unroll
            for (int mt = 0; mt < 4; ++mt)
                afr[mt] = *(const f16x8*)((char*)s_h1 + (mt * 16 + l15) * 144 + ks * 64 + lk * 16);
#pragma unroll
            for (int nt = 0; nt < 2; ++nt) {
                int c2 = wave * 32 + nt * 16 + l15;
                f16x8 bfr = *(const f16x8*)(w2h + ((size_t)c2 * 2 + ks) * 32 + lk * 8);
#pragma unroll
                for (int mt = 0; mt < 4; ++mt)
                    a2[mt][nt] = __builtin_amdgcn_mfma_f32_16x16x32_f16(afr[mt], bfr, a2[mt][nt], 0, 0, 0);
            }
        }
        int qhalf = lk >> 1;
#pragma unroll
        for (int nt = 0; nt < 2; ++nt) {
            int col = wave * 32 + nt * 16 + l15;
            float bb2 = b2[col];
#pragma unroll
            for (int mt = 0; mt < 4; ++mt) {
                int q = mt * 2 + qhalf;
                float v[4];
                float mloc = -3.4e38f;
#pragma unroll
                for (int reg = 0; reg < 4; ++reg) {
                    v[reg] = a2[mt][nt][reg] + bb2;
                    mloc = fmaxf(mloc, v[reg]);
                }
                float mf = fmaxf(mloc, __shfl_xor(mloc, 16));
                float e[4], sl = 0.f;
#pragma unroll
                for (int reg = 0; reg < 4; ++reg) {
                    e[reg] = __expf(v[reg] - mf);
                    sl += e[reg];
                }
                float sf = sl + __shfl_xor(sl, 16);
                float inv = 1.0f / sf;
                float rp = 0.f;
#pragma unroll
                for (int reg = 0; reg < 4; ++reg) {
                    int row = mt * 16 + lk * 4 + reg;
                    rp += (float)s_pred[row * 136 + col] * e[reg];
                }
                rp *= inv;
                float rf = rp + __shfl_xor(rp, 16);
                if ((lk & 1) == 0) s_rec[q * 136 + col] = (f16)rf;
            }
        }
    }
    __syncthreads();  // s_pred/s_h1 dead; s_rec ready

    // ---- ffn1 (MFMA): rec[16][128] @ f1[128][64] -> s_hh[16][64] f16 ----
    {
        f32x4 a1 = (f32x4){0.f, 0.f, 0.f, 0.f};
        int c1 = wave * 16 + l15;
#pragma unroll
        for (int ks = 0; ks < 4; ++ks) {
            f16x8 afr = *(const f16x8*)((char*)s_rec + l15 * 272 + ks * 64 + lk * 16);
            f16x8 bfr = *(const f16x8*)(f1h + ((size_t)c1 * 4 + ks) * 32 + lk * 8);
            a1 = __builtin_amdgcn_mfma_f32_16x16x32_f16(afr, bfr, a1, 0, 0, 0);
        }
        float bb = fb1[c1];
#pragma unroll
        for (int reg = 0; reg < 4; ++reg) {
            int row = lk * 4 + reg;   // rows 8-15 garbage, discarded downstream
            s_hh[row * 72 + c1] = (f16)gelu_f(a1[reg] + bb);
        }
    }
    __syncthreads();

    // ---- ffn2 (MFMA): h[16][64] @ f2[64][odim] -> out ----
    if (!out_nchw) {
        // level1: odim=128, f16 NHWC out, +residual (recon)
        f32x4 a2[2];
        a2[0] = (f32x4){0.f, 0.f, 0.f, 0.f};
        a2[1] = (f32x4){0.f, 0.f, 0.f, 0.f};
#pragma unroll
        for (int ks = 0; ks < 2; ++ks) {
            f16x8 afr = *(const f16x8*)((char*)s_hh + l15 * 144 + ks * 64 + lk * 16);
#pragma unroll
            for (int nt = 0; nt < 2; ++nt) {
                int col = wave * 32 + nt * 16 + l15;
                f16x8 bfr = *(const f16x8*)(f2h + ((size_t)col * 2 + ks) * 32 + lk * 8);
                a2[nt] = __builtin_amdgcn_mfma_f32_16x16x32_f16(afr, bfr, a2[nt], 0, 0, 0);
            }
        }
#pragma unroll
        for (int nt = 0; nt < 2; ++nt) {
            int col = wave * 32 + nt * 16 + l15;
            float bb = fb2[col];
#pragma unroll
            for (int reg = 0; reg < 4; ++reg) {
                int q = lk * 4 + reg;
                if (q < 8) {
                    int n = n0 + q;
                    int qy = n / Wq, qx = n - qy * Wq;
                    float val = a2[nt][reg] + bb;
                    if (residual) val += (float)s_rec[q * 136 + col];
                    out16[((size_t)(b * Hq + qy) * Wq + qx) * 128 + col] = (f16)val;
                }
            }
        }
    } else {
        // level2: odim=31 (pad 32), fp32 NCHW out, +lms
        if (wave < 2) {
            f32x4 a2 = (f32x4){0.f, 0.f, 0.f, 0.f};
#pragma unroll
            for (int ks = 0; ks < 2; ++ks) {
                f16x8 afr = *(const f16x8*)((char*)s_hh + l15 * 144 + ks * 64 + lk * 16);
                int col = wave * 16 + l15;
                f16x8 bfr = *(const f16x8*)(f2h + ((size_t)col * 2 + ks) * 32 + lk * 8);
                a2 = __builtin_amdgcn_mfma_f32_16x16x32_f16(afr, bfr, a2, 0, 0, 0);
            }
            int d = wave * 16 + l15;
            if (d < odim) {
                float bb = fb2[d];
#pragma unroll
                for (int reg = 0; reg < 4; ++reg) {
                    int q = lk * 4 + reg;
                    if (q < 8) {
                        int n = n0 + q;
                        int qy = n / Wq, qx = n - qy * Wq;
                        size_t oi = (((size_t)b * odim + d) * Hq + qy) * Wq + qx;
                        outf[oi] = a2[reg] + bb + lms[oi];
                    }
                }
            }
        }
    }
}

// ---- workspace byte offsets ----
#define WPACK_B   0ull
#define CC_B      5529600ull
#define SPEIN_B   (CC_B)
#define X2_B      (CC_B + 331776ull)
#define R2_B      (CC_B + 1658880ull)
#define T2_B      (CC_B + 2985984ull)
#define RH_B      14450688ull
#define TH_B      32292864ull
#define XH_B      50135040ull
#define G32_B     (TH_B)                    // f16 [16,32,32,128] 4194304
#define G16_B     (TH_B + 4194304ull)       // f16 [16,16,16,128] 1048576
#define L1T_B     (TH_B + 5242880ull)       // f16 [16,32,32,128] 4194304
#define LRSPE_B   (CC_B + 4313088ull)       // f16 [16,16,16,128] 1048576
#define HR16_B    67977216ull               // f16 [16,64,64,128] 16777216
#define LVLW_B    101531648ull
#define L1IMW_B   (LVLW_B)
#define L1W1_B    (LVLW_B + 212992ull)
#define L1W2_B    (LVLW_B + 229376ull)
#define L1F1_B    (LVLW_B + 245760ull)
#define L1F2_B    (LVLW_B + 262144ull)
#define L2IMW_B   (LVLW_B + 278528ull)
#define L2W1_B    (LVLW_B + 491520ull)
#define L2W2_B    (LVLW_B + 507904ull)
#define L2F1_B    (LVLW_B + 524288ull)
#define L2F2_B    (LVLW_B + 540672ull)

extern "C" void kernel_launch(void* const* d_in, const int* in_sizes, int n_in,
                              void* d_out, int out_size, void* d_ws, size_t ws_size,
                              hipStream_t stream) {
    (void)in_sizes; (void)n_in; (void)out_size; (void)ws_size;
    const float* HR_MSI     = (const float*)d_in[0];
    const float* lms        = (const float*)d_in[1];
    const float* LR_HSI     = (const float*)d_in[2];
    const float* spa_head_w = (const float*)d_in[3];
    const float* spa_head_b = (const float*)d_in[4];
    const float* spa_res_w  = (const float*)d_in[5];
    const float* spa_res_b  = (const float*)d_in[6];
    const float* spa_tail_w = (const float*)d_in[7];
    const float* spa_tail_b = (const float*)d_in[8];
    const float* spe_head_w = (const float*)d_in[9];
    const float* spe_head_b = (const float*)d_in[10];
    const float* spe_res_w  = (const float*)d_in[11];
    const float* spe_res_b  = (const float*)d_in[12];
    const float* spe_tail_w = (const float*)d_in[13];
    const float* spe_tail_b = (const float*)d_in[14];
    const float* l1_w   = (const float*)d_in[15];
    const float* l1_b   = (const float*)d_in[16];
    const float* wg32_w1 = (const float*)d_in[17];
    const float* wg32_b1 = (const float*)d_in[18];
    const float* wg32_w2 = (const float*)d_in[19];
    const float* wg32_b2 = (const float*)d_in[20];
    const float* ffn32_w1 = (const float*)d_in[21];
    const float* ffn32_b1 = (const float*)d_in[22];
    const float* ffn32_w2 = (const float*)d_in[23];
    const float* ffn32_b2 = (const float*)d_in[24];
    const float* l2_w   = (const float*)d_in[25];
    const float* l2_b   = (const float*)d_in[26];
    const float* wg64_w1 = (const float*)d_in[27];
    const float* wg64_b1 = (const float*)d_in[28];
    const float* wg64_w2 = (const float*)d_in[29];
    const float* wg64_b2 = (const float*)d_in[30];
    const float* ffn64_w1 = (const float*)d_in[31];
    const float* ffn64_b1 = (const float*)d_in[32];
    const float* ffn64_w2 = (const float*)d_in[33];
    const float* ffn64_b2 = (const float*)d_in[34];

    char* ws = (char*)d_ws;
    f16* Wp      = (f16*)(ws + WPACK_B);
    f16* Cc      = (f16*)(ws + CC_B);
    f16* SPEin   = (f16*)(ws + SPEIN_B);
    f16* X2h     = (f16*)(ws + X2_B);
    f16* R2h     = (f16*)(ws + R2_B);
    f16* T2h     = (f16*)(ws + T2_B);
    f16* lrspe16 = (f16*)(ws + LRSPE_B);
    f16* Rh      = (f16*)(ws + RH_B);
    f16* Xh      = (f16*)(ws + XH_B);
    f16* Th      = (f16*)(ws + TH_B);
    f16* g32T    = (f16*)(ws + G32_B);
    f16* g16T    = (f16*)(ws + G16_B);
    f16* l1T16   = (f16*)(ws + L1T_B);
    f16* hr16    = (f16*)(ws + HR16_B);
    f16* l1imw = (f16*)(ws + L1IMW_B);
    f16* l1w1  = (f16*)(ws + L1W1_B);
    f16* l1w2  = (f16*)(ws + L1W2_B);
    f16* l1f1  = (f16*)(ws + L1F1_B);
    f16* l1f2  = (f16*)(ws + L1F2_B);
    f16* l2imw = (f16*)(ws + L2IMW_B);
    f16* l2w1  = (f16*)(ws + L2W1_B);
    f16* l2w2  = (f16*)(ws + L2W2_B);
    f16* l2f1  = (f16*)(ws + L2F1_B);
    f16* l2f2  = (f16*)(ws + L2F2_B);

    // zero padded fp16 regions (borders must be 0)
    hipMemsetAsync(ws + CC_B, 0, 8921088ull, stream);
    hipMemsetAsync(ws + RH_B, 0, 53526528ull, stream);

    // pack conv weights
    pack_w<<<288, 256, 0, stream>>>(spa_head_w, Wp + 0, 34, 2, 73728);
    pack_w<<<4608, 256, 0, stream>>>(spa_res_w, Wp + 73728, 128, 4, 1179648);
    pack_w<<<576, 256, 0, stream>>>(spa_tail_w, Wp + 1253376, 128, 4, 147456);
    pack_w<<<144, 256, 0, stream>>>(spe_head_w, Wp + 1400832, 31, 1, 36864);
    pack_w<<<4608, 256, 0, stream>>>(spe_res_w, Wp + 1437696, 128, 4, 1179648);
    pack_w<<<576, 256, 0, stream>>>(spe_tail_w, Wp + 2617344, 128, 4, 147456);

    // pack level MLP weights
    pack_lvl<<<416, 256, 0, stream>>>(l1_w, l1imw, 386, 256, 13);
    pack_lvl<<<32, 256, 0, stream>>>(wg32_w1, l1w1, 128, 64, 4);
    pack_lvl<<<32, 256, 0, stream>>>(wg32_w2, l1w2, 64, 128, 2);
    pack_lvl<<<32, 256, 0, stream>>>(ffn32_w1, l1f1, 128, 64, 4);
    pack_lvl<<<32, 256, 0, stream>>>(ffn32_w2, l1f2, 64, 128, 2);
    pack_lvl<<<416, 256, 0, stream>>>(l2_w, l2imw, 386, 256, 13);
    pack_lvl<<<32, 256, 0, stream>>>(wg64_w1, l2w1, 128, 64, 4);
    pack_lvl<<<32, 256, 0, stream>>>(wg64_w2, l2w2, 64, 128, 2);
    pack_lvl<<<32, 256, 0, stream>>>(ffn64_w1, l2f1, 128, 64, 4);
    pack_lvl<<<8, 256, 0, stream>>>(ffn64_w2, l2f2, 64, 31, 2);

    // ---- spatial EDSR ----
    build_cc<<<8704, 256, 0, stream>>>(HR_MSI, lms, Cc, 16 * 64 * 64 * 34);
    conv_mfma<66, 6, 2><<<512, 256, 0, stream>>>(Cc, 2, Wp + 0, spa_head_b,
                                                 nullptr, Xh, nullptr, 0);
    hipMemsetAsync(ws + SPEIN_B, 0, 5361664ull, stream);  // spe bufs + lrspe16
    hipMemcpyAsync(Rh, Xh, 17842176ull, hipMemcpyDeviceToDevice, stream);
    for (int i = 0; i < 4; ++i) {
        conv_mfma<66, 6, 2><<<512, 256, 0, stream>>>(
            Rh, 4, Wp + 73728 + (size_t)(2 * i) * 147456, spa_res_b + 2 * i * 128,
            nullptr, Th, nullptr, 1);
        conv_mfma<66, 6, 2><<<512, 256, 0, stream>>>(
            Th, 4, Wp + 73728 + (size_t)(2 * i + 1) * 147456, spa_res_b + (2 * i + 1) * 128,
            nullptr, Rh, nullptr, 2);
    }
    conv_mfma<66, 6, 2><<<512, 256, 0, stream>>>(Rh, 4, Wp + 1253376, spa_tail_b,
                                                 Xh, nullptr, hr16, 3);

    maxpool_nhwc<<<8192, 256, 0, stream>>>(hr16, g32T, 64, 64, 2, 2097152);
    maxpool_nhwc<<<2048, 256, 0, stream>>>(hr16, g16T, 64, 64, 4, 524288);

    // ---- spectral EDSR ----
    build_spe<<<496, 256, 0, stream>>>(LR_HSI, SPEin, 16 * 16 * 16 * 31);
    conv_mfma<18, 4, 4><<<64, 256, 0, stream>>>(SPEin, 1, Wp + 1400832, spe_head_b,
                                                nullptr, X2h, nullptr, 0);
    hipMemcpyAsync(R2h, X2h, 1327104ull, hipMemcpyDeviceToDevice, stream);
    for (int i = 0; i < 4; ++i) {
        conv_mfma<18, 4, 4><<<64, 256, 0, stream>>>(
            R2h, 4, Wp + 1437696 + (size_t)(2 * i) * 147456, spe_res_b + 2 * i * 128,
            nullptr, T2h, nullptr, 1);
        conv_mfma<18, 4, 4><<<64, 256, 0, stream>>>(
            T2h, 4, Wp + 1437696 + (size_t)(2 * i + 1) * 147456, spe_res_b + (2 * i + 1) * 128,
            nullptr, R2h, nullptr, 2);
    }
    conv_mfma<18, 4, 4><<<64, 256, 0, stream>>>(R2h, 4, Wp + 2617344, spe_tail_b,
                                                X2h, nullptr, lrspe16, 3);

    // ---- level 1: 32x32 queries -> l1T16 f16 ----
    level_kernel<<<2048, 256, 0, stream>>>(
        lrspe16, 16, 16, g32T, 32, 32, g16T, 16, 16,
        32, 32, 128,
        l1imw, l1_b, l1w1, wg32_b1, l1w2, wg32_b2,
        l1f1, ffn32_b1, l1f2, ffn32_b2,
        128, 1, 0, nullptr, l1T16, nullptr);

    // ---- level 2: 64x64 queries, + lms, fp32 NCHW to d_out ----
    level_kernel<<<8192, 256, 0, stream>>>(
        l1T16, 32, 32, hr16, 64, 64, g32T, 32, 32,
        64, 64, 512,
        l2imw, l2_b, l2w1, wg64_b1, l2w2, wg64_b2,
        l2f1, ffn64_b1, l2f2, ffn64_b2,
        31, 0, 1, lms, nullptr, (float*)d_out);
}

// Round 7
// 1061.790 us; speedup vs baseline: 8.1492x; 1.0949x over previous
//
#include <hip/hip_runtime.h>
#include <math.h>

typedef _Float16 f16;
typedef __attribute__((ext_vector_type(4))) _Float16 f16x4;
typedef __attribute__((ext_vector_type(8))) _Float16 f16x8;
typedef __attribute__((ext_vector_type(4))) float f32x4;
typedef __attribute__((ext_vector_type(4))) unsigned int u32x4;

// exact-GELU via Abramowitz-Stegun 7.1.26 erf (|err| <= 1.5e-7)
__device__ __forceinline__ float gelu_f(float x) {
    float xs = x * 0.70710678118654752440f;
    float ax = fabsf(xs);
    float t = __builtin_amdgcn_rcpf(1.0f + 0.3275911f * ax);
    float p = t * (0.254829592f + t * (-0.284496736f + t * (1.421413741f +
              t * (-1.453152027f + t * 1.061405429f))));
    float erfv = 1.0f - p * __expf(-ax * ax);
    erfv = copysignf(erfv, xs);
    return 0.5f * x * (1.0f + erfv);
}

__device__ __forceinline__ void nsamp(float cy, float cx, int hi, int wi,
                                      int& iy, int& ix, bool& valid) {
    float fy = rintf(((cy + 1.0f) * (float)hi - 1.0f) * 0.5f);
    float fx = rintf(((cx + 1.0f) * (float)wi - 1.0f) * 0.5f);
    valid = (fy >= 0.0f) && (fy < (float)hi) && (fx >= 0.0f) && (fx < (float)wi);
    iy = (int)fminf(fmaxf(fy, 0.0f), (float)(hi - 1));
    ix = (int)fminf(fmaxf(fx, 0.0f), (float)(wi - 1));
}

// ---- conv weight pre-pack: OIHW fp32 -> [conv][cout][chunk][tap][ci32] fp16 ----
__global__ __launch_bounds__(256) void pack_w(
    const float* __restrict__ src, f16* __restrict__ dst,
    int Cin, int NCHUNK, int total) {
    int i = blockIdx.x * 256 + threadIdx.x;
    if (i >= total) return;
    int ci = i & 31;
    int tap = (i >> 5) % 9;
    int q = i / 288;
    int chunk = q % NCHUNK;
    int q2 = q / NCHUNK;
    int cout = q2 & 127;
    int conv = q2 >> 7;
    int cin = chunk * 32 + ci;
    float v = (cin < Cin) ? src[((size_t)(conv * 128 + cout) * Cin + cin) * 9 + tap] : 0.f;
    dst[i] = (f16)v;
}

// ---- level MLP weight pack: src fp32 [K][N] -> dst fp16 [N][NC][32] ----
__global__ __launch_bounds__(256) void pack_lvl(
    const float* __restrict__ src, f16* __restrict__ dst,
    int Ksrc, int N, int NC) {
    int i = blockIdx.x * 256 + threadIdx.x;
    if (i >= N * NC * 32) return;
    int kk = i & 31;
    int c = (i >> 5) % NC;
    int n = i / (32 * NC);
    int k = c * 32 + kk;
    dst[i] = (f16)((k < Ksrc) ? src[(size_t)k * N + n] : 0.f);
}

// concat(HR_MSI, lms) -> padded NHWC fp16 [16][66][66][64]
__global__ __launch_bounds__(256) void build_cc(
    const float* __restrict__ msi, const float* __restrict__ lms,
    f16* __restrict__ out, int total) {
    int i = blockIdx.x * 256 + threadIdx.x;
    if (i >= total) return;
    int ch = i % 34;
    int p = i / 34;
    int x = p & 63, y = (p >> 6) & 63, b = p >> 12;
    float v = (ch < 3) ? msi[(((size_t)(b * 3 + ch) << 6) + y << 6) + x]
                       : lms[(((size_t)(b * 31 + ch - 3) << 6) + y << 6) + x];
    out[((size_t)(b * 66 + y + 1) * 66 + x + 1) * 64 + ch] = v;
}

// LR_HSI -> padded NHWC fp16 [16][18][18][32]
__global__ __launch_bounds__(256) void build_spe(
    const float* __restrict__ in, f16* __restrict__ out, int total) {
    int i = blockIdx.x * 256 + threadIdx.x;
    if (i >= total) return;
    int ch = i % 31;
    int p = i / 31;
    int x = p & 15, y = (p >> 4) & 15, b = p >> 8;
    out[((size_t)(b * 18 + y + 1) * 18 + x + 1) * 32 + ch] =
        (f16)in[(((size_t)(b * 31 + ch) << 4) + y << 4) + x];
}

// ---- implicit-GEMM conv3x3 SAME, NHWC fp16 padded in, Cout=128 ----
// Block: ROWS*XW px x 128 cout; WAVES waves = 2 (M halves) x WN (N split).
// mode: 0 plain->out_h, 1 relu->out_h, 2 self-add, 3 tail (+skip -> out2 unpadded),
//       4 dual write (out_h and out2, both padded)
template<int PXW, int XSH, int ROWS, int WAVES>
__global__ __launch_bounds__(WAVES * 64) void conv_mfma(
    const f16* __restrict__ in_h, int NCHUNK,
    const f16* __restrict__ wp, const float* __restrict__ bias,
    const f16* __restrict__ skip_h, f16* __restrict__ out_h,
    f16* __restrict__ out2, int mode) {
    constexpr int XW = 1 << XSH;
    constexpr int PH = XW + 2;
    constexpr int NPX = (ROWS + 2) * PXW;
    constexpr int UNITS = NPX * 4;
    constexpr int NTH = WAVES * 64;
    constexpr int ITER = (UNITS + NTH - 1) / NTH;
    constexpr int WN = WAVES / 2;   // waves along N
    constexpr int NT = 8 / WN;      // 16-col tiles per wave
    constexpr int MT = (ROWS << XSH) >> 5;  // 16-row tiles per wave (per M half)
    __shared__ u32x4 ldsv[UNITS];
    char* ldsb = (char*)ldsv;

    int tid = threadIdx.x;
    constexpr int NYB = XW / ROWS;
    int b = blockIdx.x / NYB;
    int y0 = (blockIdx.x % NYB) * ROWS;
    int wave = tid >> 6, lane = tid & 63;
    int wm = wave / WN, wn = wave % WN;
    int l15 = lane & 15, lk = lane >> 4;
    int CST = NCHUNK * 32;

    int gaddr[ITER], laddr[ITER];
#pragma unroll
    for (int i = 0; i < ITER; ++i) {
        int u = tid + NTH * i;
        if (u < UNITS) {
            int px = u >> 2, kg = u & 3;
            int r = px / PXW, xp = px - r * PXW;
            gaddr[i] = ((b * PH + y0 + r) * PXW + xp) * CST + kg * 8;
            laddr[i] = (u * 16) ^ (((px >> 1) & 3) << 4);
        } else {
            gaddr[i] = -1; laddr[i] = 0;
        }
    }

    f32x4 acc[MT][NT];
#pragma unroll
    for (int mt = 0; mt < MT; ++mt)
#pragma unroll
        for (int nt = 0; nt < NT; ++nt)
            acc[mt][nt] = (f32x4){0.f, 0.f, 0.f, 0.f};

    u32x4 v[ITER];
#pragma unroll
    for (int i = 0; i < ITER; ++i)
        if (gaddr[i] >= 0) v[i] = *(const u32x4*)(in_h + gaddr[i]);

    for (int c = 0; c < NCHUNK; ++c) {
        if (c) __syncthreads();
#pragma unroll
        for (int i = 0; i < ITER; ++i)
            if (gaddr[i] >= 0) *(u32x4*)(ldsb + laddr[i]) = v[i];
        __syncthreads();
        if (c + 1 < NCHUNK) {
#pragma unroll
            for (int i = 0; i < ITER; ++i)
                if (gaddr[i] >= 0) v[i] = *(const u32x4*)(in_h + gaddr[i] + (c + 1) * 32);
        }
#pragma unroll
        for (int tap = 0; tap < 9; ++tap) {
            const int dy = tap / 3, dx = tap % 3;
            f16x8 afr[MT];
#pragma unroll
            for (int mt = 0; mt < MT; ++mt) {
                int px = (wm * MT + mt) * 16 + l15;
                int row = px >> XSH, x = px & (XW - 1);
                int pxl = (row + dy) * PXW + x + dx;
                int la = pxl * 64 + lk * 16;
                afr[mt] = *(const f16x8*)(ldsb + (la ^ (((pxl >> 1) & 3) << 4)));
            }
#pragma unroll
            for (int nt = 0; nt < NT; ++nt) {
                int cout = wn * (NT * 16) + nt * 16 + l15;
                f16x8 bfr = *(const f16x8*)(wp + ((size_t)(cout * NCHUNK + c) * 9 + tap) * 32 + lk * 8);
#pragma unroll
                for (int mt = 0; mt < MT; ++mt)
                    acc[mt][nt] = __builtin_amdgcn_mfma_f32_16x16x32_f16(afr[mt], bfr, acc[mt][nt], 0, 0, 0);
            }
        }
    }

#pragma unroll
    for (int mt = 0; mt < MT; ++mt)
#pragma unroll
        for (int nt = 0; nt < NT; ++nt) {
            int cout = wn * (NT * 16) + nt * 16 + l15;
            float bv = bias[cout];
#pragma unroll
            for (int reg = 0; reg < 4; ++reg) {
                int px = (wm * MT + mt) * 16 + lk * 4 + reg;
                int row = px >> XSH, x = px & (XW - 1);
                int yim = y0 + row;
                float vv = acc[mt][nt][reg] + bv;
                size_t ah = ((size_t)(b * PH + yim + 1) * PXW + x + 1) * 128 + cout;
                if (mode == 1) vv = fmaxf(vv, 0.f);
                if (mode == 2) vv += (float)out_h[ah];
                if (mode == 3) {
                    vv += (float)skip_h[ah];
                    out2[((size_t)((b << XSH) + yim) << XSH | x) * 128 + cout] = (f16)vv;
                } else if (mode == 4) {
                    f16 hv = (f16)vv;
                    out_h[ah] = hv;
                    out2[ah] = hv;
                } else {
                    out_h[ah] = (f16)vv;
                }
            }
        }
}

// max pool kxk stride k on NHWC f16 (C=128)
__global__ __launch_bounds__(256) void maxpool_nhwc(
    const f16* __restrict__ in, f16* __restrict__ out,
    int H, int W, int k, int total) {
    int i = blockIdx.x * 256 + threadIdx.x;
    if (i >= total) return;
    int c = i & 127;
    int r = i >> 7;
    int Wo = W / k, Ho = H / k;
    int x = r % Wo; r /= Wo;
    int y = r % Ho;
    int b = r / Ho;
    float m = -3.402823466e38f;
    for (int dy = 0; dy < k; ++dy)
        for (int dx = 0; dx < k; ++dx)
            m = fmaxf(m, (float)in[((size_t)(b * H + y * k + dy) * W + x * k + dx) * 128 + c]);
    out[i] = (f16)m;
}

// ---- Fused level(), all-MFMA version. 8 queries/block, 256 threads. ----
__global__ __launch_bounds__(256) void level_kernel(
    const f16* __restrict__ featT, int fh, int fw,
    const f16* __restrict__ guideT, int Hg, int Wg,
    const f16* __restrict__ glrT, int hl, int wl,
    int Hq, int Wq, int n_per_b,
    const f16* __restrict__ imw_h, const float* __restrict__ imb,
    const f16* __restrict__ w1h, const float* __restrict__ b1,
    const f16* __restrict__ w2h, const float* __restrict__ b2,
    const f16* __restrict__ f1h, const float* __restrict__ fb1,
    const f16* __restrict__ f2h, const float* __restrict__ fb2,
    int odim, int residual, int out_nchw,
    const float* __restrict__ lms,
    f16* __restrict__ out16, float* __restrict__ outf) {
    __shared__ char smem[31488];
    f16* s_inp  = (f16*)smem;            // [32][424]
    f16* s_pred = (f16*)smem;            // [64][136] overlay
    f16* s_h1   = (f16*)(smem + 17408);  // [64][72]
    f16* s_hh   = (f16*)smem;            // [16][72] overlay (after s_pred dead)
    f16* s_rec  = (f16*)(smem + 27136);  // [16][136]

    int tid = threadIdx.x;
    int b = blockIdx.x / n_per_b;
    int n0 = (blockIdx.x % n_per_b) * 8;
    float invHq = 1.0f / (float)Hq, invWq = 1.0f / (float)Wq;
    float invfh = 1.0f / (float)fh, invfw = 1.0f / (float)fw;
    int wave = tid >> 6, lane = tid & 63;
    int l15 = lane & 15, lk = lane >> 4;

    // ---- gather: build s_inp[32][424] fp16 ----
    {
        const int r32 = tid >> 3, t8 = tid & 7;
        const int cidx = r32 >> 3, q = r32 & 7;
        int n = n0 + q;
        int qy = n / Wq, qx = n - qy * Wq;
        float cy = -1.0f + (float)(2 * qy + 1) * invHq;
        float cx = -1.0f + (float)(2 * qx + 1) * invWq;
        float vxc = (cidx < 2) ? -1.0f : 1.0f;
        float vyc = (cidx & 1) ? 1.0f : -1.0f;
        float cy_ = cy + vxc * invfh;
        float cx_ = cx + vyc * invfw;
        int iy, ix; bool vf;
        nsamp(cy_, cx_, fh, fw, iy, ix, vf);
        const f16* fp = featT + ((size_t)(b * fh + iy) * fw + ix) * 128;
        int gy, gx; bool vg0;
        nsamp(cy, cx, Hg, Wg, gy, gx, vg0);
        const f16* gp = guideT + ((size_t)(b * Hg + gy) * Wg + gx) * 128;
        int ly, lx; bool vl;
        nsamp(cy_, cx_, hl, wl, ly, lx, vl);
        const f16* lp = glrT + ((size_t)(b * hl + ly) * wl + lx) * 128;
        f16* row = s_inp + r32 * 424;
        const u32x4 zz = (u32x4){0, 0, 0, 0};
#pragma unroll
        for (int e = 0; e < 2; ++e) {
            int d0 = t8 * 8 + e * 64;
            u32x4 av = vf ? *(const u32x4*)(fp + d0) : zz;
            u32x4 gv = vg0 ? *(const u32x4*)(gp + d0) : zz;
            u32x4 lv = vl ? *(const u32x4*)(lp + d0) : zz;
            *(u32x4*)(row + d0) = av;
            *(u32x4*)(row + 128 + d0) = gv;
            *(u32x4*)(row + 256 + d0) = lv;
        }
        if (t8 == 0) {
#pragma unroll
            for (int e = 0; e < 4; ++e)
                *(u32x4*)((char*)row + 768 + e * 16) = zz;
            float csy = vf ? (-1.0f + (float)(2 * iy + 1) * invfh) : 0.0f;
            float csx = vf ? (-1.0f + (float)(2 * ix + 1) * invfw) : 0.0f;
            row[384] = (f16)((cy - csy) * (float)fh);
            row[385] = (f16)((cx - csx) * (float)fw);
        }
    }
    __syncthreads();

    // ---- corner GEMM: 32x416 @ 416x256 ----
    f32x4 acc[2][4];
    {
#pragma unroll
        for (int mt = 0; mt < 2; ++mt)
#pragma unroll
            for (int nt = 0; nt < 4; ++nt)
                acc[mt][nt] = (f32x4){0.f, 0.f, 0.f, 0.f};
        int nbase = wave * 64;
#pragma unroll
        for (int ks = 0; ks < 13; ++ks) {
            f16x8 afr[2];
#pragma unroll
            for (int mt = 0; mt < 2; ++mt)
                afr[mt] = *(const f16x8*)((char*)s_inp + (mt * 16 + l15) * 848 + ks * 64 + lk * 16);
#pragma unroll
            for (int nt = 0; nt < 4; ++nt) {
                f16x8 bfr = *(const f16x8*)(imw_h + ((size_t)(nbase + nt * 16 + l15) * 13 + ks) * 32 + lk * 8);
                acc[0][nt] = __builtin_amdgcn_mfma_f32_16x16x32_f16(afr[0], bfr, acc[0][nt], 0, 0, 0);
                acc[1][nt] = __builtin_amdgcn_mfma_f32_16x16x32_f16(afr[1], bfr, acc[1][nt], 0, 0, 0);
            }
        }
    }
    __syncthreads();

    // ---- epilogue: bias + relu -> s_pred fp16 [qj][128] (overlay) ----
    {
        int nbase = wave * 64;
#pragma unroll
        for (int nt = 0; nt < 4; ++nt) {
            int col = nbase + nt * 16 + l15;
            float bv = imb[col];
            int j_hi = col >> 7, d = col & 127;
#pragma unroll
            for (int mt = 0; mt < 2; ++mt)
#pragma unroll
                for (int reg = 0; reg < 4; ++reg) {
                    int row32 = mt * 16 + lk * 4 + reg;
                    int q = row32 & 7, cidx = row32 >> 3;
                    int qj = q * 8 + cidx * 2 + j_hi;
                    s_pred[qj * 136 + d] = (f16)fmaxf(acc[mt][nt][reg] + bv, 0.f);
                }
        }
    }
    __syncthreads();

    // ---- wg1: preds[64][128] @ w1[128][64] -> h1 fp16 ----
    {
        f32x4 a1[4];
#pragma unroll
        for (int mt = 0; mt < 4; ++mt) a1[mt] = (f32x4){0.f, 0.f, 0.f, 0.f};
        int c1 = wave * 16 + l15;
#pragma unroll
        for (int ks = 0; ks < 4; ++ks) {
            f16x8 bfr = *(const f16x8*)(w1h + ((size_t)c1 * 4 + ks) * 32 + lk * 8);
#pragma unroll
            for (int mt = 0; mt < 4; ++mt) {
                f16x8 afr = *(const f16x8*)((char*)s_pred + (mt * 16 + l15) * 272 + ks * 64 + lk * 16);
                a1[mt] = __builtin_amdgcn_mfma_f32_16x16x32_f16(afr, bfr, a1[mt], 0, 0, 0);
            }
        }
        float bb1 = b1[c1];
#pragma unroll
        for (int mt = 0; mt < 4; ++mt)
#pragma unroll
            for (int reg = 0; reg < 4; ++reg) {
                int row = mt * 16 + lk * 4 + reg;
                s_h1[row * 72 + c1] = (f16)gelu_f(a1[mt][reg] + bb1);
            }
    }
    __syncthreads();

    // ---- wg2 + softmax over j + recon -> s_rec f16 [16][136] ----
    {
        f32x4 a2[4][2];
#pragma unroll
        for (int mt = 0; mt < 4; ++mt) {
            a2[mt][0] = (f32x4){0.f, 0.f, 0.f, 0.f};
            a2[mt][1] = (f32x4){0.f, 0.f, 0.f, 0.f};
        }
#pragma unroll
        for (int ks = 0; ks < 2; ++ks) {
            f16x8 afr[4];
#pragma unroll
            for (int mt = 0; mt < 4; ++mt)
                afr[mt] = *(const f16x8*)((char*)s_h1 + (mt * 16 + l15) * 144 + ks * 64 + lk * 16);
#pragma unroll
            for (int nt = 0; nt < 2; ++nt) {
                int c2 = wave * 32 + nt * 16 + l15;
                f16x8 bfr = *(const f16x8*)(w2h + ((size_t)c2 * 2 + ks) * 32 + lk * 8);
#pragma unroll
                for (int mt = 0; mt < 4; ++mt)
                    a2[mt][nt] = __builtin_amdgcn_mfma_f32_16x16x32_f16(afr[mt], bfr, a2[mt][nt], 0, 0, 0);
            }
        }
        int qhalf = lk >> 1;
#pragma unroll
        for (int nt = 0; nt < 2; ++nt) {
            int col = wave * 32 + nt * 16 + l15;
            float bb2 = b2[col];
#pragma unroll
            for (int mt = 0; mt < 4; ++mt) {
                int q = mt * 2 + qhalf;
                float v[4];
                float mloc = -3.4e38f;
#pragma unroll
                for (int reg = 0; reg < 4; ++reg) {
                    v[reg] = a2[mt][nt][reg] + bb2;
                    mloc = fmaxf(mloc, v[reg]);
                }
                float mf = fmaxf(mloc, __shfl_xor(mloc, 16));
                float e[4], sl = 0.f;
#pragma unroll
                for (int reg = 0; reg < 4; ++reg) {
                    e[reg] = __expf(v[reg] - mf);
                    sl += e[reg];
                }
                float sf = sl + __shfl_xor(sl, 16);
                float inv = 1.0f / sf;
                float rp = 0.f;
#pragma unroll
                for (int reg = 0; reg < 4; ++reg) {
                    int row = mt * 16 + lk * 4 + reg;
                    rp += (float)s_pred[row * 136 + col] * e[reg];
                }
                rp *= inv;
                float rf = rp + __shfl_xor(rp, 16);
                if ((lk & 1) == 0) s_rec[q * 136 + col] = (f16)rf;
            }
        }
    }
    __syncthreads();

    // ---- ffn1 (MFMA): rec[16][128] @ f1[128][64] -> s_hh[16][64] f16 ----
    {
        f32x4 a1 = (f32x4){0.f, 0.f, 0.f, 0.f};
        int c1 = wave * 16 + l15;
#pragma unroll
        for (int ks = 0; ks < 4; ++ks) {
            f16x8 afr = *(const f16x8*)((char*)s_rec + l15 * 272 + ks * 64 + lk * 16);
            f16x8 bfr = *(const f16x8*)(f1h + ((size_t)c1 * 4 + ks) * 32 + lk * 8);
            a1 = __builtin_amdgcn_mfma_f32_16x16x32_f16(afr, bfr, a1, 0, 0, 0);
        }
        float bb = fb1[c1];
#pragma unroll
        for (int reg = 0; reg < 4; ++reg) {
            int row = lk * 4 + reg;
            s_hh[row * 72 + c1] = (f16)gelu_f(a1[reg] + bb);
        }
    }
    __syncthreads();

    // ---- ffn2 (MFMA): h[16][64] @ f2[64][odim] -> out ----
    if (!out_nchw) {
        f32x4 a2[2];
        a2[0] = (f32x4){0.f, 0.f, 0.f, 0.f};
        a2[1] = (f32x4){0.f, 0.f, 0.f, 0.f};
#pragma unroll
        for (int ks = 0; ks < 2; ++ks) {
            f16x8 afr = *(const f16x8*)((char*)s_hh + l15 * 144 + ks * 64 + lk * 16);
#pragma unroll
            for (int nt = 0; nt < 2; ++nt) {
                int col = wave * 32 + nt * 16 + l15;
                f16x8 bfr = *(const f16x8*)(f2h + ((size_t)col * 2 + ks) * 32 + lk * 8);
                a2[nt] = __builtin_amdgcn_mfma_f32_16x16x32_f16(afr, bfr, a2[nt], 0, 0, 0);
            }
        }
#pragma unroll
        for (int nt = 0; nt < 2; ++nt) {
            int col = wave * 32 + nt * 16 + l15;
            float bb = fb2[col];
#pragma unroll
            for (int reg = 0; reg < 4; ++reg) {
                int q = lk * 4 + reg;
                if (q < 8) {
                    int n = n0 + q;
                    int qy = n / Wq, qx = n - qy * Wq;
                    float val = a2[nt][reg] + bb;
                    if (residual) val += (float)s_rec[q * 136 + col];
                    out16[((size_t)(b * Hq + qy) * Wq + qx) * 128 + col] = (f16)val;
                }
            }
        }
    } else {
        if (wave < 2) {
            f32x4 a2 = (f32x4){0.f, 0.f, 0.f, 0.f};
#pragma unroll
            for (int ks = 0; ks < 2; ++ks) {
                f16x8 afr = *(const f16x8*)((char*)s_hh + l15 * 144 + ks * 64 + lk * 16);
                int col = wave * 16 + l15;
                f16x8 bfr = *(const f16x8*)(f2h + ((size_t)col * 2 + ks) * 32 + lk * 8);
                a2 = __builtin_amdgcn_mfma_f32_16x16x32_f16(afr, bfr, a2, 0, 0, 0);
            }
            int d = wave * 16 + l15;
            if (d < odim) {
                float bb = fb2[d];
#pragma unroll
                for (int reg = 0; reg < 4; ++reg) {
                    int q = lk * 4 + reg;
                    if (q < 8) {
                        int n = n0 + q;
                        int qy = n / Wq, qx = n - qy * Wq;
                        size_t oi = (((size_t)b * odim + d) * Hq + qy) * Wq + qx;
                        outf[oi] = a2[reg] + bb + lms[oi];
                    }
                }
            }
        }
    }
}

// ---- workspace byte offsets ----
#define WPACK_B   0ull
#define CC_B      5529600ull
#define SPEIN_B   (CC_B)
#define X2_B      (CC_B + 331776ull)
#define R2_B      (CC_B + 1658880ull)
#define T2_B      (CC_B + 2985984ull)
#define RH_B      14450688ull
#define TH_B      32292864ull
#define XH_B      50135040ull
#define G32_B     (TH_B)
#define G16_B     (TH_B + 4194304ull)
#define L1T_B     (TH_B + 5242880ull)
#define LRSPE_B   (CC_B + 4313088ull)
#define HR16_B    67977216ull
#define LVLW_B    101531648ull
#define L1IMW_B   (LVLW_B)
#define L1W1_B    (LVLW_B + 212992ull)
#define L1W2_B    (LVLW_B + 229376ull)
#define L1F1_B    (LVLW_B + 245760ull)
#define L1F2_B    (LVLW_B + 262144ull)
#define L2IMW_B   (LVLW_B + 278528ull)
#define L2W1_B    (LVLW_B + 491520ull)
#define L2W2_B    (LVLW_B + 507904ull)
#define L2F1_B    (LVLW_B + 524288ull)
#define L2F2_B    (LVLW_B + 540672ull)

extern "C" void kernel_launch(void* const* d_in, const int* in_sizes, int n_in,
                              void* d_out, int out_size, void* d_ws, size_t ws_size,
                              hipStream_t stream) {
    (void)in_sizes; (void)n_in; (void)out_size; (void)ws_size;
    const float* HR_MSI     = (const float*)d_in[0];
    const float* lms        = (const float*)d_in[1];
    const float* LR_HSI     = (const float*)d_in[2];
    const float* spa_head_w = (const float*)d_in[3];
    const float* spa_head_b = (const float*)d_in[4];
    const float* spa_res_w  = (const float*)d_in[5];
    const float* spa_res_b  = (const float*)d_in[6];
    const float* spa_tail_w = (const float*)d_in[7];
    const float* spa_tail_b = (const float*)d_in[8];
    const float* spe_head_w = (const float*)d_in[9];
    const float* spe_head_b = (const float*)d_in[10];
    const float* spe_res_w  = (const float*)d_in[11];
    const float* spe_res_b  = (const float*)d_in[12];
    const float* spe_tail_w = (const float*)d_in[13];
    const float* spe_tail_b = (const float*)d_in[14];
    const float* l1_w   = (const float*)d_in[15];
    const float* l1_b   = (const float*)d_in[16];
    const float* wg32_w1 = (const float*)d_in[17];
    const float* wg32_b1 = (const float*)d_in[18];
    const float* wg32_w2 = (const float*)d_in[19];
    const float* wg32_b2 = (const float*)d_in[20];
    const float* ffn32_w1 = (const float*)d_in[21];
    const float* ffn32_b1 = (const float*)d_in[22];
    const float* ffn32_w2 = (const float*)d_in[23];
    const float* ffn32_b2 = (const float*)d_in[24];
    const float* l2_w   = (const float*)d_in[25];
    const float* l2_b   = (const float*)d_in[26];
    const float* wg64_w1 = (const float*)d_in[27];
    const float* wg64_b1 = (const float*)d_in[28];
    const float* wg64_w2 = (const float*)d_in[29];
    const float* wg64_b2 = (const float*)d_in[30];
    const float* ffn64_w1 = (const float*)d_in[31];
    const float* ffn64_b1 = (const float*)d_in[32];
    const float* ffn64_w2 = (const float*)d_in[33];
    const float* ffn64_b2 = (const float*)d_in[34];

    char* ws = (char*)d_ws;
    f16* Wp      = (f16*)(ws + WPACK_B);
    f16* Cc      = (f16*)(ws + CC_B);
    f16* SPEin   = (f16*)(ws + SPEIN_B);
    f16* X2h     = (f16*)(ws + X2_B);
    f16* R2h     = (f16*)(ws + R2_B);
    f16* T2h     = (f16*)(ws + T2_B);
    f16* lrspe16 = (f16*)(ws + LRSPE_B);
    f16* Rh      = (f16*)(ws + RH_B);
    f16* Xh      = (f16*)(ws + XH_B);
    f16* Th      = (f16*)(ws + TH_B);
    f16* g32T    = (f16*)(ws + G32_B);
    f16* g16T    = (f16*)(ws + G16_B);
    f16* l1T16   = (f16*)(ws + L1T_B);
    f16* hr16    = (f16*)(ws + HR16_B);
    f16* l1imw = (f16*)(ws + L1IMW_B);
    f16* l1w1  = (f16*)(ws + L1W1_B);
    f16* l1w2  = (f16*)(ws + L1W2_B);
    f16* l1f1  = (f16*)(ws + L1F1_B);
    f16* l1f2  = (f16*)(ws + L1F2_B);
    f16* l2imw = (f16*)(ws + L2IMW_B);
    f16* l2w1  = (f16*)(ws + L2W1_B);
    f16* l2w2  = (f16*)(ws + L2W2_B);
    f16* l2f1  = (f16*)(ws + L2F1_B);
    f16* l2f2  = (f16*)(ws + L2F2_B);

    // zero padded fp16 regions (borders + never-written channels must be 0)
    hipMemsetAsync(ws + CC_B, 0, 8921088ull, stream);
    hipMemsetAsync(ws + RH_B, 0, 53526528ull, stream);

    // pack conv weights
    pack_w<<<288, 256, 0, stream>>>(spa_head_w, Wp + 0, 34, 2, 73728);
    pack_w<<<4608, 256, 0, stream>>>(spa_res_w, Wp + 73728, 128, 4, 1179648);
    pack_w<<<576, 256, 0, stream>>>(spa_tail_w, Wp + 1253376, 128, 4, 147456);
    pack_w<<<144, 256, 0, stream>>>(spe_head_w, Wp + 1400832, 31, 1, 36864);
    pack_w<<<4608, 256, 0, stream>>>(spe_res_w, Wp + 1437696, 128, 4, 1179648);
    pack_w<<<576, 256, 0, stream>>>(spe_tail_w, Wp + 2617344, 128, 4, 147456);

    // pack level MLP weights
    pack_lvl<<<416, 256, 0, stream>>>(l1_w, l1imw, 386, 256, 13);
    pack_lvl<<<32, 256, 0, stream>>>(wg32_w1, l1w1, 128, 64, 4);
    pack_lvl<<<32, 256, 0, stream>>>(wg32_w2, l1w2, 64, 128, 2);
    pack_lvl<<<32, 256, 0, stream>>>(ffn32_w1, l1f1, 128, 64, 4);
    pack_lvl<<<32, 256, 0, stream>>>(ffn32_w2, l1f2, 64, 128, 2);
    pack_lvl<<<416, 256, 0, stream>>>(l2_w, l2imw, 386, 256, 13);
    pack_lvl<<<32, 256, 0, stream>>>(wg64_w1, l2w1, 128, 64, 4);
    pack_lvl<<<32, 256, 0, stream>>>(wg64_w2, l2w2, 64, 128, 2);
    pack_lvl<<<32, 256, 0, stream>>>(ffn64_w1, l2f1, 128, 64, 4);
    pack_lvl<<<8, 256, 0, stream>>>(ffn64_w2, l2f2, 64, 31, 2);

    // ---- spatial EDSR (512-thread blocks: 8 waves, 2M x 4N) ----
    build_cc<<<8704, 256, 0, stream>>>(HR_MSI, lms, Cc, 16 * 64 * 64 * 34);
    conv_mfma<66, 6, 2, 8><<<512, 512, 0, stream>>>(Cc, 2, Wp + 0, spa_head_b,
                                                    nullptr, Xh, Rh, 4);
    hipMemsetAsync(ws + SPEIN_B, 0, 5361664ull, stream);
    for (int i = 0; i < 4; ++i) {
        conv_mfma<66, 6, 2, 8><<<512, 512, 0, stream>>>(
            Rh, 4, Wp + 73728 + (size_t)(2 * i) * 147456, spa_res_b + 2 * i * 128,
            nullptr, Th, nullptr, 1);
        conv_mfma<66, 6, 2, 8><<<512, 512, 0, stream>>>(
            Th, 4, Wp + 73728 + (size_t)(2 * i + 1) * 147456, spa_res_b + (2 * i + 1) * 128,
            nullptr, Rh, nullptr, 2);
    }
    conv_mfma<66, 6, 2, 8><<<512, 512, 0, stream>>>(Rh, 4, Wp + 1253376, spa_tail_b,
                                                    Xh, nullptr, hr16, 3);

    maxpool_nhwc<<<8192, 256, 0, stream>>>(hr16, g32T, 64, 64, 2, 2097152);
    maxpool_nhwc<<<2048, 256, 0, stream>>>(hr16, g16T, 64, 64, 4, 524288);

    // ---- spectral EDSR ----
    build_spe<<<496, 256, 0, stream>>>(LR_HSI, SPEin, 16 * 16 * 16 * 31);
    conv_mfma<18, 4, 4, 4><<<64, 256, 0, stream>>>(SPEin, 1, Wp + 1400832, spe_head_b,
                                                   nullptr, X2h, R2h, 4);
    for (int i = 0; i < 4; ++i) {
        conv_mfma<18, 4, 4, 4><<<64, 256, 0, stream>>>(
            R2h, 4, Wp + 1437696 + (size_t)(2 * i) * 147456, spe_res_b + 2 * i * 128,
            nullptr, T2h, nullptr, 1);
        conv_mfma<18, 4, 4, 4><<<64, 256, 0, stream>>>(
            T2h, 4, Wp + 1437696 + (size_t)(2 * i + 1) * 147456, spe_res_b + (2 * i + 1) * 128,
            nullptr, R2h, nullptr, 2);
    }
    conv_mfma<18, 4, 4, 4><<<64, 256, 0, stream>>>(R2h, 4, Wp + 2617344, spe_tail_b,
                                                   X2h, nullptr, lrspe16, 3);

    // ---- level 1: 32x32 queries -> l1T16 f16 ----
    level_kernel<<<2048, 256, 0, stream>>>(
        lrspe16, 16, 16, g32T, 32, 32, g16T, 16, 16,
        32, 32, 128,
        l1imw, l1_b, l1w1, wg32_b1, l1w2, wg32_b2,
        l1f1, ffn32_b1, l1f2, ffn32_b2,
        128, 1, 0, nullptr, l1T16, nullptr);

    // ---- level 2: 64x64 queries, + lms, fp32 NCHW to d_out ----
    level_kernel<<<8192, 256, 0, stream>>>(
        l1T16, 32, 32, hr16, 64, 64, g32T, 32, 32,
        64, 64, 512,
        l2imw, l2_b, l2w1, wg64_b1, l2w2, wg64_b2,
        l2f1, ffn64_b1, l2f2, ffn64_b2,
        31, 0, 1, lms, nullptr, (float*)d_out);
}

// Round 8
// 1038.934 us; speedup vs baseline: 8.3285x; 1.0220x over previous
//
#include <hip/hip_runtime.h>
#include <math.h>

typedef _Float16 f16;
typedef __attribute__((ext_vector_type(4))) _Float16 f16x4;
typedef __attribute__((ext_vector_type(8))) _Float16 f16x8;
typedef __attribute__((ext_vector_type(4))) float f32x4;
typedef __attribute__((ext_vector_type(4))) unsigned int u32x4;

// exact-GELU via Abramowitz-Stegun 7.1.26 erf (|err| <= 1.5e-7)
__device__ __forceinline__ float gelu_f(float x) {
    float xs = x * 0.70710678118654752440f;
    float ax = fabsf(xs);
    float t = __builtin_amdgcn_rcpf(1.0f + 0.3275911f * ax);
    float p = t * (0.254829592f + t * (-0.284496736f + t * (1.421413741f +
              t * (-1.453152027f + t * 1.061405429f))));
    float erfv = 1.0f - p * __expf(-ax * ax);
    erfv = copysignf(erfv, xs);
    return 0.5f * x * (1.0f + erfv);
}

__device__ __forceinline__ void nsamp(float cy, float cx, int hi, int wi,
                                      int& iy, int& ix, bool& valid) {
    float fy = rintf(((cy + 1.0f) * (float)hi - 1.0f) * 0.5f);
    float fx = rintf(((cx + 1.0f) * (float)wi - 1.0f) * 0.5f);
    valid = (fy >= 0.0f) && (fy < (float)hi) && (fx >= 0.0f) && (fx < (float)wi);
    iy = (int)fminf(fmaxf(fy, 0.0f), (float)(hi - 1));
    ix = (int)fminf(fmaxf(fx, 0.0f), (float)(wi - 1));
}

// ---- conv weight pre-pack: OIHW fp32 -> [conv][cout][chunk][tap][ci32] fp16 ----
__global__ __launch_bounds__(256) void pack_w(
    const float* __restrict__ src, f16* __restrict__ dst,
    int Cin, int NCHUNK, int total) {
    int i = blockIdx.x * 256 + threadIdx.x;
    if (i >= total) return;
    int ci = i & 31;
    int tap = (i >> 5) % 9;
    int q = i / 288;
    int chunk = q % NCHUNK;
    int q2 = q / NCHUNK;
    int cout = q2 & 127;
    int conv = q2 >> 7;
    int cin = chunk * 32 + ci;
    float v = (cin < Cin) ? src[((size_t)(conv * 128 + cout) * Cin + cin) * 9 + tap] : 0.f;
    dst[i] = (f16)v;
}

// ---- level MLP weight pack: src fp32 [K][N] -> dst fp16 [N][NC][32] ----
__global__ __launch_bounds__(256) void pack_lvl(
    const float* __restrict__ src, f16* __restrict__ dst,
    int Ksrc, int N, int NC) {
    int i = blockIdx.x * 256 + threadIdx.x;
    if (i >= N * NC * 32) return;
    int kk = i & 31;
    int c = (i >> 5) % NC;
    int n = i / (32 * NC);
    int k = c * 32 + kk;
    dst[i] = (f16)((k < Ksrc) ? src[(size_t)k * N + n] : 0.f);
}

// concat(HR_MSI, lms) -> padded NHWC fp16 [16][66][66][64]
__global__ __launch_bounds__(256) void build_cc(
    const float* __restrict__ msi, const float* __restrict__ lms,
    f16* __restrict__ out, int total) {
    int i = blockIdx.x * 256 + threadIdx.x;
    if (i >= total) return;
    int ch = i % 34;
    int p = i / 34;
    int x = p & 63, y = (p >> 6) & 63, b = p >> 12;
    float v = (ch < 3) ? msi[(((size_t)(b * 3 + ch) << 6) + y << 6) + x]
                       : lms[(((size_t)(b * 31 + ch - 3) << 6) + y << 6) + x];
    out[((size_t)(b * 66 + y + 1) * 66 + x + 1) * 64 + ch] = v;
}

// LR_HSI -> padded NHWC fp16 [16][18][18][32]
__global__ __launch_bounds__(256) void build_spe(
    const float* __restrict__ in, f16* __restrict__ out, int total) {
    int i = blockIdx.x * 256 + threadIdx.x;
    if (i >= total) return;
    int ch = i % 31;
    int p = i / 31;
    int x = p & 15, y = (p >> 4) & 15, b = p >> 8;
    out[((size_t)(b * 18 + y + 1) * 18 + x + 1) * 32 + ch] =
        (f16)in[(((size_t)(b * 31 + ch) << 4) + y << 4) + x];
}

// ---- implicit-GEMM conv3x3 SAME, NHWC fp16 padded in, Cout=128 ----
template<int PXW, int XSH, int ROWS, int WAVES>
__global__ __launch_bounds__(WAVES * 64) void conv_mfma(
    const f16* __restrict__ in_h, int NCHUNK,
    const f16* __restrict__ wp, const float* __restrict__ bias,
    const f16* __restrict__ skip_h, f16* __restrict__ out_h,
    f16* __restrict__ out2, int mode) {
    constexpr int XW = 1 << XSH;
    constexpr int PH = XW + 2;
    constexpr int NPX = (ROWS + 2) * PXW;
    constexpr int UNITS = NPX * 4;
    constexpr int NTH = WAVES * 64;
    constexpr int ITER = (UNITS + NTH - 1) / NTH;
    constexpr int WN = WAVES / 2;
    constexpr int NT = 8 / WN;
    constexpr int MT = (ROWS << XSH) >> 5;
    __shared__ u32x4 ldsv[UNITS];
    char* ldsb = (char*)ldsv;

    int tid = threadIdx.x;
    constexpr int NYB = XW / ROWS;
    int b = blockIdx.x / NYB;
    int y0 = (blockIdx.x % NYB) * ROWS;
    int wave = tid >> 6, lane = tid & 63;
    int wm = wave / WN, wn = wave % WN;
    int l15 = lane & 15, lk = lane >> 4;
    int CST = NCHUNK * 32;

    int gaddr[ITER], laddr[ITER];
#pragma unroll
    for (int i = 0; i < ITER; ++i) {
        int u = tid + NTH * i;
        if (u < UNITS) {
            int px = u >> 2, kg = u & 3;
            int r = px / PXW, xp = px - r * PXW;
            gaddr[i] = ((b * PH + y0 + r) * PXW + xp) * CST + kg * 8;
            laddr[i] = (u * 16) ^ (((px >> 1) & 3) << 4);
        } else {
            gaddr[i] = -1; laddr[i] = 0;
        }
    }

    f32x4 acc[MT][NT];
#pragma unroll
    for (int mt = 0; mt < MT; ++mt)
#pragma unroll
        for (int nt = 0; nt < NT; ++nt)
            acc[mt][nt] = (f32x4){0.f, 0.f, 0.f, 0.f};

    u32x4 v[ITER];
#pragma unroll
    for (int i = 0; i < ITER; ++i)
        if (gaddr[i] >= 0) v[i] = *(const u32x4*)(in_h + gaddr[i]);

    for (int c = 0; c < NCHUNK; ++c) {
        if (c) __syncthreads();
#pragma unroll
        for (int i = 0; i < ITER; ++i)
            if (gaddr[i] >= 0) *(u32x4*)(ldsb + laddr[i]) = v[i];
        __syncthreads();
        if (c + 1 < NCHUNK) {
#pragma unroll
            for (int i = 0; i < ITER; ++i)
                if (gaddr[i] >= 0) v[i] = *(const u32x4*)(in_h + gaddr[i] + (c + 1) * 32);
        }
#pragma unroll
        for (int tap = 0; tap < 9; ++tap) {
            const int dy = tap / 3, dx = tap % 3;
            f16x8 afr[MT];
#pragma unroll
            for (int mt = 0; mt < MT; ++mt) {
                int px = (wm * MT + mt) * 16 + l15;
                int row = px >> XSH, x = px & (XW - 1);
                int pxl = (row + dy) * PXW + x + dx;
                int la = pxl * 64 + lk * 16;
                afr[mt] = *(const f16x8*)(ldsb + (la ^ (((pxl >> 1) & 3) << 4)));
            }
#pragma unroll
            for (int nt = 0; nt < NT; ++nt) {
                int cout = wn * (NT * 16) + nt * 16 + l15;
                f16x8 bfr = *(const f16x8*)(wp + ((size_t)(cout * NCHUNK + c) * 9 + tap) * 32 + lk * 8);
#pragma unroll
                for (int mt = 0; mt < MT; ++mt)
                    acc[mt][nt] = __builtin_amdgcn_mfma_f32_16x16x32_f16(afr[mt], bfr, acc[mt][nt], 0, 0, 0);
            }
        }
    }

#pragma unroll
    for (int mt = 0; mt < MT; ++mt)
#pragma unroll
        for (int nt = 0; nt < NT; ++nt) {
            int cout = wn * (NT * 16) + nt * 16 + l15;
            float bv = bias[cout];
#pragma unroll
            for (int reg = 0; reg < 4; ++reg) {
                int px = (wm * MT + mt) * 16 + lk * 4 + reg;
                int row = px >> XSH, x = px & (XW - 1);
                int yim = y0 + row;
                float vv = acc[mt][nt][reg] + bv;
                size_t ah = ((size_t)(b * PH + yim + 1) * PXW + x + 1) * 128 + cout;
                if (mode == 1) vv = fmaxf(vv, 0.f);
                if (mode == 2) vv += (float)out_h[ah];
                if (mode == 3) {
                    vv += (float)skip_h[ah];
                    out2[((size_t)((b << XSH) + yim) << XSH | x) * 128 + cout] = (f16)vv;
                } else if (mode == 4) {
                    f16 hv = (f16)vv;
                    out_h[ah] = hv;
                    out2[ah] = hv;
                } else {
                    out_h[ah] = (f16)vv;
                }
            }
        }
}

// max pool kxk stride k on NHWC f16 (C=128)
__global__ __launch_bounds__(256) void maxpool_nhwc(
    const f16* __restrict__ in, f16* __restrict__ out,
    int H, int W, int k, int total) {
    int i = blockIdx.x * 256 + threadIdx.x;
    if (i >= total) return;
    int c = i & 127;
    int r = i >> 7;
    int Wo = W / k, Ho = H / k;
    int x = r % Wo; r /= Wo;
    int y = r % Ho;
    int b = r / Ho;
    float m = -3.402823466e38f;
    for (int dy = 0; dy < k; ++dy)
        for (int dx = 0; dx < k; ++dx)
            m = fmaxf(m, (float)in[((size_t)(b * H + y * k + dy) * W + x * k + dx) * 128 + c]);
    out[i] = (f16)m;
}

// ---- Fused level(), all-MFMA, 16 queries/block, 256 threads. ----
// LDS map (58624 B):
//   [0, 54272)      s_inp[64][424]  -> overlay: s_pred[128][136] (34816) + s_h1[128][72] @34816
//                                   -> after wg2: s_hh[16][72] @0
//   [54272, 58624)  s_rec[16][136] f16 (all 16 rows real)
__global__ __launch_bounds__(256) void level_kernel(
    const f16* __restrict__ featT, int fh, int fw,
    const f16* __restrict__ guideT, int Hg, int Wg,
    const f16* __restrict__ glrT, int hl, int wl,
    int Hq, int Wq, int n_per_b,
    const f16* __restrict__ imw_h, const float* __restrict__ imb,
    const f16* __restrict__ w1h, const float* __restrict__ b1,
    const f16* __restrict__ w2h, const float* __restrict__ b2,
    const f16* __restrict__ f1h, const float* __restrict__ fb1,
    const f16* __restrict__ f2h, const float* __restrict__ fb2,
    int odim, int residual, int out_nchw,
    const float* __restrict__ lms,
    f16* __restrict__ out16, float* __restrict__ outf) {
    __shared__ char smem[58624];
    f16* s_inp  = (f16*)smem;            // [64][424]
    f16* s_pred = (f16*)smem;            // [128][136] overlay
    f16* s_h1   = (f16*)(smem + 34816);  // [128][72]
    f16* s_hh   = (f16*)smem;            // [16][72] overlay (after s_pred dead)
    f16* s_rec  = (f16*)(smem + 54272);  // [16][136]

    int tid = threadIdx.x;
    int b = blockIdx.x / n_per_b;
    int n0 = (blockIdx.x % n_per_b) * 16;
    float invHq = 1.0f / (float)Hq, invWq = 1.0f / (float)Wq;
    float invfh = 1.0f / (float)fh, invfw = 1.0f / (float)fw;
    int wave = tid >> 6, lane = tid & 63;
    int l15 = lane & 15, lk = lane >> 4;

    // ---- gather: build s_inp[64][424] fp16; row = (cidx, q), 4 threads/row ----
    {
        const int r64 = tid >> 2, t4 = tid & 3;
        const int cidx = r64 >> 4, q = r64 & 15;
        int n = n0 + q;
        int qy = n / Wq, qx = n - qy * Wq;
        float cy = -1.0f + (float)(2 * qy + 1) * invHq;
        float cx = -1.0f + (float)(2 * qx + 1) * invWq;
        float vxc = (cidx < 2) ? -1.0f : 1.0f;
        float vyc = (cidx & 1) ? 1.0f : -1.0f;
        float cy_ = cy + vxc * invfh;
        float cx_ = cx + vyc * invfw;
        int iy, ix; bool vf;
        nsamp(cy_, cx_, fh, fw, iy, ix, vf);
        const f16* fp = featT + ((size_t)(b * fh + iy) * fw + ix) * 128;
        int gy, gx; bool vg0;
        nsamp(cy, cx, Hg, Wg, gy, gx, vg0);
        const f16* gp = guideT + ((size_t)(b * Hg + gy) * Wg + gx) * 128;
        int ly, lx; bool vl;
        nsamp(cy_, cx_, hl, wl, ly, lx, vl);
        const f16* lp = glrT + ((size_t)(b * hl + ly) * wl + lx) * 128;
        f16* row = s_inp + r64 * 424;
        const u32x4 zz = (u32x4){0, 0, 0, 0};
#pragma unroll
        for (int e = 0; e < 4; ++e) {
            int d0 = t4 * 8 + e * 32;
            u32x4 av = vf ? *(const u32x4*)(fp + d0) : zz;
            u32x4 gv = vg0 ? *(const u32x4*)(gp + d0) : zz;
            u32x4 lv = vl ? *(const u32x4*)(lp + d0) : zz;
            *(u32x4*)(row + d0) = av;
            *(u32x4*)(row + 128 + d0) = gv;
            *(u32x4*)(row + 256 + d0) = lv;
        }
        if (t4 == 0) {
#pragma unroll
            for (int e = 0; e < 4; ++e)
                *(u32x4*)((char*)row + 768 + e * 16) = zz;
            float csy = vf ? (-1.0f + (float)(2 * iy + 1) * invfh) : 0.0f;
            float csx = vf ? (-1.0f + (float)(2 * ix + 1) * invfw) : 0.0f;
            row[384] = (f16)((cy - csy) * (float)fh);
            row[385] = (f16)((cx - csx) * (float)fw);
        }
    }
    __syncthreads();

    // ---- corner GEMM: 64x416 @ 416x256 ----
    f32x4 acc[4][4];
    {
#pragma unroll
        for (int mt = 0; mt < 4; ++mt)
#pragma unroll
            for (int nt = 0; nt < 4; ++nt)
                acc[mt][nt] = (f32x4){0.f, 0.f, 0.f, 0.f};
        int nbase = wave * 64;
#pragma unroll
        for (int ks = 0; ks < 13; ++ks) {
            f16x8 afr[4];
#pragma unroll
            for (int mt = 0; mt < 4; ++mt)
                afr[mt] = *(const f16x8*)((char*)s_inp + (mt * 16 + l15) * 848 + ks * 64 + lk * 16);
#pragma unroll
            for (int nt = 0; nt < 4; ++nt) {
                f16x8 bfr = *(const f16x8*)(imw_h + ((size_t)(nbase + nt * 16 + l15) * 13 + ks) * 32 + lk * 8);
#pragma unroll
                for (int mt = 0; mt < 4; ++mt)
                    acc[mt][nt] = __builtin_amdgcn_mfma_f32_16x16x32_f16(afr[mt], bfr, acc[mt][nt], 0, 0, 0);
            }
        }
    }
    __syncthreads();  // s_inp reads complete; region may be overlaid

    // ---- epilogue: bias + relu -> s_pred fp16 [qj][128] ----
    {
        int nbase = wave * 64;
#pragma unroll
        for (int nt = 0; nt < 4; ++nt) {
            int col = nbase + nt * 16 + l15;
            float bv = imb[col];
            int j_hi = col >> 7, d = col & 127;
#pragma unroll
            for (int mt = 0; mt < 4; ++mt)
#pragma unroll
                for (int reg = 0; reg < 4; ++reg) {
                    int row64 = mt * 16 + lk * 4 + reg;
                    int q = row64 & 15, cidx = row64 >> 4;
                    int qj = q * 8 + cidx * 2 + j_hi;
                    s_pred[qj * 136 + d] = (f16)fmaxf(acc[mt][nt][reg] + bv, 0.f);
                }
        }
    }
    __syncthreads();

    // ---- wg1: preds[128][128] @ w1[128][64] -> h1 fp16 [128][72] ----
    {
        f32x4 a1[8];
#pragma unroll
        for (int mt = 0; mt < 8; ++mt) a1[mt] = (f32x4){0.f, 0.f, 0.f, 0.f};
        int c1 = wave * 16 + l15;
#pragma unroll
        for (int ks = 0; ks < 4; ++ks) {
            f16x8 bfr = *(const f16x8*)(w1h + ((size_t)c1 * 4 + ks) * 32 + lk * 8);
#pragma unroll
            for (int mt = 0; mt < 8; ++mt) {
                f16x8 afr = *(const f16x8*)((char*)s_pred + (mt * 16 + l15) * 272 + ks * 64 + lk * 16);
                a1[mt] = __builtin_amdgcn_mfma_f32_16x16x32_f16(afr, bfr, a1[mt], 0, 0, 0);
            }
        }
        float bb1 = b1[c1];
#pragma unroll
        for (int mt = 0; mt < 8; ++mt)
#pragma unroll
            for (int reg = 0; reg < 4; ++reg) {
                int row = mt * 16 + lk * 4 + reg;
                s_h1[row * 72 + c1] = (f16)gelu_f(a1[mt][reg] + bb1);
            }
    }
    __syncthreads();

    // ---- wg2 + softmax over j + recon -> s_rec f16 [16][136] ----
    {
        f32x4 a2[8][2];
#pragma unroll
        for (int mt = 0; mt < 8; ++mt) {
            a2[mt][0] = (f32x4){0.f, 0.f, 0.f, 0.f};
            a2[mt][1] = (f32x4){0.f, 0.f, 0.f, 0.f};
        }
#pragma unroll
        for (int ks = 0; ks < 2; ++ks) {
#pragma unroll
            for (int nt = 0; nt < 2; ++nt) {
                int c2 = wave * 32 + nt * 16 + l15;
                f16x8 bfr = *(const f16x8*)(w2h + ((size_t)c2 * 2 + ks) * 32 + lk * 8);
#pragma unroll
                for (int mt = 0; mt < 8; ++mt) {
                    f16x8 afr = *(const f16x8*)((char*)s_h1 + (mt * 16 + l15) * 144 + ks * 64 + lk * 16);
                    a2[mt][nt] = __builtin_amdgcn_mfma_f32_16x16x32_f16(afr, bfr, a2[mt][nt], 0, 0, 0);
                }
            }
        }
        int qhalf = lk >> 1;
#pragma unroll
        for (int nt = 0; nt < 2; ++nt) {
            int col = wave * 32 + nt * 16 + l15;
            float bb2 = b2[col];
#pragma unroll
            for (int mt = 0; mt < 8; ++mt) {
                int q = mt * 2 + qhalf;
                float v[4];
                float mloc = -3.4e38f;
#pragma unroll
                for (int reg = 0; reg < 4; ++reg) {
                    v[reg] = a2[mt][nt][reg] + bb2;
                    mloc = fmaxf(mloc, v[reg]);
                }
                float mf = fmaxf(mloc, __shfl_xor(mloc, 16));
                float e[4], sl = 0.f;
#pragma unroll
                for (int reg = 0; reg < 4; ++reg) {
                    e[reg] = __expf(v[reg] - mf);
                    sl += e[reg];
                }
                float sf = sl + __shfl_xor(sl, 16);
                float inv = 1.0f / sf;
                float rp = 0.f;
#pragma unroll
                for (int reg = 0; reg < 4; ++reg) {
                    int row = mt * 16 + lk * 4 + reg;
                    rp += (float)s_pred[row * 136 + col] * e[reg];
                }
                rp *= inv;
                float rf = rp + __shfl_xor(rp, 16);
                if ((lk & 1) == 0) s_rec[q * 136 + col] = (f16)rf;
            }
        }
    }
    __syncthreads();  // s_pred/s_h1 dead; s_rec ready

    // ---- ffn1 (MFMA): rec[16][128] @ f1[128][64] -> s_hh[16][72] (all rows real) ----
    {
        f32x4 a1 = (f32x4){0.f, 0.f, 0.f, 0.f};
        int c1 = wave * 16 + l15;
#pragma unroll
        for (int ks = 0; ks < 4; ++ks) {
            f16x8 afr = *(const f16x8*)((char*)s_rec + l15 * 272 + ks * 64 + lk * 16);
            f16x8 bfr = *(const f16x8*)(f1h + ((size_t)c1 * 4 + ks) * 32 + lk * 8);
            a1 = __builtin_amdgcn_mfma_f32_16x16x32_f16(afr, bfr, a1, 0, 0, 0);
        }
        float bb = fb1[c1];
#pragma unroll
        for (int reg = 0; reg < 4; ++reg) {
            int row = lk * 4 + reg;
            s_hh[row * 72 + c1] = (f16)gelu_f(a1[reg] + bb);
        }
    }
    __syncthreads();

    // ---- ffn2 (MFMA): h[16][64] @ f2[64][odim] -> out ----
    if (!out_nchw) {
        f32x4 a2[2];
        a2[0] = (f32x4){0.f, 0.f, 0.f, 0.f};
        a2[1] = (f32x4){0.f, 0.f, 0.f, 0.f};
#pragma unroll
        for (int ks = 0; ks < 2; ++ks) {
            f16x8 afr = *(const f16x8*)((char*)s_hh + l15 * 144 + ks * 64 + lk * 16);
#pragma unroll
            for (int nt = 0; nt < 2; ++nt) {
                int col = wave * 32 + nt * 16 + l15;
                f16x8 bfr = *(const f16x8*)(f2h + ((size_t)col * 2 + ks) * 32 + lk * 8);
                a2[nt] = __builtin_amdgcn_mfma_f32_16x16x32_f16(afr, bfr, a2[nt], 0, 0, 0);
            }
        }
#pragma unroll
        for (int nt = 0; nt < 2; ++nt) {
            int col = wave * 32 + nt * 16 + l15;
            float bb = fb2[col];
#pragma unroll
            for (int reg = 0; reg < 4; ++reg) {
                int q = lk * 4 + reg;
                int n = n0 + q;
                int qy = n / Wq, qx = n - qy * Wq;
                float val = a2[nt][reg] + bb;
                if (residual) val += (float)s_rec[q * 136 + col];
                out16[((size_t)(b * Hq + qy) * Wq + qx) * 128 + col] = (f16)val;
            }
        }
    } else {
        if (wave < 2) {
            f32x4 a2 = (f32x4){0.f, 0.f, 0.f, 0.f};
#pragma unroll
            for (int ks = 0; ks < 2; ++ks) {
                f16x8 afr = *(const f16x8*)((char*)s_hh + l15 * 144 + ks * 64 + lk * 16);
                int col = wave * 16 + l15;
                f16x8 bfr = *(const f16x8*)(f2h + ((size_t)col * 2 + ks) * 32 + lk * 8);
                a2 = __builtin_amdgcn_mfma_f32_16x16x32_f16(afr, bfr, a2, 0, 0, 0);
            }
            int d = wave * 16 + l15;
            if (d < odim) {
                float bb = fb2[d];
#pragma unroll
                for (int reg = 0; reg < 4; ++reg) {
                    int q = lk * 4 + reg;
                    int n = n0 + q;
                    int qy = n / Wq, qx = n - qy * Wq;
                    size_t oi = (((size_t)b * odim + d) * Hq + qy) * Wq + qx;
                    outf[oi] = a2[reg] + bb + lms[oi];
                }
            }
        }
    }
}

// ---- workspace byte offsets ----
#define WPACK_B   0ull
#define CC_B      5529600ull
#define SPEIN_B   (CC_B)
#define X2_B      (CC_B + 331776ull)
#define R2_B      (CC_B + 1658880ull)
#define T2_B      (CC_B + 2985984ull)
#define RH_B      14450688ull
#define TH_B      32292864ull
#define XH_B      50135040ull
#define G32_B     (TH_B)
#define G16_B     (TH_B + 4194304ull)
#define L1T_B     (TH_B + 5242880ull)
#define LRSPE_B   (CC_B + 4313088ull)
#define HR16_B    67977216ull
#define LVLW_B    101531648ull
#define L1IMW_B   (LVLW_B)
#define L1W1_B    (LVLW_B + 212992ull)
#define L1W2_B    (LVLW_B + 229376ull)
#define L1F1_B    (LVLW_B + 245760ull)
#define L1F2_B    (LVLW_B + 262144ull)
#define L2IMW_B   (LVLW_B + 278528ull)
#define L2W1_B    (LVLW_B + 491520ull)
#define L2W2_B    (LVLW_B + 507904ull)
#define L2F1_B    (LVLW_B + 524288ull)
#define L2F2_B    (LVLW_B + 540672ull)

extern "C" void kernel_launch(void* const* d_in, const int* in_sizes, int n_in,
                              void* d_out, int out_size, void* d_ws, size_t ws_size,
                              hipStream_t stream) {
    (void)in_sizes; (void)n_in; (void)out_size; (void)ws_size;
    const float* HR_MSI     = (const float*)d_in[0];
    const float* lms        = (const float*)d_in[1];
    const float* LR_HSI     = (const float*)d_in[2];
    const float* spa_head_w = (const float*)d_in[3];
    const float* spa_head_b = (const float*)d_in[4];
    const float* spa_res_w  = (const float*)d_in[5];
    const float* spa_res_b  = (const float*)d_in[6];
    const float* spa_tail_w = (const float*)d_in[7];
    const float* spa_tail_b = (const float*)d_in[8];
    const float* spe_head_w = (const float*)d_in[9];
    const float* spe_head_b = (const float*)d_in[10];
    const float* spe_res_w  = (const float*)d_in[11];
    const float* spe_res_b  = (const float*)d_in[12];
    const float* spe_tail_w = (const float*)d_in[13];
    const float* spe_tail_b = (const float*)d_in[14];
    const float* l1_w   = (const float*)d_in[15];
    const float* l1_b   = (const float*)d_in[16];
    const float* wg32_w1 = (const float*)d_in[17];
    const float* wg32_b1 = (const float*)d_in[18];
    const float* wg32_w2 = (const float*)d_in[19];
    const float* wg32_b2 = (const float*)d_in[20];
    const float* ffn32_w1 = (const float*)d_in[21];
    const float* ffn32_b1 = (const float*)d_in[22];
    const float* ffn32_w2 = (const float*)d_in[23];
    const float* ffn32_b2 = (const float*)d_in[24];
    const float* l2_w   = (const float*)d_in[25];
    const float* l2_b   = (const float*)d_in[26];
    const float* wg64_w1 = (const float*)d_in[27];
    const float* wg64_b1 = (const float*)d_in[28];
    const float* wg64_w2 = (const float*)d_in[29];
    const float* wg64_b2 = (const float*)d_in[30];
    const float* ffn64_w1 = (const float*)d_in[31];
    const float* ffn64_b1 = (const float*)d_in[32];
    const float* ffn64_w2 = (const float*)d_in[33];
    const float* ffn64_b2 = (const float*)d_in[34];

    char* ws = (char*)d_ws;
    f16* Wp      = (f16*)(ws + WPACK_B);
    f16* Cc      = (f16*)(ws + CC_B);
    f16* SPEin   = (f16*)(ws + SPEIN_B);
    f16* X2h     = (f16*)(ws + X2_B);
    f16* R2h     = (f16*)(ws + R2_B);
    f16* T2h     = (f16*)(ws + T2_B);
    f16* lrspe16 = (f16*)(ws + LRSPE_B);
    f16* Rh      = (f16*)(ws + RH_B);
    f16* Xh      = (f16*)(ws + XH_B);
    f16* Th      = (f16*)(ws + TH_B);
    f16* g32T    = (f16*)(ws + G32_B);
    f16* g16T    = (f16*)(ws + G16_B);
    f16* l1T16   = (f16*)(ws + L1T_B);
    f16* hr16    = (f16*)(ws + HR16_B);
    f16* l1imw = (f16*)(ws + L1IMW_B);
    f16* l1w1  = (f16*)(ws + L1W1_B);
    f16* l1w2  = (f16*)(ws + L1W2_B);
    f16* l1f1  = (f16*)(ws + L1F1_B);
    f16* l1f2  = (f16*)(ws + L1F2_B);
    f16* l2imw = (f16*)(ws + L2IMW_B);
    f16* l2w1  = (f16*)(ws + L2W1_B);
    f16* l2w2  = (f16*)(ws + L2W2_B);
    f16* l2f1  = (f16*)(ws + L2F1_B);
    f16* l2f2  = (f16*)(ws + L2F2_B);

    // zero padded fp16 regions (borders + never-written channels must be 0)
    hipMemsetAsync(ws + CC_B, 0, 8921088ull, stream);
    hipMemsetAsync(ws + RH_B, 0, 53526528ull, stream);

    // pack conv weights
    pack_w<<<288, 256, 0, stream>>>(spa_head_w, Wp + 0, 34, 2, 73728);
    pack_w<<<4608, 256, 0, stream>>>(spa_res_w, Wp + 73728, 128, 4, 1179648);
    pack_w<<<576, 256, 0, stream>>>(spa_tail_w, Wp + 1253376, 128, 4, 147456);
    pack_w<<<144, 256, 0, stream>>>(spe_head_w, Wp + 1400832, 31, 1, 36864);
    pack_w<<<4608, 256, 0, stream>>>(spe_res_w, Wp + 1437696, 128, 4, 1179648);
    pack_w<<<576, 256, 0, stream>>>(spe_tail_w, Wp + 2617344, 128, 4, 147456);

    // pack level MLP weights
    pack_lvl<<<416, 256, 0, stream>>>(l1_w, l1imw, 386, 256, 13);
    pack_lvl<<<32, 256, 0, stream>>>(wg32_w1, l1w1, 128, 64, 4);
    pack_lvl<<<32, 256, 0, stream>>>(wg32_w2, l1w2, 64, 128, 2);
    pack_lvl<<<32, 256, 0, stream>>>(ffn32_w1, l1f1, 128, 64, 4);
    pack_lvl<<<32, 256, 0, stream>>>(ffn32_w2, l1f2, 64, 128, 2);
    pack_lvl<<<416, 256, 0, stream>>>(l2_w, l2imw, 386, 256, 13);
    pack_lvl<<<32, 256, 0, stream>>>(wg64_w1, l2w1, 128, 64, 4);
    pack_lvl<<<32, 256, 0, stream>>>(wg64_w2, l2w2, 64, 128, 2);
    pack_lvl<<<32, 256, 0, stream>>>(ffn64_w1, l2f1, 128, 64, 4);
    pack_lvl<<<8, 256, 0, stream>>>(ffn64_w2, l2f2, 64, 31, 2);

    // ---- spatial EDSR (512-thread blocks: 8 waves, 2M x 4N) ----
    build_cc<<<8704, 256, 0, stream>>>(HR_MSI, lms, Cc, 16 * 64 * 64 * 34);
    conv_mfma<66, 6, 2, 8><<<512, 512, 0, stream>>>(Cc, 2, Wp + 0, spa_head_b,
                                                    nullptr, Xh, Rh, 4);
    hipMemsetAsync(ws + SPEIN_B, 0, 5361664ull, stream);
    for (int i = 0; i < 4; ++i) {
        conv_mfma<66, 6, 2, 8><<<512, 512, 0, stream>>>(
            Rh, 4, Wp + 73728 + (size_t)(2 * i) * 147456, spa_res_b + 2 * i * 128,
            nullptr, Th, nullptr, 1);
        conv_mfma<66, 6, 2, 8><<<512, 512, 0, stream>>>(
            Th, 4, Wp + 73728 + (size_t)(2 * i + 1) * 147456, spa_res_b + (2 * i + 1) * 128,
            nullptr, Rh, nullptr, 2);
    }
    conv_mfma<66, 6, 2, 8><<<512, 512, 0, stream>>>(Rh, 4, Wp + 1253376, spa_tail_b,
                                                    Xh, nullptr, hr16, 3);

    maxpool_nhwc<<<8192, 256, 0, stream>>>(hr16, g32T, 64, 64, 2, 2097152);
    maxpool_nhwc<<<2048, 256, 0, stream>>>(hr16, g16T, 64, 64, 4, 524288);

    // ---- spectral EDSR ----
    build_spe<<<496, 256, 0, stream>>>(LR_HSI, SPEin, 16 * 16 * 16 * 31);
    conv_mfma<18, 4, 4, 4><<<64, 256, 0, stream>>>(SPEin, 1, Wp + 1400832, spe_head_b,
                                                   nullptr, X2h, R2h, 4);
    for (int i = 0; i < 4; ++i) {
        conv_mfma<18, 4, 4, 4><<<64, 256, 0, stream>>>(
            R2h, 4, Wp + 1437696 + (size_t)(2 * i) * 147456, spe_res_b + 2 * i * 128,
            nullptr, T2h, nullptr, 1);
        conv_mfma<18, 4, 4, 4><<<64, 256, 0, stream>>>(
            T2h, 4, Wp + 1437696 + (size_t)(2 * i + 1) * 147456, spe_res_b + (2 * i + 1) * 128,
            nullptr, R2h, nullptr, 2);
    }
    conv_mfma<18, 4, 4, 4><<<64, 256, 0, stream>>>(R2h, 4, Wp + 2617344, spe_tail_b,
                                                   X2h, nullptr, lrspe16, 3);

    // ---- level 1: 32x32 queries, 16 q/block -> l1T16 f16 ----
    level_kernel<<<1024, 256, 0, stream>>>(
        lrspe16, 16, 16, g32T, 32, 32, g16T, 16, 16,
        32, 32, 64,
        l1imw, l1_b, l1w1, wg32_b1, l1w2, wg32_b2,
        l1f1, ffn32_b1, l1f2, ffn32_b2,
        128, 1, 0, nullptr, l1T16, nullptr);

    // ---- level 2: 64x64 queries, 16 q/block, + lms, fp32 NCHW to d_out ----
    level_kernel<<<4096, 256, 0, stream>>>(
        l1T16, 32, 32, hr16, 64, 64, g32T, 32, 32,
        64, 64, 256,
        l2imw, l2_b, l2w1, wg64_b1, l2w2, wg64_b2,
        l2f1, ffn64_b1, l2f2, ffn64_b2,
        31, 0, 1, lms, nullptr, (float*)d_out);
}

// Round 9
// 1027.354 us; speedup vs baseline: 8.4224x; 1.0113x over previous
//
#include <hip/hip_runtime.h>
#include <math.h>

typedef _Float16 f16;
typedef __attribute__((ext_vector_type(4))) _Float16 f16x4;
typedef __attribute__((ext_vector_type(8))) _Float16 f16x8;
typedef __attribute__((ext_vector_type(4))) float f32x4;
typedef __attribute__((ext_vector_type(4))) unsigned int u32x4;

// exact-GELU via Abramowitz-Stegun 7.1.26 erf (|err| <= 1.5e-7)
__device__ __forceinline__ float gelu_f(float x) {
    float xs = x * 0.70710678118654752440f;
    float ax = fabsf(xs);
    float t = __builtin_amdgcn_rcpf(1.0f + 0.3275911f * ax);
    float p = t * (0.254829592f + t * (-0.284496736f + t * (1.421413741f +
              t * (-1.453152027f + t * 1.061405429f))));
    float erfv = 1.0f - p * __expf(-ax * ax);
    erfv = copysignf(erfv, xs);
    return 0.5f * x * (1.0f + erfv);
}

__device__ __forceinline__ void nsamp(float cy, float cx, int hi, int wi,
                                      int& iy, int& ix, bool& valid) {
    float fy = rintf(((cy + 1.0f) * (float)hi - 1.0f) * 0.5f);
    float fx = rintf(((cx + 1.0f) * (float)wi - 1.0f) * 0.5f);
    valid = (fy >= 0.0f) && (fy < (float)hi) && (fx >= 0.0f) && (fx < (float)wi);
    iy = (int)fminf(fmaxf(fy, 0.0f), (float)(hi - 1));
    ix = (int)fminf(fmaxf(fx, 0.0f), (float)(wi - 1));
}

// ---- conv weight pre-pack: OIHW fp32 -> [conv][cout][chunk][tap][ci32] fp16 ----
__global__ __launch_bounds__(256) void pack_w(
    const float* __restrict__ src, f16* __restrict__ dst,
    int Cin, int NCHUNK, int total) {
    int i = blockIdx.x * 256 + threadIdx.x;
    if (i >= total) return;
    int ci = i & 31;
    int tap = (i >> 5) % 9;
    int q = i / 288;
    int chunk = q % NCHUNK;
    int q2 = q / NCHUNK;
    int cout = q2 & 127;
    int conv = q2 >> 7;
    int cin = chunk * 32 + ci;
    float v = (cin < Cin) ? src[((size_t)(conv * 128 + cout) * Cin + cin) * 9 + tap] : 0.f;
    dst[i] = (f16)v;
}

// ---- level MLP weight pack: src fp32 [K][N] -> dst fp16 [N][NC][32] ----
__global__ __launch_bounds__(256) void pack_lvl(
    const float* __restrict__ src, f16* __restrict__ dst,
    int Ksrc, int N, int NC) {
    int i = blockIdx.x * 256 + threadIdx.x;
    if (i >= N * NC * 32) return;
    int kk = i & 31;
    int c = (i >> 5) % NC;
    int n = i / (32 * NC);
    int k = c * 32 + kk;
    dst[i] = (f16)((k < Ksrc) ? src[(size_t)k * N + n] : 0.f);
}

// concat(HR_MSI, lms) -> padded NHWC fp16 [16][66][66][64]
__global__ __launch_bounds__(256) void build_cc(
    const float* __restrict__ msi, const float* __restrict__ lms,
    f16* __restrict__ out, int total) {
    int i = blockIdx.x * 256 + threadIdx.x;
    if (i >= total) return;
    int ch = i % 34;
    int p = i / 34;
    int x = p & 63, y = (p >> 6) & 63, b = p >> 12;
    float v = (ch < 3) ? msi[(((size_t)(b * 3 + ch) << 6) + y << 6) + x]
                       : lms[(((size_t)(b * 31 + ch - 3) << 6) + y << 6) + x];
    out[((size_t)(b * 66 + y + 1) * 66 + x + 1) * 64 + ch] = v;
}

// LR_HSI -> padded NHWC fp16 [16][18][18][32]
__global__ __launch_bounds__(256) void build_spe(
    const float* __restrict__ in, f16* __restrict__ out, int total) {
    int i = blockIdx.x * 256 + threadIdx.x;
    if (i >= total) return;
    int ch = i % 31;
    int p = i / 31;
    int x = p & 15, y = (p >> 4) & 15, b = p >> 8;
    out[((size_t)(b * 18 + y + 1) * 18 + x + 1) * 32 + ch] =
        (f16)in[(((size_t)(b * 31 + ch) << 4) + y << 4) + x];
}

// ---- implicit-GEMM conv3x3 SAME, NHWC fp16 padded in, Cout=128 ----
// Whole input tile staged to LDS ONCE -> single barrier -> all MFMAs free-running.
// Block: ROWS*XW px x 128 cout; WAVES = 2 (M halves) x WN (N split); NCHUNK comptime.
// mode: 0 plain->out_h, 1 relu->out_h, 2 self-add, 3 tail (+skip -> out2 unpadded),
//       4 dual write (out_h and out2, both padded)
template<int PXW, int XSH, int ROWS, int WAVES, int NCHUNK>
__global__ __launch_bounds__(WAVES * 64, 4) void conv_mfma(
    const f16* __restrict__ in_h,
    const f16* __restrict__ wp, const float* __restrict__ bias,
    const f16* __restrict__ skip_h, f16* __restrict__ out_h,
    f16* __restrict__ out2, int mode) {
    constexpr int XW = 1 << XSH;
    constexpr int PH = XW + 2;
    constexpr int NPX = (ROWS + 2) * PXW;
    constexpr int UPP = NCHUNK * 4;        // 16B units per pixel
    constexpr int UNITS = NPX * UPP;
    constexpr int NTH = WAVES * 64;
    constexpr int ITER = (UNITS + NTH - 1) / NTH;
    constexpr int WN = WAVES / 2;
    constexpr int NT = 8 / WN;
    constexpr int MT = (ROWS << XSH) >> 5;
    constexpr int PXB = NCHUNK * 64;       // bytes per pixel in LDS
    __shared__ char ldsb[NPX * PXB];

    int tid = threadIdx.x;
    constexpr int NYB = XW / ROWS;
    int b = blockIdx.x / NYB;
    int y0 = (blockIdx.x % NYB) * ROWS;
    int wave = tid >> 6, lane = tid & 63;
    int wm = wave / WN, wn = wave % WN;
    int l15 = lane & 15, lk = lane >> 4;

    // ---- stage the whole (ROWS+2) x PXW x Cin tile (one barrier) ----
#pragma unroll
    for (int i = 0; i < ITER; ++i) {
        int u = tid + NTH * i;
        if (u < UNITS) {
            int px = u / UPP, kg = u % UPP;
            int r = px / PXW, xp = px - r * PXW;
            u32x4 v = *(const u32x4*)(in_h +
                (size_t)((b * PH + y0 + r) * PXW + xp) * (NCHUNK * 32) + kg * 8);
            *(u32x4*)(ldsb + ((u * 16) ^ ((px & 7) << 4))) = v;
        }
    }
    __syncthreads();

    f32x4 acc[MT][NT];
#pragma unroll
    for (int mt = 0; mt < MT; ++mt)
#pragma unroll
        for (int nt = 0; nt < NT; ++nt)
            acc[mt][nt] = (f32x4){0.f, 0.f, 0.f, 0.f};

#pragma unroll
    for (int c = 0; c < NCHUNK; ++c) {
#pragma unroll
        for (int tap = 0; tap < 9; ++tap) {
            const int dy = tap / 3, dx = tap % 3;
            f16x8 afr[MT];
#pragma unroll
            for (int mt = 0; mt < MT; ++mt) {
                int px = (wm * MT + mt) * 16 + l15;
                int row = px >> XSH, x = px & (XW - 1);
                int pxl = (row + dy) * PXW + x + dx;
                int la = pxl * PXB + c * 64 + lk * 16;
                afr[mt] = *(const f16x8*)(ldsb + (la ^ ((pxl & 7) << 4)));
            }
#pragma unroll
            for (int nt = 0; nt < NT; ++nt) {
                int cout = wn * (NT * 16) + nt * 16 + l15;
                f16x8 bfr = *(const f16x8*)(wp + ((size_t)(cout * NCHUNK + c) * 9 + tap) * 32 + lk * 8);
#pragma unroll
                for (int mt = 0; mt < MT; ++mt)
                    acc[mt][nt] = __builtin_amdgcn_mfma_f32_16x16x32_f16(afr[mt], bfr, acc[mt][nt], 0, 0, 0);
            }
        }
    }

#pragma unroll
    for (int mt = 0; mt < MT; ++mt)
#pragma unroll
        for (int nt = 0; nt < NT; ++nt) {
            int cout = wn * (NT * 16) + nt * 16 + l15;
            float bv = bias[cout];
#pragma unroll
            for (int reg = 0; reg < 4; ++reg) {
                int px = (wm * MT + mt) * 16 + lk * 4 + reg;
                int row = px >> XSH, x = px & (XW - 1);
                int yim = y0 + row;
                float vv = acc[mt][nt][reg] + bv;
                size_t ah = ((size_t)(b * PH + yim + 1) * PXW + x + 1) * 128 + cout;
                if (mode == 1) vv = fmaxf(vv, 0.f);
                if (mode == 2) vv += (float)out_h[ah];
                if (mode == 3) {
                    vv += (float)skip_h[ah];
                    out2[((size_t)((b << XSH) + yim) << XSH | x) * 128 + cout] = (f16)vv;
                } else if (mode == 4) {
                    f16 hv = (f16)vv;
                    out_h[ah] = hv;
                    out2[ah] = hv;
                } else {
                    out_h[ah] = (f16)vv;
                }
            }
        }
}

// max pool kxk stride k on NHWC f16 (C=128)
__global__ __launch_bounds__(256) void maxpool_nhwc(
    const f16* __restrict__ in, f16* __restrict__ out,
    int H, int W, int k, int total) {
    int i = blockIdx.x * 256 + threadIdx.x;
    if (i >= total) return;
    int c = i & 127;
    int r = i >> 7;
    int Wo = W / k, Ho = H / k;
    int x = r % Wo; r /= Wo;
    int y = r % Ho;
    int b = r / Ho;
    float m = -3.402823466e38f;
    for (int dy = 0; dy < k; ++dy)
        for (int dx = 0; dx < k; ++dx)
            m = fmaxf(m, (float)in[((size_t)(b * H + y * k + dy) * W + x * k + dx) * 128 + c]);
    out[i] = (f16)m;
}

// ---- Fused level(), all-MFMA, 16 queries/block, 256 threads. ----
__global__ __launch_bounds__(256) void level_kernel(
    const f16* __restrict__ featT, int fh, int fw,
    const f16* __restrict__ guideT, int Hg, int Wg,
    const f16* __restrict__ glrT, int hl, int wl,
    int Hq, int Wq, int n_per_b,
    const f16* __restrict__ imw_h, const float* __restrict__ imb,
    const f16* __restrict__ w1h, const float* __restrict__ b1,
    const f16* __restrict__ w2h, const float* __restrict__ b2,
    const f16* __restrict__ f1h, const float* __restrict__ fb1,
    const f16* __restrict__ f2h, const float* __restrict__ fb2,
    int odim, int residual, int out_nchw,
    const float* __restrict__ lms,
    f16* __restrict__ out16, float* __restrict__ outf) {
    __shared__ char smem[58624];
    f16* s_inp  = (f16*)smem;            // [64][424]
    f16* s_pred = (f16*)smem;            // [128][136] overlay
    f16* s_h1   = (f16*)(smem + 34816);  // [128][72]
    f16* s_hh   = (f16*)smem;            // [16][72] overlay (after s_pred dead)
    f16* s_rec  = (f16*)(smem + 54272);  // [16][136]

    int tid = threadIdx.x;
    int b = blockIdx.x / n_per_b;
    int n0 = (blockIdx.x % n_per_b) * 16;
    float invHq = 1.0f / (float)Hq, invWq = 1.0f / (float)Wq;
    float invfh = 1.0f / (float)fh, invfw = 1.0f / (float)fw;
    int wave = tid >> 6, lane = tid & 63;
    int l15 = lane & 15, lk = lane >> 4;

    // ---- gather: build s_inp[64][424] fp16; row = (cidx, q), 4 threads/row ----
    {
        const int r64 = tid >> 2, t4 = tid & 3;
        const int cidx = r64 >> 4, q = r64 & 15;
        int n = n0 + q;
        int qy = n / Wq, qx = n - qy * Wq;
        float cy = -1.0f + (float)(2 * qy + 1) * invHq;
        float cx = -1.0f + (float)(2 * qx + 1) * invWq;
        float vxc = (cidx < 2) ? -1.0f : 1.0f;
        float vyc = (cidx & 1) ? 1.0f : -1.0f;
        float cy_ = cy + vxc * invfh;
        float cx_ = cx + vyc * invfw;
        int iy, ix; bool vf;
        nsamp(cy_, cx_, fh, fw, iy, ix, vf);
        const f16* fp = featT + ((size_t)(b * fh + iy) * fw + ix) * 128;
        int gy, gx; bool vg0;
        nsamp(cy, cx, Hg, Wg, gy, gx, vg0);
        const f16* gp = guideT + ((size_t)(b * Hg + gy) * Wg + gx) * 128;
        int ly, lx; bool vl;
        nsamp(cy_, cx_, hl, wl, ly, lx, vl);
        const f16* lp = glrT + ((size_t)(b * hl + ly) * wl + lx) * 128;
        f16* row = s_inp + r64 * 424;
        const u32x4 zz = (u32x4){0, 0, 0, 0};
#pragma unroll
        for (int e = 0; e < 4; ++e) {
            int d0 = t4 * 8 + e * 32;
            u32x4 av = vf ? *(const u32x4*)(fp + d0) : zz;
            u32x4 gv = vg0 ? *(const u32x4*)(gp + d0) : zz;
            u32x4 lv = vl ? *(const u32x4*)(lp + d0) : zz;
            *(u32x4*)(row + d0) = av;
            *(u32x4*)(row + 128 + d0) = gv;
            *(u32x4*)(row + 256 + d0) = lv;
        }
        if (t4 == 0) {
#pragma unroll
            for (int e = 0; e < 4; ++e)
                *(u32x4*)((char*)row + 768 + e * 16) = zz;
            float csy = vf ? (-1.0f + (float)(2 * iy + 1) * invfh) : 0.0f;
            float csx = vf ? (-1.0f + (float)(2 * ix + 1) * invfw) : 0.0f;
            row[384] = (f16)((cy - csy) * (float)fh);
            row[385] = (f16)((cx - csx) * (float)fw);
        }
    }
    __syncthreads();

    // ---- corner GEMM: 64x416 @ 416x256 ----
    f32x4 acc[4][4];
    {
#pragma unroll
        for (int mt = 0; mt < 4; ++mt)
#pragma unroll
            for (int nt = 0; nt < 4; ++nt)
                acc[mt][nt] = (f32x4){0.f, 0.f, 0.f, 0.f};
        int nbase = wave * 64;
#pragma unroll
        for (int ks = 0; ks < 13; ++ks) {
            f16x8 afr[4];
#pragma unroll
            for (int mt = 0; mt < 4; ++mt)
                afr[mt] = *(const f16x8*)((char*)s_inp + (mt * 16 + l15) * 848 + ks * 64 + lk * 16);
#pragma unroll
            for (int nt = 0; nt < 4; ++nt) {
                f16x8 bfr = *(const f16x8*)(imw_h + ((size_t)(nbase + nt * 16 + l15) * 13 + ks) * 32 + lk * 8);
#pragma unroll
                for (int mt = 0; mt < 4; ++mt)
                    acc[mt][nt] = __builtin_amdgcn_mfma_f32_16x16x32_f16(afr[mt], bfr, acc[mt][nt], 0, 0, 0);
            }
        }
    }
    __syncthreads();  // s_inp reads complete; region may be overlaid

    // ---- epilogue: bias + relu -> s_pred fp16 [qj][128] ----
    {
        int nbase = wave * 64;
#pragma unroll
        for (int nt = 0; nt < 4; ++nt) {
            int col = nbase + nt * 16 + l15;
            float bv = imb[col];
            int j_hi = col >> 7, d = col & 127;
#pragma unroll
            for (int mt = 0; mt < 4; ++mt)
#pragma unroll
                for (int reg = 0; reg < 4; ++reg) {
                    int row64 = mt * 16 + lk * 4 + reg;
                    int q = row64 & 15, cidx = row64 >> 4;
                    int qj = q * 8 + cidx * 2 + j_hi;
                    s_pred[qj * 136 + d] = (f16)fmaxf(acc[mt][nt][reg] + bv, 0.f);
                }
        }
    }
    __syncthreads();

    // ---- wg1: preds[128][128] @ w1[128][64] -> h1 fp16 [128][72] ----
    {
        f32x4 a1[8];
#pragma unroll
        for (int mt = 0; mt < 8; ++mt) a1[mt] = (f32x4){0.f, 0.f, 0.f, 0.f};
        int c1 = wave * 16 + l15;
#pragma unroll
        for (int ks = 0; ks < 4; ++ks) {
            f16x8 bfr = *(const f16x8*)(w1h + ((size_t)c1 * 4 + ks) * 32 + lk * 8);
#pragma unroll
            for (int mt = 0; mt < 8; ++mt) {
                f16x8 afr = *(const f16x8*)((char*)s_pred + (mt * 16 + l15) * 272 + ks * 64 + lk * 16);
                a1[mt] = __builtin_amdgcn_mfma_f32_16x16x32_f16(afr, bfr, a1[mt], 0, 0, 0);
            }
        }
        float bb1 = b1[c1];
#pragma unroll
        for (int mt = 0; mt < 8; ++mt)
#pragma unroll
            for (int reg = 0; reg < 4; ++reg) {
                int row = mt * 16 + lk * 4 + reg;
                s_h1[row * 72 + c1] = (f16)gelu_f(a1[mt][reg] + bb1);
            }
    }
    __syncthreads();

    // ---- wg2 + softmax over j + recon -> s_rec f16 [16][136] ----
    {
        f32x4 a2[8][2];
#pragma unroll
        for (int mt = 0; mt < 8; ++mt) {
            a2[mt][0] = (f32x4){0.f, 0.f, 0.f, 0.f};
            a2[mt][1] = (f32x4){0.f, 0.f, 0.f, 0.f};
        }
#pragma unroll
        for (int ks = 0; ks < 2; ++ks) {
#pragma unroll
            for (int nt = 0; nt < 2; ++nt) {
                int c2 = wave * 32 + nt * 16 + l15;
                f16x8 bfr = *(const f16x8*)(w2h + ((size_t)c2 * 2 + ks) * 32 + lk * 8);
#pragma unroll
                for (int mt = 0; mt < 8; ++mt) {
                    f16x8 afr = *(const f16x8*)((char*)s_h1 + (mt * 16 + l15) * 144 + ks * 64 + lk * 16);
                    a2[mt][nt] = __builtin_amdgcn_mfma_f32_16x16x32_f16(afr, bfr, a2[mt][nt], 0, 0, 0);
                }
            }
        }
        int qhalf = lk >> 1;
#pragma unroll
        for (int nt = 0; nt < 2; ++nt) {
            int col = wave * 32 + nt * 16 + l15;
            float bb2 = b2[col];
#pragma unroll
            for (int mt = 0; mt < 8; ++mt) {
                int q = mt * 2 + qhalf;
                float v[4];
                float mloc = -3.4e38f;
#pragma unroll
                for (int reg = 0; reg < 4; ++reg) {
                    v[reg] = a2[mt][nt][reg] + bb2;
                    mloc = fmaxf(mloc, v[reg]);
                }
                float mf = fmaxf(mloc, __shfl_xor(mloc, 16));
                float e[4], sl = 0.f;
#pragma unroll
                for (int reg = 0; reg < 4; ++reg) {
                    e[reg] = __expf(v[reg] - mf);
                    sl += e[reg];
                }
                float sf = sl + __shfl_xor(sl, 16);
                float inv = 1.0f / sf;
                float rp = 0.f;
#pragma unroll
                for (int reg = 0; reg < 4; ++reg) {
                    int row = mt * 16 + lk * 4 + reg;
                    rp += (float)s_pred[row * 136 + col] * e[reg];
                }
                rp *= inv;
                float rf = rp + __shfl_xor(rp, 16);
                if ((lk & 1) == 0) s_rec[q * 136 + col] = (f16)rf;
            }
        }
    }
    __syncthreads();  // s_pred/s_h1 dead; s_rec ready

    // ---- ffn1 (MFMA): rec[16][128] @ f1[128][64] -> s_hh[16][72] ----
    {
        f32x4 a1 = (f32x4){0.f, 0.f, 0.f, 0.f};
        int c1 = wave * 16 + l15;
#pragma unroll
        for (int ks = 0; ks < 4; ++ks) {
            f16x8 afr = *(const f16x8*)((char*)s_rec + l15 * 272 + ks * 64 + lk * 16);
            f16x8 bfr = *(const f16x8*)(f1h + ((size_t)c1 * 4 + ks) * 32 + lk * 8);
            a1 = __builtin_amdgcn_mfma_f32_16x16x32_f16(afr, bfr, a1, 0, 0, 0);
        }
        float bb = fb1[c1];
#pragma unroll
        for (int reg = 0; reg < 4; ++reg) {
            int row = lk * 4 + reg;
            s_hh[row * 72 + c1] = (f16)gelu_f(a1[reg] + bb);
        }
    }
    __syncthreads();

    // ---- ffn2 (MFMA): h[16][64] @ f2[64][odim] -> out ----
    if (!out_nchw) {
        f32x4 a2[2];
        a2[0] = (f32x4){0.f, 0.f, 0.f, 0.f};
        a2[1] = (f32x4){0.f, 0.f, 0.f, 0.f};
#pragma unroll
        for (int ks = 0; ks < 2; ++ks) {
            f16x8 afr = *(const f16x8*)((char*)s_hh + l15 * 144 + ks * 64 + lk * 16);
#pragma unroll
            for (int nt = 0; nt < 2; ++nt) {
                int col = wave * 32 + nt * 16 + l15;
                f16x8 bfr = *(const f16x8*)(f2h + ((size_t)col * 2 + ks) * 32 + lk * 8);
                a2[nt] = __builtin_amdgcn_mfma_f32_16x16x32_f16(afr, bfr, a2[nt], 0, 0, 0);
            }
        }
#pragma unroll
        for (int nt = 0; nt < 2; ++nt) {
            int col = wave * 32 + nt * 16 + l15;
            float bb = fb2[col];
#pragma unroll
            for (int reg = 0; reg < 4; ++reg) {
                int q = lk * 4 + reg;
                int n = n0 + q;
                int qy = n / Wq, qx = n - qy * Wq;
                float val = a2[nt][reg] + bb;
                if (residual) val += (float)s_rec[q * 136 + col];
                out16[((size_t)(b * Hq + qy) * Wq + qx) * 128 + col] = (f16)val;
            }
        }
    } else {
        if (wave < 2) {
            f32x4 a2 = (f32x4){0.f, 0.f, 0.f, 0.f};
#pragma unroll
            for (int ks = 0; ks < 2; ++ks) {
                f16x8 afr = *(const f16x8*)((char*)s_hh + l15 * 144 + ks * 64 + lk * 16);
                int col = wave * 16 + l15;
                f16x8 bfr = *(const f16x8*)(f2h + ((size_t)col * 2 + ks) * 32 + lk * 8);
                a2 = __builtin_amdgcn_mfma_f32_16x16x32_f16(afr, bfr, a2, 0, 0, 0);
            }
            int d = wave * 16 + l15;
            if (d < odim) {
                float bb = fb2[d];
#pragma unroll
                for (int reg = 0; reg < 4; ++reg) {
                    int q = lk * 4 + reg;
                    int n = n0 + q;
                    int qy = n / Wq, qx = n - qy * Wq;
                    size_t oi = (((size_t)b * odim + d) * Hq + qy) * Wq + qx;
                    outf[oi] = a2[reg] + bb + lms[oi];
                }
            }
        }
    }
}

// ---- workspace byte offsets ----
#define WPACK_B   0ull
#define CC_B      5529600ull
#define SPEIN_B   (CC_B)
#define X2_B      (CC_B + 331776ull)
#define R2_B      (CC_B + 1658880ull)
#define T2_B      (CC_B + 2985984ull)
#define RH_B      14450688ull
#define TH_B      32292864ull
#define XH_B      50135040ull
#define G32_B     (TH_B)
#define G16_B     (TH_B + 4194304ull)
#define L1T_B     (TH_B + 5242880ull)
#define LRSPE_B   (CC_B + 4313088ull)
#define HR16_B    67977216ull
#define LVLW_B    101531648ull
#define L1IMW_B   (LVLW_B)
#define L1W1_B    (LVLW_B + 212992ull)
#define L1W2_B    (LVLW_B + 229376ull)
#define L1F1_B    (LVLW_B + 245760ull)
#define L1F2_B    (LVLW_B + 262144ull)
#define L2IMW_B   (LVLW_B + 278528ull)
#define L2W1_B    (LVLW_B + 491520ull)
#define L2W2_B    (LVLW_B + 507904ull)
#define L2F1_B    (LVLW_B + 524288ull)
#define L2F2_B    (LVLW_B + 540672ull)

extern "C" void kernel_launch(void* const* d_in, const int* in_sizes, int n_in,
                              void* d_out, int out_size, void* d_ws, size_t ws_size,
                              hipStream_t stream) {
    (void)in_sizes; (void)n_in; (void)out_size; (void)ws_size;
    const float* HR_MSI     = (const float*)d_in[0];
    const float* lms        = (const float*)d_in[1];
    const float* LR_HSI     = (const float*)d_in[2];
    const float* spa_head_w = (const float*)d_in[3];
    const float* spa_head_b = (const float*)d_in[4];
    const float* spa_res_w  = (const float*)d_in[5];
    const float* spa_res_b  = (const float*)d_in[6];
    const float* spa_tail_w = (const float*)d_in[7];
    const float* spa_tail_b = (const float*)d_in[8];
    const float* spe_head_w = (const float*)d_in[9];
    const float* spe_head_b = (const float*)d_in[10];
    const float* spe_res_w  = (const float*)d_in[11];
    const float* spe_res_b  = (const float*)d_in[12];
    const float* spe_tail_w = (const float*)d_in[13];
    const float* spe_tail_b = (const float*)d_in[14];
    const float* l1_w   = (const float*)d_in[15];
    const float* l1_b   = (const float*)d_in[16];
    const float* wg32_w1 = (const float*)d_in[17];
    const float* wg32_b1 = (const float*)d_in[18];
    const float* wg32_w2 = (const float*)d_in[19];
    const float* wg32_b2 = (const float*)d_in[20];
    const float* ffn32_w1 = (const float*)d_in[21];
    const float* ffn32_b1 = (const float*)d_in[22];
    const float* ffn32_w2 = (const float*)d_in[23];
    const float* ffn32_b2 = (const float*)d_in[24];
    const float* l2_w   = (const float*)d_in[25];
    const float* l2_b   = (const float*)d_in[26];
    const float* wg64_w1 = (const float*)d_in[27];
    const float* wg64_b1 = (const float*)d_in[28];
    const float* wg64_w2 = (const float*)d_in[29];
    const float* wg64_b2 = (const float*)d_in[30];
    const float* ffn64_w1 = (const float*)d_in[31];
    const float* ffn64_b1 = (const float*)d_in[32];
    const float* ffn64_w2 = (const float*)d_in[33];
    const float* ffn64_b2 = (const float*)d_in[34];

    char* ws = (char*)d_ws;
    f16* Wp      = (f16*)(ws + WPACK_B);
    f16* Cc      = (f16*)(ws + CC_B);
    f16* SPEin   = (f16*)(ws + SPEIN_B);
    f16* X2h     = (f16*)(ws + X2_B);
    f16* R2h     = (f16*)(ws + R2_B);
    f16* T2h     = (f16*)(ws + T2_B);
    f16* lrspe16 = (f16*)(ws + LRSPE_B);
    f16* Rh      = (f16*)(ws + RH_B);
    f16* Xh      = (f16*)(ws + XH_B);
    f16* Th      = (f16*)(ws + TH_B);
    f16* g32T    = (f16*)(ws + G32_B);
    f16* g16T    = (f16*)(ws + G16_B);
    f16* l1T16   = (f16*)(ws + L1T_B);
    f16* hr16    = (f16*)(ws + HR16_B);
    f16* l1imw = (f16*)(ws + L1IMW_B);
    f16* l1w1  = (f16*)(ws + L1W1_B);
    f16* l1w2  = (f16*)(ws + L1W2_B);
    f16* l1f1  = (f16*)(ws + L1F1_B);
    f16* l1f2  = (f16*)(ws + L1F2_B);
    f16* l2imw = (f16*)(ws + L2IMW_B);
    f16* l2w1  = (f16*)(ws + L2W1_B);
    f16* l2w2  = (f16*)(ws + L2W2_B);
    f16* l2f1  = (f16*)(ws + L2F1_B);
    f16* l2f2  = (f16*)(ws + L2F2_B);

    // zero padded fp16 regions (borders + never-written channels must be 0)
    hipMemsetAsync(ws + CC_B, 0, 8921088ull, stream);
    hipMemsetAsync(ws + RH_B, 0, 53526528ull, stream);

    // pack conv weights
    pack_w<<<288, 256, 0, stream>>>(spa_head_w, Wp + 0, 34, 2, 73728);
    pack_w<<<4608, 256, 0, stream>>>(spa_res_w, Wp + 73728, 128, 4, 1179648);
    pack_w<<<576, 256, 0, stream>>>(spa_tail_w, Wp + 1253376, 128, 4, 147456);
    pack_w<<<144, 256, 0, stream>>>(spe_head_w, Wp + 1400832, 31, 1, 36864);
    pack_w<<<4608, 256, 0, stream>>>(spe_res_w, Wp + 1437696, 128, 4, 1179648);
    pack_w<<<576, 256, 0, stream>>>(spe_tail_w, Wp + 2617344, 128, 4, 147456);

    // pack level MLP weights
    pack_lvl<<<416, 256, 0, stream>>>(l1_w, l1imw, 386, 256, 13);
    pack_lvl<<<32, 256, 0, stream>>>(wg32_w1, l1w1, 128, 64, 4);
    pack_lvl<<<32, 256, 0, stream>>>(wg32_w2, l1w2, 64, 128, 2);
    pack_lvl<<<32, 256, 0, stream>>>(ffn32_w1, l1f1, 128, 64, 4);
    pack_lvl<<<32, 256, 0, stream>>>(ffn32_w2, l1f2, 64, 128, 2);
    pack_lvl<<<416, 256, 0, stream>>>(l2_w, l2imw, 386, 256, 13);
    pack_lvl<<<32, 256, 0, stream>>>(wg64_w1, l2w1, 128, 64, 4);
    pack_lvl<<<32, 256, 0, stream>>>(wg64_w2, l2w2, 64, 128, 2);
    pack_lvl<<<32, 256, 0, stream>>>(ffn64_w1, l2f1, 128, 64, 4);
    pack_lvl<<<8, 256, 0, stream>>>(ffn64_w2, l2f2, 64, 31, 2);

    // ---- spatial EDSR (512-thread blocks, whole-tile LDS, 1 barrier) ----
    build_cc<<<8704, 256, 0, stream>>>(HR_MSI, lms, Cc, 16 * 64 * 64 * 34);
    conv_mfma<66, 6, 2, 8, 2><<<512, 512, 0, stream>>>(Cc, Wp + 0, spa_head_b,
                                                       nullptr, Xh, Rh, 4);
    hipMemsetAsync(ws + SPEIN_B, 0, 5361664ull, stream);
    for (int i = 0; i < 4; ++i) {
        conv_mfma<66, 6, 2, 8, 4><<<512, 512, 0, stream>>>(
            Rh, Wp + 73728 + (size_t)(2 * i) * 147456, spa_res_b + 2 * i * 128,
            nullptr, Th, nullptr, 1);
        conv_mfma<66, 6, 2, 8, 4><<<512, 512, 0, stream>>>(
            Th, Wp + 73728 + (size_t)(2 * i + 1) * 147456, spa_res_b + (2 * i + 1) * 128,
            nullptr, Rh, nullptr, 2);
    }
    conv_mfma<66, 6, 2, 8, 4><<<512, 512, 0, stream>>>(Rh, Wp + 1253376, spa_tail_b,
                                                       Xh, nullptr, hr16, 3);

    maxpool_nhwc<<<8192, 256, 0, stream>>>(hr16, g32T, 64, 64, 2, 2097152);
    maxpool_nhwc<<<2048, 256, 0, stream>>>(hr16, g16T, 64, 64, 4, 524288);

    // ---- spectral EDSR (ROWS=2 -> 128 blocks, 2x CU coverage) ----
    build_spe<<<496, 256, 0, stream>>>(LR_HSI, SPEin, 16 * 16 * 16 * 31);
    conv_mfma<18, 4, 2, 4, 1><<<128, 256, 0, stream>>>(SPEin, Wp + 1400832, spe_head_b,
                                                       nullptr, X2h, R2h, 4);
    for (int i = 0; i < 4; ++i) {
        conv_mfma<18, 4, 2, 4, 4><<<128, 256, 0, stream>>>(
            R2h, Wp + 1437696 + (size_t)(2 * i) * 147456, spe_res_b + 2 * i * 128,
            nullptr, T2h, nullptr, 1);
        conv_mfma<18, 4, 2, 4, 4><<<128, 256, 0, stream>>>(
            T2h, Wp + 1437696 + (size_t)(2 * i + 1) * 147456, spe_res_b + (2 * i + 1) * 128,
            nullptr, R2h, nullptr, 2);
    }
    conv_mfma<18, 4, 2, 4, 4><<<128, 256, 0, stream>>>(R2h, Wp + 2617344, spe_tail_b,
                                                       X2h, nullptr, lrspe16, 3);

    // ---- level 1: 32x32 queries, 16 q/block -> l1T16 f16 ----
    level_kernel<<<1024, 256, 0, stream>>>(
        lrspe16, 16, 16, g32T, 32, 32, g16T, 16, 16,
        32, 32, 64,
        l1imw, l1_b, l1w1, wg32_b1, l1w2, wg32_b2,
        l1f1, ffn32_b1, l1f2, ffn32_b2,
        128, 1, 0, nullptr, l1T16, nullptr);

    // ---- level 2: 64x64 queries, 16 q/block, + lms, fp32 NCHW to d_out ----
    level_kernel<<<4096, 256, 0, stream>>>(
        l1T16, 32, 32, hr16, 64, 64, g32T, 32, 32,
        64, 64, 256,
        l2imw, l2_b, l2w1, wg64_b1, l2w2, wg64_b2,
        l2f1, ffn64_b1, l2f2, ffn64_b2,
        31, 0, 1, lms, nullptr, (float*)d_out);
}